// Round 1
// baseline (14095.604 us; speedup 1.0000x reference)
//
#include <hip/hip_runtime.h>
#include <math.h>

#define N_NODES 100000
#define E_EDGES 1600000
#define ETOT    (E_EDGES + N_NODES)
#define HEADS   8
#define HID     16
#define NEG     0.2f

// float atomic max via int/uint trick. Init bit pattern 0xFFFFFFFF acts as -inf:
//  - as int it's -1 (< any non-negative float's int bits)
//  - as uint it's UINT_MAX (> any negative float's uint bits)
__device__ inline void atomicMaxF(float* a, float v) {
    if (v >= 0.f) atomicMax((int*)a, __float_as_int(v));
    else          atomicMin((unsigned int*)a, __float_as_uint(v));
}

__device__ inline float lrelu(float x) { return x > 0.f ? x : NEG * x; }

// ---------------- layer 1 GEMM: h1 = x @ W1, plus s1/d1 attention halves ----
// block = 256 threads, handles 8 nodes. thread (sg = t>>7, j = t&127) computes
// columns j of nodes {n0+sg, n0+sg+2, n0+sg+4, n0+sg+6}.
__global__ __launch_bounds__(256) void k_gemm1(
    const float* __restrict__ x, const float* __restrict__ W,
    const float* __restrict__ asrc, const float* __restrict__ adst,
    float* __restrict__ h1, float* __restrict__ s1, float* __restrict__ d1) {
    __shared__ float xs[8][128];
    int n0 = blockIdx.x * 8;
    int t = threadIdx.x;
#pragma unroll
    for (int i = 0; i < 4; ++i) {
        int idx = t + i * 256;
        xs[idx >> 7][idx & 127] = x[(long)n0 * 128 + idx];
    }
    __syncthreads();
    int j = t & 127, sg = t >> 7;
    float a0 = 0.f, a1 = 0.f, a2 = 0.f, a3 = 0.f;
    for (int k = 0; k < 128; ++k) {
        float w = W[k * 128 + j];
        a0 = fmaf(xs[sg + 0][k], w, a0);
        a1 = fmaf(xs[sg + 2][k], w, a1);
        a2 = fmaf(xs[sg + 4][k], w, a2);
        a3 = fmaf(xs[sg + 6][k], w, a3);
    }
    float as = asrc[j], ad = adst[j];
    float accs[4] = {a0, a1, a2, a3};
#pragma unroll
    for (int i = 0; i < 4; ++i) {
        int n = n0 + sg + 2 * i;
        h1[(long)n * 128 + j] = accs[i];
        float ps = accs[i] * as, pd = accs[i] * ad;
#pragma unroll
        for (int off = 8; off; off >>= 1) {
            ps += __shfl_down(ps, off, 16);
            pd += __shfl_down(pd, off, 16);
        }
        if ((j & 15) == 0) {
            s1[n * 8 + (j >> 4)] = ps;
            d1[n * 8 + (j >> 4)] = pd;
        }
    }
}

// ---------------- layer 1 edge kernels (8 heads) ----------------------------
__global__ void k_emax1(const int* __restrict__ src, const int* __restrict__ dst,
                        const float* __restrict__ s1, const float* __restrict__ d1,
                        float* __restrict__ emax) {
    int t = blockIdx.x * blockDim.x + threadIdx.x;
    if (t >= ETOT * HEADS) return;
    int eid = t >> 3, h = t & 7;
    int s, d;
    if (eid < E_EDGES) { s = src[eid]; d = dst[eid]; } else { s = d = eid - E_EDGES; }
    float e = lrelu(s1[s * 8 + h] + d1[d * 8 + h]);
    atomicMaxF(&emax[d * 8 + h], e);
}

__global__ void k_esum1(const int* __restrict__ src, const int* __restrict__ dst,
                        const float* __restrict__ s1, const float* __restrict__ d1,
                        const float* __restrict__ emax, float* __restrict__ den) {
    int t = blockIdx.x * blockDim.x + threadIdx.x;
    if (t >= ETOT * HEADS) return;
    int eid = t >> 3, h = t & 7;
    int s, d;
    if (eid < E_EDGES) { s = src[eid]; d = dst[eid]; } else { s = d = eid - E_EDGES; }
    float e = lrelu(s1[s * 8 + h] + d1[d * 8 + h]);
    atomicAdd(&den[d * 8 + h], __expf(e - emax[d * 8 + h]));
}

__global__ void k_eagg1(const int* __restrict__ src, const int* __restrict__ dst,
                        const float* __restrict__ s1, const float* __restrict__ d1,
                        const float* __restrict__ emax, const float* __restrict__ den,
                        const float* __restrict__ h1, float* __restrict__ agg) {
    int t = blockIdx.x * blockDim.x + threadIdx.x;
    if (t >= ETOT * HEADS) return;
    int eid = t >> 3, h = t & 7;
    int s, d;
    if (eid < E_EDGES) { s = src[eid]; d = dst[eid]; } else { s = d = eid - E_EDGES; }
    float e = lrelu(s1[s * 8 + h] + d1[d * 8 + h]);
    float alpha = __expf(e - emax[d * 8 + h]) / (den[d * 8 + h] + 1e-16f);
    const float4* hr = (const float4*)(h1 + (long)s * 128 + h * 16);
    float* ar = agg + (long)d * 128 + h * 16;
#pragma unroll
    for (int i = 0; i < 4; ++i) {
        float4 v = hr[i];
        atomicAdd(ar + 4 * i + 0, alpha * v.x);
        atomicAdd(ar + 4 * i + 1, alpha * v.y);
        atomicAdd(ar + 4 * i + 2, alpha * v.z);
        atomicAdd(ar + 4 * i + 3, alpha * v.w);
    }
}

// bias + ELU, in place on the embeddings region of d_out
__global__ void k_fin1(float* __restrict__ emb, const float* __restrict__ b1) {
    int t = blockIdx.x * blockDim.x + threadIdx.x;
    if (t >= N_NODES * 128) return;
    float v = emb[t] + b1[t & 127];
    emb[t] = v > 0.f ? v : expm1f(v);
}

// ---------------- layer 2 GEMM: h2 = emb @ W2 (128 -> 16), 1 head -----------
// block = 256 threads handles 16 nodes; thread (sub = t>>4, j = t&15).
__global__ __launch_bounds__(256) void k_gemm2(
    const float* __restrict__ emb, const float* __restrict__ W,
    const float* __restrict__ asrc, const float* __restrict__ adst,
    float* __restrict__ h2, float* __restrict__ s2, float* __restrict__ d2) {
    __shared__ float xs[16][129];
    int n0 = blockIdx.x * 16;
    int t = threadIdx.x;
#pragma unroll
    for (int i = 0; i < 8; ++i) {
        int idx = t + i * 256;
        xs[idx >> 7][idx & 127] = emb[(long)n0 * 128 + idx];
    }
    __syncthreads();
    int j = t & 15, sub = t >> 4;
    float acc = 0.f;
    for (int k = 0; k < 128; ++k) acc = fmaf(xs[sub][k], W[k * 16 + j], acc);
    int n = n0 + sub;
    h2[(long)n * 16 + j] = acc;
    float ps = acc * asrc[j], pd = acc * adst[j];
#pragma unroll
    for (int off = 8; off; off >>= 1) {
        ps += __shfl_down(ps, off, 16);
        pd += __shfl_down(pd, off, 16);
    }
    if (j == 0) { s2[n] = ps; d2[n] = pd; }
}

// ---------------- layer 2 edge kernels (1 head) -----------------------------
__global__ void k_emax2(const int* __restrict__ src, const int* __restrict__ dst,
                        const float* __restrict__ s2, const float* __restrict__ d2,
                        float* __restrict__ emax) {
    int eid = blockIdx.x * blockDim.x + threadIdx.x;
    if (eid >= ETOT) return;
    int s, d;
    if (eid < E_EDGES) { s = src[eid]; d = dst[eid]; } else { s = d = eid - E_EDGES; }
    float e = lrelu(s2[s] + d2[d]);
    atomicMaxF(&emax[d], e);
}

__global__ void k_esum2(const int* __restrict__ src, const int* __restrict__ dst,
                        const float* __restrict__ s2, const float* __restrict__ d2,
                        const float* __restrict__ emax, float* __restrict__ den) {
    int eid = blockIdx.x * blockDim.x + threadIdx.x;
    if (eid >= ETOT) return;
    int s, d;
    if (eid < E_EDGES) { s = src[eid]; d = dst[eid]; } else { s = d = eid - E_EDGES; }
    float e = lrelu(s2[s] + d2[d]);
    atomicAdd(&den[d], __expf(e - emax[d]));
}

__global__ void k_eagg2(const int* __restrict__ src, const int* __restrict__ dst,
                        const float* __restrict__ s2, const float* __restrict__ d2,
                        const float* __restrict__ emax, const float* __restrict__ den,
                        const float* __restrict__ h2, float* __restrict__ agg) {
    int eid = blockIdx.x * blockDim.x + threadIdx.x;
    if (eid >= ETOT) return;
    int s, d;
    if (eid < E_EDGES) { s = src[eid]; d = dst[eid]; } else { s = d = eid - E_EDGES; }
    float e = lrelu(s2[s] + d2[d]);
    float alpha = __expf(e - emax[d]) / (den[d] + 1e-16f);
    const float4* hr = (const float4*)(h2 + (long)s * 16);
    float* ar = agg + (long)d * 16;
#pragma unroll
    for (int i = 0; i < 4; ++i) {
        float4 v = hr[i];
        atomicAdd(ar + 4 * i + 0, alpha * v.x);
        atomicAdd(ar + 4 * i + 1, alpha * v.y);
        atomicAdd(ar + 4 * i + 2, alpha * v.z);
        atomicAdd(ar + 4 * i + 3, alpha * v.w);
    }
}

// bias + row-wise log_softmax, in place on the logits region of d_out
__global__ __launch_bounds__(256) void k_logsm(float* __restrict__ logits,
                                               const float* __restrict__ b2) {
    int t = threadIdx.x;
    int n = blockIdx.x * 16 + (t >> 4);
    int c = t & 15;
    float v = logits[n * 16 + c] + b2[c];
    float m = v;
#pragma unroll
    for (int off = 8; off; off >>= 1) m = fmaxf(m, __shfl_xor(m, off, 16));
    float s = __expf(v - m);
#pragma unroll
    for (int off = 8; off; off >>= 1) s += __shfl_xor(s, off, 16);
    logits[n * 16 + c] = v - m - logf(s);
}

extern "C" void kernel_launch(void* const* d_in, const int* in_sizes, int n_in,
                              void* d_out, int out_size, void* d_ws, size_t ws_size,
                              hipStream_t stream) {
    const float* x   = (const float*)d_in[0];
    const int*   ei  = (const int*)d_in[1];
    const float* W1  = (const float*)d_in[2];
    const float* as1 = (const float*)d_in[3];
    const float* ad1 = (const float*)d_in[4];
    const float* b1  = (const float*)d_in[5];
    const float* W2  = (const float*)d_in[6];
    const float* as2 = (const float*)d_in[7];
    const float* ad2 = (const float*)d_in[8];
    const float* b2  = (const float*)d_in[9];

    float* out    = (float*)d_out;
    float* logits = out;                          // [N,16]
    float* emb    = out + (size_t)N_NODES * 16;   // [N,128]

    float* ws    = (float*)d_ws;
    float* h1    = ws;                              // N*128
    float* s1    = h1 + (size_t)N_NODES * 128;      // N*8
    float* d1    = s1 + (size_t)N_NODES * 8;
    float* emax1 = d1 + (size_t)N_NODES * 8;
    float* den1  = emax1 + (size_t)N_NODES * 8;
    float* h2    = den1 + (size_t)N_NODES * 8;      // N*16
    float* s2    = h2 + (size_t)N_NODES * 16;       // N
    float* d2v   = s2 + (size_t)N_NODES;
    float* emax2 = d2v + (size_t)N_NODES;
    float* den2  = emax2 + (size_t)N_NODES;

    const int* srcp = ei;
    const int* dstp = ei + E_EDGES;

    // zero accumulators (d_out doubles as agg buffers), -inf pattern for emax
    hipMemsetAsync(d_out, 0, (size_t)out_size * sizeof(float), stream);
    hipMemsetAsync(emax1, 0xFF, (size_t)N_NODES * 8 * sizeof(float), stream);
    hipMemsetAsync(den1, 0, (size_t)N_NODES * 8 * sizeof(float), stream);
    hipMemsetAsync(emax2, 0xFF, (size_t)N_NODES * sizeof(float), stream);
    hipMemsetAsync(den2, 0, (size_t)N_NODES * sizeof(float), stream);

    k_gemm1<<<N_NODES / 8, 256, 0, stream>>>(x, W1, as1, ad1, h1, s1, d1);

    int eh = ETOT * HEADS;
    int gEH = (eh + 255) / 256;
    k_emax1<<<gEH, 256, 0, stream>>>(srcp, dstp, s1, d1, emax1);
    k_esum1<<<gEH, 256, 0, stream>>>(srcp, dstp, s1, d1, emax1, den1);
    k_eagg1<<<gEH, 256, 0, stream>>>(srcp, dstp, s1, d1, emax1, den1, h1, emb);
    k_fin1<<<(N_NODES * 128 + 255) / 256, 256, 0, stream>>>(emb, b1);

    k_gemm2<<<N_NODES / 16, 256, 0, stream>>>(emb, W2, as2, ad2, h2, s2, d2v);

    int gE = (ETOT + 255) / 256;
    k_emax2<<<gE, 256, 0, stream>>>(srcp, dstp, s2, d2v, emax2);
    k_esum2<<<gE, 256, 0, stream>>>(srcp, dstp, s2, d2v, emax2, den2);
    k_eagg2<<<gE, 256, 0, stream>>>(srcp, dstp, s2, d2v, emax2, den2, h2, logits);

    k_logsm<<<N_NODES / 16, 256, 0, stream>>>(logits, b2);
}

// Round 2
// 980.565 us; speedup vs baseline: 14.3750x; 14.3750x over previous
//
#include <hip/hip_runtime.h>
#include <math.h>

#define N_NODES 100000
#define E_EDGES 1600000
#define ETOT    (E_EDGES + N_NODES)
#define HEADS   8
#define NEG     0.2f

__device__ inline float lrelu(float x) { return x > 0.f ? x : NEG * x; }

// ---------------- CSR build --------------------------------------------------
__global__ void k_hist(const int* __restrict__ dst, int* __restrict__ deg) {
    int e = blockIdx.x * blockDim.x + threadIdx.x;
    if (e >= ETOT) return;
    int d = (e < E_EDGES) ? dst[e] : e - E_EDGES;   // self-loops appended
    atomicAdd(&deg[d], 1);
}

// single-block exclusive scan of deg[N] -> off[N+1], duplicate into cur[N]
__global__ __launch_bounds__(1024) void k_scan(const int* __restrict__ deg,
                                               int* __restrict__ off,
                                               int* __restrict__ cur) {
    __shared__ int sums[1024];
    const int CH = (N_NODES + 1023) / 1024;
    int t = threadIdx.x;
    int lo = t * CH, hi = min(lo + CH, N_NODES);
    int s = 0;
    for (int i = lo; i < hi; ++i) s += deg[i];
    sums[t] = s;
    __syncthreads();
    for (int ofs = 1; ofs < 1024; ofs <<= 1) {
        int u = (t >= ofs) ? sums[t - ofs] : 0;
        __syncthreads();
        sums[t] += u;
        __syncthreads();
    }
    int run = sums[t] - s;          // exclusive prefix
    for (int i = lo; i < hi; ++i) { off[i] = run; cur[i] = run; run += deg[i]; }
    if (t == 1023) off[N_NODES] = run;   // == ETOT
}

__global__ void k_scatter(const int* __restrict__ src, const int* __restrict__ dst,
                          int* __restrict__ cur, int* __restrict__ csr) {
    int e = blockIdx.x * blockDim.x + threadIdx.x;
    if (e >= ETOT) return;
    int s, d;
    if (e < E_EDGES) { s = src[e]; d = dst[e]; } else { s = d = e - E_EDGES; }
    int slot = atomicAdd(&cur[d], 1);
    csr[slot] = s;
}

// ---------------- layer 1 GEMM: h1 = x @ W1, plus s1/d1 attention halves ----
__global__ __launch_bounds__(256) void k_gemm1(
    const float* __restrict__ x, const float* __restrict__ W,
    const float* __restrict__ asrc, const float* __restrict__ adst,
    float* __restrict__ h1, float* __restrict__ s1, float* __restrict__ d1) {
    __shared__ float xs[8][128];
    int n0 = blockIdx.x * 8;
    int t = threadIdx.x;
#pragma unroll
    for (int i = 0; i < 4; ++i) {
        int idx = t + i * 256;
        xs[idx >> 7][idx & 127] = x[(long)n0 * 128 + idx];
    }
    __syncthreads();
    int j = t & 127, sg = t >> 7;
    float a0 = 0.f, a1 = 0.f, a2 = 0.f, a3 = 0.f;
    for (int k = 0; k < 128; ++k) {
        float w = W[k * 128 + j];
        a0 = fmaf(xs[sg + 0][k], w, a0);
        a1 = fmaf(xs[sg + 2][k], w, a1);
        a2 = fmaf(xs[sg + 4][k], w, a2);
        a3 = fmaf(xs[sg + 6][k], w, a3);
    }
    float as = asrc[j], ad = adst[j];
    float accs[4] = {a0, a1, a2, a3};
#pragma unroll
    for (int i = 0; i < 4; ++i) {
        int n = n0 + sg + 2 * i;
        h1[(long)n * 128 + j] = accs[i];
        float ps = accs[i] * as, pd = accs[i] * ad;
#pragma unroll
        for (int off = 8; off; off >>= 1) {
            ps += __shfl_down(ps, off, 16);
            pd += __shfl_down(pd, off, 16);
        }
        if ((j & 15) == 0) {
            s1[n * 8 + (j >> 4)] = ps;
            d1[n * 8 + (j >> 4)] = pd;
        }
    }
}

// ---------------- layer 1 attention: online softmax stats per (node, head) --
// block = 256 = 4 nodes x 64 lanes; lane l: h = l&7, i = l>>3 (8 slots/head)
__global__ __launch_bounds__(256) void k_att1(
    const int* __restrict__ off, const int* __restrict__ csr,
    const float* __restrict__ s1, const float* __restrict__ d1,
    float* __restrict__ emax, float* __restrict__ den) {
    int t = threadIdx.x;
    int node = blockIdx.x * 4 + (t >> 6);
    if (node >= N_NODES) return;
    int l = t & 63, h = l & 7, i = l >> 3;
    int lo = off[node], hi = off[node + 1];
    float dv = d1[node * 8 + h];
    float m = -1e30f, ssum = 0.f;
    for (int idx = lo + i; idx < hi; idx += 8) {
        int s = csr[idx];
        float e = lrelu(s1[s * 8 + h] + dv);
        float mn = fmaxf(m, e);
        ssum = ssum * __expf(m - mn) + __expf(e - mn);
        m = mn;
    }
#pragma unroll
    for (int ofs = 8; ofs < 64; ofs <<= 1) {
        float mo = __shfl_xor(m, ofs, 64);
        float so = __shfl_xor(ssum, ofs, 64);
        float mn = fmaxf(m, mo);
        ssum = ssum * __expf(m - mn) + so * __expf(mo - mn);
        m = mn;
    }
    if (i == 0) { emax[node * 8 + h] = m; den[node * 8 + h] = ssum; }
}

// ---------------- layer 1 aggregate (gather) + bias + ELU -------------------
// block = 256 = 2 nodes x 128 channels
__global__ __launch_bounds__(256) void k_agg1(
    const int* __restrict__ off, const int* __restrict__ csr,
    const float* __restrict__ s1, const float* __restrict__ d1,
    const float* __restrict__ emax, const float* __restrict__ den,
    const float* __restrict__ h1, const float* __restrict__ b1,
    float* __restrict__ emb) {
    int t = threadIdx.x;
    int node = blockIdx.x * 2 + (t >> 7);
    if (node >= N_NODES) return;
    int c = t & 127, h = c >> 4;
    int lo = off[node], hi = off[node + 1];
    float dv = d1[node * 8 + h];
    float mx = emax[node * 8 + h];
    float rden = 1.f / (den[node * 8 + h] + 1e-16f);
    float acc = 0.f;
    for (int idx = lo; idx < hi; ++idx) {
        int s = csr[idx];
        float e = lrelu(s1[s * 8 + h] + dv);
        float alpha = __expf(e - mx) * rden;
        acc = fmaf(alpha, h1[(long)s * 128 + c], acc);
    }
    float v = acc + b1[c];
    emb[(long)node * 128 + c] = v > 0.f ? v : expm1f(v);
}

// ---------------- layer 2 GEMM: h2 = emb @ W2 (128 -> 16), 1 head -----------
__global__ __launch_bounds__(256) void k_gemm2(
    const float* __restrict__ emb, const float* __restrict__ W,
    const float* __restrict__ asrc, const float* __restrict__ adst,
    float* __restrict__ h2, float* __restrict__ s2, float* __restrict__ d2) {
    __shared__ float xs[16][129];
    int n0 = blockIdx.x * 16;
    int t = threadIdx.x;
#pragma unroll
    for (int i = 0; i < 8; ++i) {
        int idx = t + i * 256;
        xs[idx >> 7][idx & 127] = emb[(long)n0 * 128 + idx];
    }
    __syncthreads();
    int j = t & 15, sub = t >> 4;
    float acc = 0.f;
    for (int k = 0; k < 128; ++k) acc = fmaf(xs[sub][k], W[k * 16 + j], acc);
    int n = n0 + sub;
    h2[(long)n * 16 + j] = acc;
    float ps = acc * asrc[j], pd = acc * adst[j];
#pragma unroll
    for (int off = 8; off; off >>= 1) {
        ps += __shfl_down(ps, off, 16);
        pd += __shfl_down(pd, off, 16);
    }
    if (j == 0) { s2[n] = ps; d2[n] = pd; }
}

// ---------------- layer 2 attention (1 head): 16 lanes per node -------------
__global__ __launch_bounds__(256) void k_att2(
    const int* __restrict__ off, const int* __restrict__ csr,
    const float* __restrict__ s2, const float* __restrict__ d2,
    float* __restrict__ emax, float* __restrict__ den) {
    int t = threadIdx.x;
    int node = blockIdx.x * 16 + (t >> 4);
    int i = t & 15;
    int lo = off[node], hi = off[node + 1];
    float dv = d2[node];
    float m = -1e30f, ssum = 0.f;
    for (int idx = lo + i; idx < hi; idx += 16) {
        int s = csr[idx];
        float e = lrelu(s2[s] + dv);
        float mn = fmaxf(m, e);
        ssum = ssum * __expf(m - mn) + __expf(e - mn);
        m = mn;
    }
#pragma unroll
    for (int ofs = 1; ofs < 16; ofs <<= 1) {
        float mo = __shfl_xor(m, ofs, 16);
        float so = __shfl_xor(ssum, ofs, 16);
        float mn = fmaxf(m, mo);
        ssum = ssum * __expf(m - mn) + so * __expf(mo - mn);
        m = mn;
    }
    if (i == 0) { emax[node] = m; den[node] = ssum; }
}

// ---------------- layer 2 aggregate + bias + log_softmax --------------------
// block = 256 = 16 nodes x 16 channels
__global__ __launch_bounds__(256) void k_agg2(
    const int* __restrict__ off, const int* __restrict__ csr,
    const float* __restrict__ s2, const float* __restrict__ d2,
    const float* __restrict__ emax, const float* __restrict__ den,
    const float* __restrict__ h2, const float* __restrict__ b2,
    float* __restrict__ logits) {
    int t = threadIdx.x;
    int node = blockIdx.x * 16 + (t >> 4);
    int c = t & 15;
    int lo = off[node], hi = off[node + 1];
    float dv = d2[node];
    float mx = emax[node];
    float rden = 1.f / (den[node] + 1e-16f);
    float acc = 0.f;
    for (int idx = lo; idx < hi; ++idx) {
        int s = csr[idx];
        float alpha = __expf(lrelu(s2[s] + dv) - mx) * rden;
        acc = fmaf(alpha, h2[s * 16 + c], acc);
    }
    float v = acc + b2[c];
    float m = v;
#pragma unroll
    for (int ofs = 8; ofs; ofs >>= 1) m = fmaxf(m, __shfl_xor(m, ofs, 16));
    float sm = __expf(v - m);
#pragma unroll
    for (int ofs = 8; ofs; ofs >>= 1) sm += __shfl_xor(sm, ofs, 16);
    logits[node * 16 + c] = v - m - logf(sm);
}

extern "C" void kernel_launch(void* const* d_in, const int* in_sizes, int n_in,
                              void* d_out, int out_size, void* d_ws, size_t ws_size,
                              hipStream_t stream) {
    const float* x   = (const float*)d_in[0];
    const int*   ei  = (const int*)d_in[1];
    const float* W1  = (const float*)d_in[2];
    const float* as1 = (const float*)d_in[3];
    const float* ad1 = (const float*)d_in[4];
    const float* b1  = (const float*)d_in[5];
    const float* W2  = (const float*)d_in[6];
    const float* as2 = (const float*)d_in[7];
    const float* ad2 = (const float*)d_in[8];
    const float* b2  = (const float*)d_in[9];

    float* out    = (float*)d_out;
    float* logits = out;                          // [N,16]
    float* emb    = out + (size_t)N_NODES * 16;   // [N,128]

    float* ws    = (float*)d_ws;
    float* h1    = ws;                              // N*128
    float* s1    = h1 + (size_t)N_NODES * 128;      // N*8
    float* d1    = s1 + (size_t)N_NODES * 8;
    float* emax1 = d1 + (size_t)N_NODES * 8;
    float* den1  = emax1 + (size_t)N_NODES * 8;
    float* h2    = den1 + (size_t)N_NODES * 8;      // N*16
    float* s2    = h2 + (size_t)N_NODES * 16;       // N
    float* d2v   = s2 + (size_t)N_NODES;
    float* emax2 = d2v + (size_t)N_NODES;
    float* den2  = emax2 + (size_t)N_NODES;
    int*   deg   = (int*)(den2 + (size_t)N_NODES);  // N
    int*   offs  = deg + N_NODES;                   // N+1
    int*   cur   = offs + N_NODES + 1;              // N
    int*   csr   = cur + N_NODES;                   // ETOT

    const int* srcp = ei;
    const int* dstp = ei + E_EDGES;

    hipMemsetAsync(deg, 0, (size_t)N_NODES * sizeof(int), stream);

    int gE = (ETOT + 255) / 256;
    k_hist<<<gE, 256, 0, stream>>>(dstp, deg);
    k_scan<<<1, 1024, 0, stream>>>(deg, offs, cur);
    k_scatter<<<gE, 256, 0, stream>>>(srcp, dstp, cur, csr);

    k_gemm1<<<N_NODES / 8, 256, 0, stream>>>(x, W1, as1, ad1, h1, s1, d1);
    k_att1<<<N_NODES / 4, 256, 0, stream>>>(offs, csr, s1, d1, emax1, den1);
    k_agg1<<<N_NODES / 2, 256, 0, stream>>>(offs, csr, s1, d1, emax1, den1,
                                            h1, b1, emb);

    k_gemm2<<<N_NODES / 16, 256, 0, stream>>>(emb, W2, as2, ad2, h2, s2, d2v);
    k_att2<<<N_NODES / 16, 256, 0, stream>>>(offs, csr, s2, d2v, emax2, den2);
    k_agg2<<<N_NODES / 16, 256, 0, stream>>>(offs, csr, s2, d2v, emax2, den2,
                                             h2, b2, logits);
}

// Round 3
// 803.129 us; speedup vs baseline: 17.5509x; 1.2209x over previous
//
#include <hip/hip_runtime.h>
#include <hip/hip_bf16.h>
#include <math.h>

#define N_NODES 100000
#define E_EDGES 1600000
#define ETOT    (E_EDGES + N_NODES)
#define NEG     0.2f

__device__ inline float lrelu(float x) { return x > 0.f ? x : NEG * x; }
__device__ inline float bflo(unsigned int b) { return __uint_as_float(b << 16); }
__device__ inline float bfhi(unsigned int b) { return __uint_as_float(b & 0xFFFF0000u); }

// ---------------- CSR build --------------------------------------------------
__global__ void k_hist(const int* __restrict__ dst, int* __restrict__ deg) {
    int e = blockIdx.x * blockDim.x + threadIdx.x;
    if (e >= ETOT) return;
    int d = (e < E_EDGES) ? dst[e] : e - E_EDGES;   // self-loops appended
    atomicAdd(&deg[d], 1);
}

__global__ __launch_bounds__(1024) void k_scan(const int* __restrict__ deg,
                                               int* __restrict__ off,
                                               int* __restrict__ cur) {
    __shared__ int sums[1024];
    const int CH = (N_NODES + 1023) / 1024;
    int t = threadIdx.x;
    int lo = t * CH, hi = min(lo + CH, N_NODES);
    int s = 0;
    for (int i = lo; i < hi; ++i) s += deg[i];
    sums[t] = s;
    __syncthreads();
    for (int ofs = 1; ofs < 1024; ofs <<= 1) {
        int u = (t >= ofs) ? sums[t - ofs] : 0;
        __syncthreads();
        sums[t] += u;
        __syncthreads();
    }
    int run = sums[t] - s;
    for (int i = lo; i < hi; ++i) { off[i] = run; cur[i] = run; run += deg[i]; }
    if (t == 1023) off[N_NODES] = run;
}

__global__ void k_scatter(const int* __restrict__ src, const int* __restrict__ dst,
                          int* __restrict__ cur, int* __restrict__ csr) {
    int e = blockIdx.x * blockDim.x + threadIdx.x;
    if (e >= ETOT) return;
    int s, d;
    if (e < E_EDGES) { s = src[e]; d = dst[e]; } else { s = d = e - E_EDGES; }
    int slot = atomicAdd(&cur[d], 1);
    csr[slot] = s;
}

// ---------------- layer 1 GEMM: h1(bf16) = x @ W1, plus s1/d1 ---------------
__global__ __launch_bounds__(256) void k_gemm1(
    const float* __restrict__ x, const float* __restrict__ W,
    const float* __restrict__ asrc, const float* __restrict__ adst,
    __hip_bfloat16* __restrict__ h1b, float* __restrict__ s1,
    float* __restrict__ d1) {
    __shared__ float xs[8][128];
    int n0 = blockIdx.x * 8;
    int t = threadIdx.x;
#pragma unroll
    for (int i = 0; i < 4; ++i) {
        int idx = t + i * 256;
        xs[idx >> 7][idx & 127] = x[(long)n0 * 128 + idx];
    }
    __syncthreads();
    int j = t & 127, sg = t >> 7;
    float a0 = 0.f, a1 = 0.f, a2 = 0.f, a3 = 0.f;
    for (int k = 0; k < 128; ++k) {
        float w = W[k * 128 + j];
        a0 = fmaf(xs[sg + 0][k], w, a0);
        a1 = fmaf(xs[sg + 2][k], w, a1);
        a2 = fmaf(xs[sg + 4][k], w, a2);
        a3 = fmaf(xs[sg + 6][k], w, a3);
    }
    float as = asrc[j], ad = adst[j];
    float accs[4] = {a0, a1, a2, a3};
#pragma unroll
    for (int i = 0; i < 4; ++i) {
        int n = n0 + sg + 2 * i;
        h1b[(long)n * 128 + j] = __float2bfloat16(accs[i]);
        float ps = accs[i] * as, pd = accs[i] * ad;
#pragma unroll
        for (int off = 8; off; off >>= 1) {
            ps += __shfl_down(ps, off, 16);
            pd += __shfl_down(pd, off, 16);
        }
        if ((j & 15) == 0) {
            s1[n * 8 + (j >> 4)] = ps;
            d1[n * 8 + (j >> 4)] = pd;
        }
    }
}

// ---------------- layer 1 fused attention + aggregate -----------------------
// block 256 = 2 nodes x 2 waves x 64 lanes.
__global__ __launch_bounds__(256) void k_l1(
    const int* __restrict__ off, const int* __restrict__ csr,
    const float* __restrict__ s1, const float* __restrict__ d1,
    const unsigned int* __restrict__ h1w, const float* __restrict__ b1,
    float* __restrict__ emb) {
    __shared__ float st[2][2][8][2];    // [node][wave][head][{m,sum}]
    __shared__ float pacc[2][64][2];    // wave-1 partial accumulators
    int t = threadIdx.x;
    int nib = t >> 7;
    int w = (t >> 6) & 1;
    int l = t & 63;
    int node = blockIdx.x * 2 + nib;
    int lo = off[node], hi = off[node + 1];

    // phase A: online softmax stats; 16 slots (2 waves x 8), head h = l&7
    int h = l & 7, i = l >> 3;
    float dv = d1[node * 8 + h];
    float m = -1e30f, ss = 0.f;
    for (int idx = lo + (w * 8 + i); idx < hi; idx += 16) {
        int s = csr[idx];
        float e = lrelu(s1[s * 8 + h] + dv);
        float mn = fmaxf(m, e);
        ss = ss * __expf(m - mn) + __expf(e - mn);
        m = mn;
    }
#pragma unroll
    for (int ofs = 8; ofs < 64; ofs <<= 1) {
        float mo = __shfl_xor(m, ofs, 64);
        float so = __shfl_xor(ss, ofs, 64);
        float mn = fmaxf(m, mo);
        ss = ss * __expf(m - mn) + so * __expf(mo - mn);
        m = mn;
    }
    if (i == 0) { st[nib][w][h][0] = m; st[nib][w][h][1] = ss; }
    __syncthreads();

    // combine the two waves' stats for this lane's channel-pair head
    int hh = l >> 3;                    // head of channels {2l, 2l+1}
    float m0 = st[nib][0][hh][0], q0 = st[nib][0][hh][1];
    float m1 = st[nib][1][hh][0], q1 = st[nib][1][hh][1];
    float mx = fmaxf(m0, m1);
    float den = q0 * __expf(m0 - mx) + q1 * __expf(m1 - mx);
    float rden = 1.f / (den + 1e-16f);
    float dvh = d1[node * 8 + hh];

    // phase B: gather-aggregate, 2-wave edge split, 1-deep prefetch
    float ax = 0.f, ay = 0.f;
    int idx = lo + w;
    int sc = 0; unsigned int bv = 0; float sv = 0.f;
    if (idx < hi) {
        sc = csr[idx];
        bv = h1w[(size_t)sc * 64 + l];
        sv = s1[sc * 8 + hh];
    }
    while (idx < hi) {
        int nidx = idx + 2;
        int sn = 0; unsigned int bn = 0; float svn = 0.f;
        if (nidx < hi) {
            sn = csr[nidx];
            bn = h1w[(size_t)sn * 64 + l];
            svn = s1[sn * 8 + hh];
        }
        float alpha = __expf(lrelu(sv + dvh) - mx) * rden;
        ax = fmaf(alpha, bflo(bv), ax);
        ay = fmaf(alpha, bfhi(bv), ay);
        sc = sn; bv = bn; sv = svn; idx = nidx;
    }
    if (w == 1) { pacc[nib][l][0] = ax; pacc[nib][l][1] = ay; }
    __syncthreads();
    if (w == 0) {
        ax += pacc[nib][l][0];
        ay += pacc[nib][l][1];
        float v0 = ax + b1[2 * l], v1 = ay + b1[2 * l + 1];
        v0 = v0 > 0.f ? v0 : expm1f(v0);
        v1 = v1 > 0.f ? v1 : expm1f(v1);
        float2* ep = (float2*)(emb + (size_t)node * 128);
        ep[l] = make_float2(v0, v1);
    }
}

// ---------------- layer 2 GEMM: h2(bf16) = emb @ W2 (128->16), s2/d2 --------
__global__ __launch_bounds__(256) void k_gemm2(
    const float* __restrict__ emb, const float* __restrict__ W,
    const float* __restrict__ asrc, const float* __restrict__ adst,
    __hip_bfloat16* __restrict__ h2b, float* __restrict__ s2,
    float* __restrict__ d2) {
    __shared__ float xs[16][129];
    int n0 = blockIdx.x * 16;
    int t = threadIdx.x;
#pragma unroll
    for (int i = 0; i < 8; ++i) {
        int idx = t + i * 256;
        xs[idx >> 7][idx & 127] = emb[(long)n0 * 128 + idx];
    }
    __syncthreads();
    int j = t & 15, sub = t >> 4;
    float acc = 0.f;
    for (int k = 0; k < 128; ++k) acc = fmaf(xs[sub][k], W[k * 16 + j], acc);
    int n = n0 + sub;
    h2b[(long)n * 16 + j] = __float2bfloat16(acc);
    float ps = acc * asrc[j], pd = acc * adst[j];
#pragma unroll
    for (int off = 8; off; off >>= 1) {
        ps += __shfl_down(ps, off, 16);
        pd += __shfl_down(pd, off, 16);
    }
    if (j == 0) { s2[n] = ps; d2[n] = pd; }
}

// ---------------- layer 2 fused attention + aggregate + log_softmax ---------
// block 256 = 4 nodes x 64 lanes (wave per node).
__global__ __launch_bounds__(256) void k_l2(
    const int* __restrict__ off, const int* __restrict__ csr,
    const float* __restrict__ s2, const float* __restrict__ d2,
    const unsigned int* __restrict__ h2w, const float* __restrict__ b2,
    float* __restrict__ logits) {
    int t = threadIdx.x;
    int node = blockIdx.x * 4 + (t >> 6);
    int l = t & 63;
    int lo = off[node], hi = off[node + 1];
    float dv = d2[node];

    // phase A: online stats over all edges, 64 slots
    float m = -1e30f, ss = 0.f;
    for (int idx = lo + l; idx < hi; idx += 64) {
        float e = lrelu(s2[csr[idx]] + dv);
        float mn = fmaxf(m, e);
        ss = ss * __expf(m - mn) + __expf(e - mn);
        m = mn;
    }
#pragma unroll
    for (int ofs = 1; ofs < 64; ofs <<= 1) {
        float mo = __shfl_xor(m, ofs, 64);
        float so = __shfl_xor(ss, ofs, 64);
        float mn = fmaxf(m, mo);
        ss = ss * __expf(m - mn) + so * __expf(mo - mn);
        m = mn;
    }
    float rden = 1.f / (ss + 1e-16f);

    // phase B: 8 edge-groups x 8 channel-pair lanes
    int g = l >> 3, p = l & 7;
    float ax = 0.f, ay = 0.f;
    for (int idx = lo + g; idx < hi; idx += 8) {
        int s = csr[idx];
        float alpha = __expf(lrelu(s2[s] + dv) - m) * rden;
        unsigned int bv = h2w[(size_t)s * 8 + p];
        ax = fmaf(alpha, bflo(bv), ax);
        ay = fmaf(alpha, bfhi(bv), ay);
    }
#pragma unroll
    for (int ofs = 8; ofs < 64; ofs <<= 1) {
        ax += __shfl_xor(ax, ofs, 64);
        ay += __shfl_xor(ay, ofs, 64);
    }
    float v0 = ax + b2[2 * p], v1 = ay + b2[2 * p + 1];
    float mm = fmaxf(v0, v1);
#pragma unroll
    for (int ofs = 1; ofs < 8; ofs <<= 1) mm = fmaxf(mm, __shfl_xor(mm, ofs, 8));
    float sm = __expf(v0 - mm) + __expf(v1 - mm);
#pragma unroll
    for (int ofs = 1; ofs < 8; ofs <<= 1) sm += __shfl_xor(sm, ofs, 8);
    if (g == 0) {
        float ls = logf(sm);
        logits[node * 16 + 2 * p]     = v0 - mm - ls;
        logits[node * 16 + 2 * p + 1] = v1 - mm - ls;
    }
}

extern "C" void kernel_launch(void* const* d_in, const int* in_sizes, int n_in,
                              void* d_out, int out_size, void* d_ws, size_t ws_size,
                              hipStream_t stream) {
    const float* x   = (const float*)d_in[0];
    const int*   ei  = (const int*)d_in[1];
    const float* W1  = (const float*)d_in[2];
    const float* as1 = (const float*)d_in[3];
    const float* ad1 = (const float*)d_in[4];
    const float* b1  = (const float*)d_in[5];
    const float* W2  = (const float*)d_in[6];
    const float* as2 = (const float*)d_in[7];
    const float* ad2 = (const float*)d_in[8];
    const float* b2  = (const float*)d_in[9];

    float* out    = (float*)d_out;
    float* logits = out;                          // [N,16]
    float* emb    = out + (size_t)N_NODES * 16;   // [N,128]

    float* ws    = (float*)d_ws;
    unsigned int* h1w = (unsigned int*)ws;                    // N*64 words (bf16 x2)
    float* s1    = (float*)(h1w + (size_t)N_NODES * 64);      // N*8
    float* d1    = s1 + (size_t)N_NODES * 8;
    unsigned int* h2w = (unsigned int*)(d1 + (size_t)N_NODES * 8); // N*8 words
    float* s2    = (float*)(h2w + (size_t)N_NODES * 8);       // N
    float* d2v   = s2 + (size_t)N_NODES;
    int*   deg   = (int*)(d2v + (size_t)N_NODES);             // N
    int*   offs  = deg + N_NODES;                             // N+1
    int*   cur   = offs + N_NODES + 1;                        // N
    int*   csr   = cur + N_NODES;                             // ETOT

    const int* srcp = ei;
    const int* dstp = ei + E_EDGES;

    hipMemsetAsync(deg, 0, (size_t)N_NODES * sizeof(int), stream);

    int gE = (ETOT + 255) / 256;
    k_hist<<<gE, 256, 0, stream>>>(dstp, deg);
    k_scan<<<1, 1024, 0, stream>>>(deg, offs, cur);
    k_scatter<<<gE, 256, 0, stream>>>(srcp, dstp, cur, csr);

    k_gemm1<<<N_NODES / 8, 256, 0, stream>>>(x, W1, as1, ad1,
                                             (__hip_bfloat16*)h1w, s1, d1);
    k_l1<<<N_NODES / 2, 256, 0, stream>>>(offs, csr, s1, d1, h1w, b1, emb);

    k_gemm2<<<N_NODES / 16, 256, 0, stream>>>(emb, W2, as2, ad2,
                                              (__hip_bfloat16*)h2w, s2, d2v);
    k_l2<<<N_NODES / 4, 256, 0, stream>>>(offs, csr, s2, d2v, h2w, b2, logits);
}

// Round 4
// 800.922 us; speedup vs baseline: 17.5992x; 1.0028x over previous
//
#include <hip/hip_runtime.h>
#include <hip/hip_bf16.h>
#include <math.h>

#define N_NODES 100000
#define E_EDGES 1600000
#define ETOT    (E_EDGES + N_NODES)
#define NEG     0.2f

__device__ inline float lrelu(float x) { return x > 0.f ? x : NEG * x; }
__device__ inline float bflo(unsigned int b) { return __uint_as_float(b << 16); }
__device__ inline float bfhi(unsigned int b) { return __uint_as_float(b & 0xFFFF0000u); }

// ---------------- CSR build --------------------------------------------------
__global__ void k_hist(const int* __restrict__ dst, int* __restrict__ deg) {
    int e = blockIdx.x * blockDim.x + threadIdx.x;
    if (e >= ETOT) return;
    int d = (e < E_EDGES) ? dst[e] : e - E_EDGES;   // self-loops appended
    atomicAdd(&deg[d], 1);
}

__global__ __launch_bounds__(1024) void k_scan(const int* __restrict__ deg,
                                               int* __restrict__ off,
                                               int* __restrict__ cur) {
    __shared__ int sums[1024];
    const int CH = (N_NODES + 1023) / 1024;
    int t = threadIdx.x;
    int lo = t * CH, hi = min(lo + CH, N_NODES);
    int s = 0;
    for (int i = lo; i < hi; ++i) s += deg[i];
    sums[t] = s;
    __syncthreads();
    for (int ofs = 1; ofs < 1024; ofs <<= 1) {
        int u = (t >= ofs) ? sums[t - ofs] : 0;
        __syncthreads();
        sums[t] += u;
        __syncthreads();
    }
    int run = sums[t] - s;
    for (int i = lo; i < hi; ++i) { off[i] = run; cur[i] = run; run += deg[i]; }
    if (t == 1023) off[N_NODES] = run;
}

__global__ void k_scatter(const int* __restrict__ src, const int* __restrict__ dst,
                          int* __restrict__ cur, int* __restrict__ csr) {
    int e = blockIdx.x * blockDim.x + threadIdx.x;
    if (e >= ETOT) return;
    int s, d;
    if (e < E_EDGES) { s = src[e]; d = dst[e]; } else { s = d = e - E_EDGES; }
    int slot = atomicAdd(&cur[d], 1);
    csr[slot] = s;
}

// ---------------- layer 1 GEMM: h1(bf16) = x @ W1, plus s1/d1 ---------------
__global__ __launch_bounds__(256) void k_gemm1(
    const float* __restrict__ x, const float* __restrict__ W,
    const float* __restrict__ asrc, const float* __restrict__ adst,
    __hip_bfloat16* __restrict__ h1b, float* __restrict__ s1,
    float* __restrict__ d1) {
    __shared__ float xs[8][128];
    int n0 = blockIdx.x * 8;
    int t = threadIdx.x;
#pragma unroll
    for (int i = 0; i < 4; ++i) {
        int idx = t + i * 256;
        xs[idx >> 7][idx & 127] = x[(long)n0 * 128 + idx];
    }
    __syncthreads();
    int j = t & 127, sg = t >> 7;
    float a0 = 0.f, a1 = 0.f, a2 = 0.f, a3 = 0.f;
    for (int k = 0; k < 128; ++k) {
        float w = W[k * 128 + j];
        a0 = fmaf(xs[sg + 0][k], w, a0);
        a1 = fmaf(xs[sg + 2][k], w, a1);
        a2 = fmaf(xs[sg + 4][k], w, a2);
        a3 = fmaf(xs[sg + 6][k], w, a3);
    }
    float as = asrc[j], ad = adst[j];
    float accs[4] = {a0, a1, a2, a3};
#pragma unroll
    for (int i = 0; i < 4; ++i) {
        int n = n0 + sg + 2 * i;
        h1b[(long)n * 128 + j] = __float2bfloat16(accs[i]);
        float ps = accs[i] * as, pd = accs[i] * ad;
#pragma unroll
        for (int off = 8; off; off >>= 1) {
            ps += __shfl_down(ps, off, 16);
            pd += __shfl_down(pd, off, 16);
        }
        if ((j & 15) == 0) {
            s1[n * 8 + (j >> 4)] = ps;
            d1[n * 8 + (j >> 4)] = pd;
        }
    }
}

// ---------------- layer 1 fused attention + aggregate -----------------------
// block 256 = 2 nodes x 2 waves x 64 lanes.
__global__ __launch_bounds__(256) void k_l1(
    const int* __restrict__ off, const int* __restrict__ csr,
    const float* __restrict__ s1, const float* __restrict__ d1,
    const unsigned int* __restrict__ h1w, const float* __restrict__ b1,
    float* __restrict__ emb) {
    __shared__ float st[2][2][8][2];    // [node][wave][head][{m,sum}]
    __shared__ float pacc[2][64][2];    // wave-1 partial accumulators
    int t = threadIdx.x;
    int nib = t >> 7;
    int w = (t >> 6) & 1;
    int l = t & 63;
    int node = blockIdx.x * 2 + nib;
    int lo = off[node], hi = off[node + 1];

    // phase A: online softmax stats; 16 slots (2 waves x 8), head h = l&7
    int h = l & 7, i = l >> 3;
    float dv = d1[node * 8 + h];
    float m = -1e30f, ss = 0.f;
    for (int idx = lo + (w * 8 + i); idx < hi; idx += 16) {
        int s = csr[idx];
        float e = lrelu(s1[s * 8 + h] + dv);
        float mn = fmaxf(m, e);
        ss = ss * __expf(m - mn) + __expf(e - mn);
        m = mn;
    }
#pragma unroll
    for (int ofs = 8; ofs < 64; ofs <<= 1) {
        float mo = __shfl_xor(m, ofs, 64);
        float so = __shfl_xor(ss, ofs, 64);
        float mn = fmaxf(m, mo);
        ss = ss * __expf(m - mn) + so * __expf(mo - mn);
        m = mn;
    }
    if (i == 0) { st[nib][w][h][0] = m; st[nib][w][h][1] = ss; }
    __syncthreads();

    // combine the two waves' stats for this lane's channel-pair head
    int hh = l >> 3;                    // head of channels {2l, 2l+1}
    float m0 = st[nib][0][hh][0], q0 = st[nib][0][hh][1];
    float m1 = st[nib][1][hh][0], q1 = st[nib][1][hh][1];
    float mx = fmaxf(m0, m1);
    float den = q0 * __expf(m0 - mx) + q1 * __expf(m1 - mx);
    float rden = 1.f / (den + 1e-16f);
    float dvh = d1[node * 8 + hh];

    // phase B: gather-aggregate, 2-wave edge split, 1-deep prefetch
    float ax = 0.f, ay = 0.f;
    int idx = lo + w;
    int sc = 0; unsigned int bv = 0; float sv = 0.f;
    if (idx < hi) {
        sc = csr[idx];
        bv = h1w[(size_t)sc * 64 + l];
        sv = s1[sc * 8 + hh];
    }
    while (idx < hi) {
        int nidx = idx + 2;
        int sn = 0; unsigned int bn = 0; float svn = 0.f;
        if (nidx < hi) {
            sn = csr[nidx];
            bn = h1w[(size_t)sn * 64 + l];
            svn = s1[sn * 8 + hh];
        }
        float alpha = __expf(lrelu(sv + dvh) - mx) * rden;
        ax = fmaf(alpha, bflo(bv), ax);
        ay = fmaf(alpha, bfhi(bv), ay);
        sc = sn; bv = bn; sv = svn; idx = nidx;
    }
    if (w == 1) { pacc[nib][l][0] = ax; pacc[nib][l][1] = ay; }
    __syncthreads();
    if (w == 0) {
        ax += pacc[nib][l][0];
        ay += pacc[nib][l][1];
        float v0 = ax + b1[2 * l], v1 = ay + b1[2 * l + 1];
        v0 = v0 > 0.f ? v0 : expm1f(v0);
        v1 = v1 > 0.f ? v1 : expm1f(v1);
        float2* ep = (float2*)(emb + (size_t)node * 128);
        ep[l] = make_float2(v0, v1);
    }
}

// ---------------- layer 2 GEMM: h2(bf16) = emb @ W2 (128->16), s2/d2 --------
__global__ __launch_bounds__(256) void k_gemm2(
    const float* __restrict__ emb, const float* __restrict__ W,
    const float* __restrict__ asrc, const float* __restrict__ adst,
    __hip_bfloat16* __restrict__ h2b, float* __restrict__ s2,
    float* __restrict__ d2) {
    __shared__ float xs[16][129];
    int n0 = blockIdx.x * 16;
    int t = threadIdx.x;
#pragma unroll
    for (int i = 0; i < 8; ++i) {
        int idx = t + i * 256;
        xs[idx >> 7][idx & 127] = emb[(long)n0 * 128 + idx];
    }
    __syncthreads();
    int j = t & 15, sub = t >> 4;
    float acc = 0.f;
    for (int k = 0; k < 128; ++k) acc = fmaf(xs[sub][k], W[k * 16 + j], acc);
    int n = n0 + sub;
    h2b[(long)n * 16 + j] = __float2bfloat16(acc);
    float ps = acc * asrc[j], pd = acc * adst[j];
#pragma unroll
    for (int off = 8; off; off >>= 1) {
        ps += __shfl_down(ps, off, 16);
        pd += __shfl_down(pd, off, 16);
    }
    if (j == 0) { s2[n] = ps; d2[n] = pd; }
}

// ---------------- layer 2 fused attention + aggregate + log_softmax ---------
// block 256 = 4 nodes x 64 lanes (wave per node).
__global__ __launch_bounds__(256) void k_l2(
    const int* __restrict__ off, const int* __restrict__ csr,
    const float* __restrict__ s2, const float* __restrict__ d2,
    const unsigned int* __restrict__ h2w, const float* __restrict__ b2,
    float* __restrict__ logits) {
    int t = threadIdx.x;
    int node = blockIdx.x * 4 + (t >> 6);
    int l = t & 63;
    int lo = off[node], hi = off[node + 1];
    float dv = d2[node];

    // phase A: online stats over all edges, 64 slots
    float m = -1e30f, ss = 0.f;
    for (int idx = lo + l; idx < hi; idx += 64) {
        float e = lrelu(s2[csr[idx]] + dv);
        float mn = fmaxf(m, e);
        ss = ss * __expf(m - mn) + __expf(e - mn);
        m = mn;
    }
#pragma unroll
    for (int ofs = 1; ofs < 64; ofs <<= 1) {
        float mo = __shfl_xor(m, ofs, 64);
        float so = __shfl_xor(ss, ofs, 64);
        float mn = fmaxf(m, mo);
        ss = ss * __expf(m - mn) + so * __expf(mo - mn);
        m = mn;
    }
    float rden = 1.f / (ss + 1e-16f);

    // phase B: 8 edge-groups x 8 channel-pair lanes
    int g = l >> 3, p = l & 7;
    float ax = 0.f, ay = 0.f;
    for (int idx = lo + g; idx < hi; idx += 8) {
        int s = csr[idx];
        float alpha = __expf(lrelu(s2[s] + dv) - m) * rden;
        unsigned int bv = h2w[(size_t)s * 8 + p];
        ax = fmaf(alpha, bflo(bv), ax);
        ay = fmaf(alpha, bfhi(bv), ay);
    }
#pragma unroll
    for (int ofs = 8; ofs < 64; ofs <<= 1) {
        ax += __shfl_xor(ax, ofs, 64);
        ay += __shfl_xor(ay, ofs, 64);
    }
    float v0 = ax + b2[2 * p], v1 = ay + b2[2 * p + 1];
    float mm = fmaxf(v0, v1);
#pragma unroll
    for (int ofs = 1; ofs < 8; ofs <<= 1) mm = fmaxf(mm, __shfl_xor(mm, ofs, 8));
    float sm = __expf(v0 - mm) + __expf(v1 - mm);
#pragma unroll
    for (int ofs = 1; ofs < 8; ofs <<= 1) sm += __shfl_xor(sm, ofs, 8);
    if (g == 0) {
        float ls = logf(sm);
        logits[node * 16 + 2 * p]     = v0 - mm - ls;
        logits[node * 16 + 2 * p + 1] = v1 - mm - ls;
    }
}

extern "C" void kernel_launch(void* const* d_in, const int* in_sizes, int n_in,
                              void* d_out, int out_size, void* d_ws, size_t ws_size,
                              hipStream_t stream) {
    const float* x   = (const float*)d_in[0];
    const int*   ei  = (const int*)d_in[1];
    const float* W1  = (const float*)d_in[2];
    const float* as1 = (const float*)d_in[3];
    const float* ad1 = (const float*)d_in[4];
    const float* b1  = (const float*)d_in[5];
    const float* W2  = (const float*)d_in[6];
    const float* as2 = (const float*)d_in[7];
    const float* ad2 = (const float*)d_in[8];
    const float* b2  = (const float*)d_in[9];

    float* out    = (float*)d_out;
    float* logits = out;                          // [N,16]
    float* emb    = out + (size_t)N_NODES * 16;   // [N,128]

    float* ws    = (float*)d_ws;
    unsigned int* h1w = (unsigned int*)ws;                    // N*64 words (bf16 x2)
    float* s1    = (float*)(h1w + (size_t)N_NODES * 64);      // N*8
    float* d1    = s1 + (size_t)N_NODES * 8;
    unsigned int* h2w = (unsigned int*)(d1 + (size_t)N_NODES * 8); // N*8 words
    float* s2    = (float*)(h2w + (size_t)N_NODES * 8);       // N
    float* d2v   = s2 + (size_t)N_NODES;
    int*   deg   = (int*)(d2v + (size_t)N_NODES);             // N
    int*   offs  = deg + N_NODES;                             // N+1
    int*   cur   = offs + N_NODES + 1;                        // N
    int*   csr   = cur + N_NODES;                             // ETOT

    const int* srcp = ei;
    const int* dstp = ei + E_EDGES;

    hipMemsetAsync(deg, 0, (size_t)N_NODES * sizeof(int), stream);

    int gE = (ETOT + 255) / 256;
    k_hist<<<gE, 256, 0, stream>>>(dstp, deg);
    k_scan<<<1, 1024, 0, stream>>>(deg, offs, cur);
    k_scatter<<<gE, 256, 0, stream>>>(srcp, dstp, cur, csr);

    k_gemm1<<<N_NODES / 8, 256, 0, stream>>>(x, W1, as1, ad1,
                                             (__hip_bfloat16*)h1w, s1, d1);
    k_l1<<<N_NODES / 2, 256, 0, stream>>>(offs, csr, s1, d1, h1w, b1, emb);

    k_gemm2<<<N_NODES / 16, 256, 0, stream>>>(emb, W2, as2, ad2,
                                              (__hip_bfloat16*)h2w, s2, d2v);
    k_l2<<<N_NODES / 4, 256, 0, stream>>>(offs, csr, s2, d2v, h2w, b2, logits);
}

// Round 5
// 584.043 us; speedup vs baseline: 24.1345x; 1.3713x over previous
//
#include <hip/hip_runtime.h>
#include <hip/hip_bf16.h>
#include <math.h>

#define N_NODES 100000
#define E_EDGES 1600000
#define ETOT    (E_EDGES + N_NODES)
#define NEG     0.2f

#define SCAN_CHUNK 1024
#define NBLK_SCAN  ((N_NODES + SCAN_CHUNK - 1) / SCAN_CHUNK)   // 98

__device__ inline float lrelu(float x) { return x > 0.f ? x : NEG * x; }
__device__ inline float bflo(unsigned int b) { return __uint_as_float(b << 16); }
__device__ inline float bfhi(unsigned int b) { return __uint_as_float(b & 0xFFFF0000u); }

// ---------------- CSR build --------------------------------------------------
__global__ void k_hist(const int* __restrict__ dst, int* __restrict__ deg) {
    int e = blockIdx.x * blockDim.x + threadIdx.x;
    if (e >= ETOT) return;
    int d = (e < E_EDGES) ? dst[e] : e - E_EDGES;   // self-loops appended
    atomicAdd(&deg[d], 1);
}

// scan phase A: per-block (1024-elem chunk) sums
__global__ __launch_bounds__(256) void k_scan_a(const int* __restrict__ deg,
                                                int* __restrict__ bsum) {
    __shared__ int red[256];
    int b = blockIdx.x, t = threadIdx.x;
    int base = b * SCAN_CHUNK + t * 4;
    int s = 0;
    if (base + 3 < N_NODES) {
        int4 v = *(const int4*)(deg + base);
        s = v.x + v.y + v.z + v.w;
    } else {
#pragma unroll
        for (int i = 0; i < 4; ++i) if (base + i < N_NODES) s += deg[base + i];
    }
    red[t] = s;
    __syncthreads();
    for (int ofs = 128; ofs; ofs >>= 1) {
        if (t < ofs) red[t] += red[t + ofs];
        __syncthreads();
    }
    if (t == 0) bsum[b] = red[0];
}

// scan phase B: one wave (64 lanes) scans NBLK_SCAN (<=128) block sums -> bpre
__global__ void k_scan_b(const int* __restrict__ bsum, int* __restrict__ bpre) {
    int t = threadIdx.x;   // 64
    int a = (2 * t     < NBLK_SCAN) ? bsum[2 * t]     : 0;
    int b = (2 * t + 1 < NBLK_SCAN) ? bsum[2 * t + 1] : 0;
    int local = a + b;
    int incl = local;
#pragma unroll
    for (int ofs = 1; ofs < 64; ofs <<= 1) {
        int u = __shfl_up(incl, ofs, 64);
        if (t >= ofs) incl += u;
    }
    int pre = incl - local;
    if (2 * t     < NBLK_SCAN) bpre[2 * t]     = pre;
    if (2 * t + 1 < NBLK_SCAN) bpre[2 * t + 1] = pre + a;
}

// scan phase C: local scan + block prefix -> off, cur
__global__ __launch_bounds__(256) void k_scan_c(const int* __restrict__ deg,
                                                const int* __restrict__ bpre,
                                                int* __restrict__ off,
                                                int* __restrict__ cur) {
    __shared__ int tsum[256];
    int b = blockIdx.x, t = threadIdx.x;
    int base = b * SCAN_CHUNK + t * 4;
    int d0 = 0, d1 = 0, d2 = 0, d3 = 0;
    if (base + 3 < N_NODES) {
        int4 v = *(const int4*)(deg + base);
        d0 = v.x; d1 = v.y; d2 = v.z; d3 = v.w;
    } else {
        if (base     < N_NODES) d0 = deg[base];
        if (base + 1 < N_NODES) d1 = deg[base + 1];
        if (base + 2 < N_NODES) d2 = deg[base + 2];
        if (base + 3 < N_NODES) d3 = deg[base + 3];
    }
    int s = d0 + d1 + d2 + d3;
    tsum[t] = s;
    __syncthreads();
    for (int ofs = 1; ofs < 256; ofs <<= 1) {
        int u = (t >= ofs) ? tsum[t - ofs] : 0;
        __syncthreads();
        tsum[t] += u;
        __syncthreads();
    }
    int run = bpre[b] + tsum[t] - s;   // exclusive prefix of this thread's quad
    if (base < N_NODES)     { off[base]     = run; cur[base]     = run; run += d0; }
    if (base + 1 < N_NODES) { off[base + 1] = run; cur[base + 1] = run; run += d1; }
    if (base + 2 < N_NODES) { off[base + 2] = run; cur[base + 2] = run; run += d2; }
    if (base + 3 < N_NODES) { off[base + 3] = run; cur[base + 3] = run; run += d3; }
    if (b == 0 && t == 0) off[N_NODES] = ETOT;
}

__global__ void k_scatter(const int* __restrict__ src, const int* __restrict__ dst,
                          int* __restrict__ cur, int* __restrict__ csr) {
    int e = blockIdx.x * blockDim.x + threadIdx.x;
    if (e >= ETOT) return;
    int s, d;
    if (e < E_EDGES) { s = src[e]; d = dst[e]; } else { s = d = e - E_EDGES; }
    int slot = atomicAdd(&cur[d], 1);
    csr[slot] = s;
}

// ---------------- layer 1 GEMM: h1(bf16) = x @ W1, plus s1/d1 ---------------
__global__ __launch_bounds__(256) void k_gemm1(
    const float* __restrict__ x, const float* __restrict__ W,
    const float* __restrict__ asrc, const float* __restrict__ adst,
    __hip_bfloat16* __restrict__ h1b, float* __restrict__ s1,
    float* __restrict__ d1) {
    __shared__ float xs[8][128];
    int n0 = blockIdx.x * 8;
    int t = threadIdx.x;
#pragma unroll
    for (int i = 0; i < 4; ++i) {
        int idx = t + i * 256;
        xs[idx >> 7][idx & 127] = x[(long)n0 * 128 + idx];
    }
    __syncthreads();
    int j = t & 127, sg = t >> 7;
    float a0 = 0.f, a1 = 0.f, a2 = 0.f, a3 = 0.f;
    for (int k = 0; k < 128; ++k) {
        float w = W[k * 128 + j];
        a0 = fmaf(xs[sg + 0][k], w, a0);
        a1 = fmaf(xs[sg + 2][k], w, a1);
        a2 = fmaf(xs[sg + 4][k], w, a2);
        a3 = fmaf(xs[sg + 6][k], w, a3);
    }
    float as = asrc[j], ad = adst[j];
    float accs[4] = {a0, a1, a2, a3};
#pragma unroll
    for (int i = 0; i < 4; ++i) {
        int n = n0 + sg + 2 * i;
        h1b[(long)n * 128 + j] = __float2bfloat16(accs[i]);
        float ps = accs[i] * as, pd = accs[i] * ad;
#pragma unroll
        for (int off = 8; off; off >>= 1) {
            ps += __shfl_down(ps, off, 16);
            pd += __shfl_down(pd, off, 16);
        }
        if ((j & 15) == 0) {
            s1[n * 8 + (j >> 4)] = ps;
            d1[n * 8 + (j >> 4)] = pd;
        }
    }
}

// ---------------- layer 1 fused attention + aggregate -----------------------
// block 256 = 2 nodes x 2 waves x 64 lanes.
__global__ __launch_bounds__(256) void k_l1(
    const int* __restrict__ off, const int* __restrict__ csr,
    const float* __restrict__ s1, const float* __restrict__ d1,
    const unsigned int* __restrict__ h1w, const float* __restrict__ b1,
    float* __restrict__ emb) {
    __shared__ float st[2][2][8][2];    // [node][wave][head][{m,sum}]
    __shared__ float pacc[2][64][2];    // wave-1 partial accumulators
    int t = threadIdx.x;
    int nib = t >> 7;
    int w = (t >> 6) & 1;
    int l = t & 63;
    int node = blockIdx.x * 2 + nib;
    int lo = off[node], hi = off[node + 1];

    // phase A: online softmax stats; 16 slots (2 waves x 8), head h = l&7
    int h = l & 7, i = l >> 3;
    float dv = d1[node * 8 + h];
    float m = -1e30f, ss = 0.f;
    for (int idx = lo + (w * 8 + i); idx < hi; idx += 16) {
        int s = csr[idx];
        float e = lrelu(s1[s * 8 + h] + dv);
        float mn = fmaxf(m, e);
        ss = ss * __expf(m - mn) + __expf(e - mn);
        m = mn;
    }
#pragma unroll
    for (int ofs = 8; ofs < 64; ofs <<= 1) {
        float mo = __shfl_xor(m, ofs, 64);
        float so = __shfl_xor(ss, ofs, 64);
        float mn = fmaxf(m, mo);
        ss = ss * __expf(m - mn) + so * __expf(mo - mn);
        m = mn;
    }
    if (i == 0) { st[nib][w][h][0] = m; st[nib][w][h][1] = ss; }
    __syncthreads();

    // combine the two waves' stats for this lane's channel-pair head
    int hh = l >> 3;                    // head of channels {2l, 2l+1}
    float m0 = st[nib][0][hh][0], q0 = st[nib][0][hh][1];
    float m1 = st[nib][1][hh][0], q1 = st[nib][1][hh][1];
    float mx = fmaxf(m0, m1);
    float den = q0 * __expf(m0 - mx) + q1 * __expf(m1 - mx);
    float rden = 1.f / (den + 1e-16f);
    float dvh = d1[node * 8 + hh];

    // phase B: gather-aggregate, 2-wave edge split, 1-deep prefetch
    float ax = 0.f, ay = 0.f;
    int idx = lo + w;
    int sc = 0; unsigned int bv = 0; float sv = 0.f;
    if (idx < hi) {
        sc = csr[idx];
        bv = h1w[(size_t)sc * 64 + l];
        sv = s1[sc * 8 + hh];
    }
    while (idx < hi) {
        int nidx = idx + 2;
        int sn = 0; unsigned int bn = 0; float svn = 0.f;
        if (nidx < hi) {
            sn = csr[nidx];
            bn = h1w[(size_t)sn * 64 + l];
            svn = s1[sn * 8 + hh];
        }
        float alpha = __expf(lrelu(sv + dvh) - mx) * rden;
        ax = fmaf(alpha, bflo(bv), ax);
        ay = fmaf(alpha, bfhi(bv), ay);
        sc = sn; bv = bn; sv = svn; idx = nidx;
    }
    if (w == 1) { pacc[nib][l][0] = ax; pacc[nib][l][1] = ay; }
    __syncthreads();
    if (w == 0) {
        ax += pacc[nib][l][0];
        ay += pacc[nib][l][1];
        float v0 = ax + b1[2 * l], v1 = ay + b1[2 * l + 1];
        v0 = v0 > 0.f ? v0 : expm1f(v0);
        v1 = v1 > 0.f ? v1 : expm1f(v1);
        float2* ep = (float2*)(emb + (size_t)node * 128);
        ep[l] = make_float2(v0, v1);
    }
}

// ---------------- layer 2 GEMM: h2(bf16) = emb @ W2 (128->16), s2/d2 --------
__global__ __launch_bounds__(256) void k_gemm2(
    const float* __restrict__ emb, const float* __restrict__ W,
    const float* __restrict__ asrc, const float* __restrict__ adst,
    __hip_bfloat16* __restrict__ h2b, float* __restrict__ s2,
    float* __restrict__ d2) {
    __shared__ float xs[16][129];
    int n0 = blockIdx.x * 16;
    int t = threadIdx.x;
#pragma unroll
    for (int i = 0; i < 8; ++i) {
        int idx = t + i * 256;
        xs[idx >> 7][idx & 127] = emb[(long)n0 * 128 + idx];
    }
    __syncthreads();
    int j = t & 15, sub = t >> 4;
    float acc = 0.f;
    for (int k = 0; k < 128; ++k) acc = fmaf(xs[sub][k], W[k * 16 + j], acc);
    int n = n0 + sub;
    h2b[(long)n * 16 + j] = __float2bfloat16(acc);
    float ps = acc * asrc[j], pd = acc * adst[j];
#pragma unroll
    for (int off = 8; off; off >>= 1) {
        ps += __shfl_down(ps, off, 16);
        pd += __shfl_down(pd, off, 16);
    }
    if (j == 0) { s2[n] = ps; d2[n] = pd; }
}

// ---------------- layer 2 fused attention + aggregate + log_softmax ---------
// block 256 = 4 nodes x 64 lanes (wave per node).
__global__ __launch_bounds__(256) void k_l2(
    const int* __restrict__ off, const int* __restrict__ csr,
    const float* __restrict__ s2, const float* __restrict__ d2,
    const unsigned int* __restrict__ h2w, const float* __restrict__ b2,
    float* __restrict__ logits) {
    int t = threadIdx.x;
    int node = blockIdx.x * 4 + (t >> 6);
    int l = t & 63;
    int lo = off[node], hi = off[node + 1];
    float dv = d2[node];

    // phase A: online stats over all edges, 64 slots
    float m = -1e30f, ss = 0.f;
    for (int idx = lo + l; idx < hi; idx += 64) {
        float e = lrelu(s2[csr[idx]] + dv);
        float mn = fmaxf(m, e);
        ss = ss * __expf(m - mn) + __expf(e - mn);
        m = mn;
    }
#pragma unroll
    for (int ofs = 1; ofs < 64; ofs <<= 1) {
        float mo = __shfl_xor(m, ofs, 64);
        float so = __shfl_xor(ss, ofs, 64);
        float mn = fmaxf(m, mo);
        ss = ss * __expf(m - mn) + so * __expf(mo - mn);
        m = mn;
    }
    float rden = 1.f / (ss + 1e-16f);

    // phase B: 8 edge-groups x 8 channel-pair lanes
    int g = l >> 3, p = l & 7;
    float ax = 0.f, ay = 0.f;
    for (int idx = lo + g; idx < hi; idx += 8) {
        int s = csr[idx];
        float alpha = __expf(lrelu(s2[s] + dv) - m) * rden;
        unsigned int bv = h2w[(size_t)s * 8 + p];
        ax = fmaf(alpha, bflo(bv), ax);
        ay = fmaf(alpha, bfhi(bv), ay);
    }
#pragma unroll
    for (int ofs = 8; ofs < 64; ofs <<= 1) {
        ax += __shfl_xor(ax, ofs, 64);
        ay += __shfl_xor(ay, ofs, 64);
    }
    float v0 = ax + b2[2 * p], v1 = ay + b2[2 * p + 1];
    float mm = fmaxf(v0, v1);
#pragma unroll
    for (int ofs = 1; ofs < 8; ofs <<= 1) mm = fmaxf(mm, __shfl_xor(mm, ofs, 8));
    float sm = __expf(v0 - mm) + __expf(v1 - mm);
#pragma unroll
    for (int ofs = 1; ofs < 8; ofs <<= 1) sm += __shfl_xor(sm, ofs, 8);
    if (g == 0) {
        float ls = logf(sm);
        logits[node * 16 + 2 * p]     = v0 - mm - ls;
        logits[node * 16 + 2 * p + 1] = v1 - mm - ls;
    }
}

extern "C" void kernel_launch(void* const* d_in, const int* in_sizes, int n_in,
                              void* d_out, int out_size, void* d_ws, size_t ws_size,
                              hipStream_t stream) {
    const float* x   = (const float*)d_in[0];
    const int*   ei  = (const int*)d_in[1];
    const float* W1  = (const float*)d_in[2];
    const float* as1 = (const float*)d_in[3];
    const float* ad1 = (const float*)d_in[4];
    const float* b1  = (const float*)d_in[5];
    const float* W2  = (const float*)d_in[6];
    const float* as2 = (const float*)d_in[7];
    const float* ad2 = (const float*)d_in[8];
    const float* b2  = (const float*)d_in[9];

    float* out    = (float*)d_out;
    float* logits = out;                          // [N,16]
    float* emb    = out + (size_t)N_NODES * 16;   // [N,128]

    float* ws    = (float*)d_ws;
    unsigned int* h1w = (unsigned int*)ws;                    // N*64 words (bf16 x2)
    float* s1    = (float*)(h1w + (size_t)N_NODES * 64);      // N*8
    float* d1    = s1 + (size_t)N_NODES * 8;
    unsigned int* h2w = (unsigned int*)(d1 + (size_t)N_NODES * 8); // N*8 words
    float* s2    = (float*)(h2w + (size_t)N_NODES * 8);       // N
    float* d2v   = s2 + (size_t)N_NODES;
    int*   deg   = (int*)(d2v + (size_t)N_NODES);             // N
    int*   offs  = deg + N_NODES;                             // N+1
    int*   cur   = offs + N_NODES + 1;                        // N
    int*   csr   = cur + N_NODES;                             // ETOT
    int*   bsum  = csr + ETOT;                                // NBLK_SCAN
    int*   bpre  = bsum + NBLK_SCAN;                          // NBLK_SCAN

    const int* srcp = ei;
    const int* dstp = ei + E_EDGES;

    hipMemsetAsync(deg, 0, (size_t)N_NODES * sizeof(int), stream);

    int gE = (ETOT + 255) / 256;
    k_hist<<<gE, 256, 0, stream>>>(dstp, deg);
    k_scan_a<<<NBLK_SCAN, 256, 0, stream>>>(deg, bsum);
    k_scan_b<<<1, 64, 0, stream>>>(bsum, bpre);
    k_scan_c<<<NBLK_SCAN, 256, 0, stream>>>(deg, bpre, offs, cur);
    k_scatter<<<gE, 256, 0, stream>>>(srcp, dstp, cur, csr);

    k_gemm1<<<N_NODES / 8, 256, 0, stream>>>(x, W1, as1, ad1,
                                             (__hip_bfloat16*)h1w, s1, d1);
    k_l1<<<N_NODES / 2, 256, 0, stream>>>(offs, csr, s1, d1, h1w, b1, emb);

    k_gemm2<<<N_NODES / 16, 256, 0, stream>>>(emb, W2, as2, ad2,
                                              (__hip_bfloat16*)h2w, s2, d2v);
    k_l2<<<N_NODES / 4, 256, 0, stream>>>(offs, csr, s2, d2v, h2w, b2, logits);
}

// Round 6
// 527.096 us; speedup vs baseline: 26.7420x; 1.1080x over previous
//
#include <hip/hip_runtime.h>
#include <hip/hip_bf16.h>
#include <math.h>

#define N_NODES 100000
#define E_EDGES 1600000
#define ETOT    (E_EDGES + N_NODES)
#define NEG     0.2f

#define SCAN_CHUNK 1024
#define NBLK_SCAN  ((N_NODES + SCAN_CHUNK - 1) / SCAN_CHUNK)   // 98

__device__ inline float lrelu(float x) { return x > 0.f ? x : NEG * x; }
__device__ inline float bflo(unsigned int b) { return __uint_as_float(b << 16); }
__device__ inline float bfhi(unsigned int b) { return __uint_as_float(b & 0xFFFF0000u); }

// ---------------- CSR build --------------------------------------------------
__global__ void k_hist(const int* __restrict__ dst, int* __restrict__ deg) {
    int e = blockIdx.x * blockDim.x + threadIdx.x;
    if (e >= ETOT) return;
    int d = (e < E_EDGES) ? dst[e] : e - E_EDGES;   // self-loops appended
    atomicAdd(&deg[d], 1);
}

__global__ __launch_bounds__(256) void k_scan_a(const int* __restrict__ deg,
                                                int* __restrict__ bsum) {
    __shared__ int red[256];
    int b = blockIdx.x, t = threadIdx.x;
    int base = b * SCAN_CHUNK + t * 4;
    int s = 0;
    if (base + 3 < N_NODES) {
        int4 v = *(const int4*)(deg + base);
        s = v.x + v.y + v.z + v.w;
    } else {
#pragma unroll
        for (int i = 0; i < 4; ++i) if (base + i < N_NODES) s += deg[base + i];
    }
    red[t] = s;
    __syncthreads();
    for (int ofs = 128; ofs; ofs >>= 1) {
        if (t < ofs) red[t] += red[t + ofs];
        __syncthreads();
    }
    if (t == 0) bsum[b] = red[0];
}

__global__ void k_scan_b(const int* __restrict__ bsum, int* __restrict__ bpre) {
    int t = threadIdx.x;   // 64
    int a = (2 * t     < NBLK_SCAN) ? bsum[2 * t]     : 0;
    int b = (2 * t + 1 < NBLK_SCAN) ? bsum[2 * t + 1] : 0;
    int local = a + b;
    int incl = local;
#pragma unroll
    for (int ofs = 1; ofs < 64; ofs <<= 1) {
        int u = __shfl_up(incl, ofs, 64);
        if (t >= ofs) incl += u;
    }
    int pre = incl - local;
    if (2 * t     < NBLK_SCAN) bpre[2 * t]     = pre;
    if (2 * t + 1 < NBLK_SCAN) bpre[2 * t + 1] = pre + a;
}

__global__ __launch_bounds__(256) void k_scan_c(const int* __restrict__ deg,
                                                const int* __restrict__ bpre,
                                                int* __restrict__ off,
                                                int* __restrict__ cur) {
    __shared__ int tsum[256];
    int b = blockIdx.x, t = threadIdx.x;
    int base = b * SCAN_CHUNK + t * 4;
    int d0 = 0, d1 = 0, d2 = 0, d3 = 0;
    if (base + 3 < N_NODES) {
        int4 v = *(const int4*)(deg + base);
        d0 = v.x; d1 = v.y; d2 = v.z; d3 = v.w;
    } else {
        if (base     < N_NODES) d0 = deg[base];
        if (base + 1 < N_NODES) d1 = deg[base + 1];
        if (base + 2 < N_NODES) d2 = deg[base + 2];
        if (base + 3 < N_NODES) d3 = deg[base + 3];
    }
    int s = d0 + d1 + d2 + d3;
    tsum[t] = s;
    __syncthreads();
    for (int ofs = 1; ofs < 256; ofs <<= 1) {
        int u = (t >= ofs) ? tsum[t - ofs] : 0;
        __syncthreads();
        tsum[t] += u;
        __syncthreads();
    }
    int run = bpre[b] + tsum[t] - s;
    if (base < N_NODES)     { off[base]     = run; cur[base]     = run; run += d0; }
    if (base + 1 < N_NODES) { off[base + 1] = run; cur[base + 1] = run; run += d1; }
    if (base + 2 < N_NODES) { off[base + 2] = run; cur[base + 2] = run; run += d2; }
    if (base + 3 < N_NODES) { off[base + 3] = run; cur[base + 3] = run; run += d3; }
    if (b == 0 && t == 0) off[N_NODES] = ETOT;
}

__global__ void k_scatter(const int* __restrict__ src, const int* __restrict__ dst,
                          int* __restrict__ cur, int* __restrict__ csr) {
    int e = blockIdx.x * blockDim.x + threadIdx.x;
    if (e >= ETOT) return;
    int s, d;
    if (e < E_EDGES) { s = src[e]; d = dst[e]; } else { s = d = e - E_EDGES; }
    int slot = atomicAdd(&cur[d], 1);
    csr[slot] = s;
}

// ---------------- layer 1 GEMM: h1(bf16) = x @ W1, plus s1/d1 ---------------
__global__ __launch_bounds__(256) void k_gemm1(
    const float* __restrict__ x, const float* __restrict__ W,
    const float* __restrict__ asrc, const float* __restrict__ adst,
    __hip_bfloat16* __restrict__ h1b, float* __restrict__ s1,
    float* __restrict__ d1) {
    __shared__ float xs[8][128];
    int n0 = blockIdx.x * 8;
    int t = threadIdx.x;
#pragma unroll
    for (int i = 0; i < 4; ++i) {
        int idx = t + i * 256;
        xs[idx >> 7][idx & 127] = x[(long)n0 * 128 + idx];
    }
    __syncthreads();
    int j = t & 127, sg = t >> 7;
    float a0 = 0.f, a1 = 0.f, a2 = 0.f, a3 = 0.f;
    for (int k = 0; k < 128; ++k) {
        float w = W[k * 128 + j];
        a0 = fmaf(xs[sg + 0][k], w, a0);
        a1 = fmaf(xs[sg + 2][k], w, a1);
        a2 = fmaf(xs[sg + 4][k], w, a2);
        a3 = fmaf(xs[sg + 6][k], w, a3);
    }
    float as = asrc[j], ad = adst[j];
    float accs[4] = {a0, a1, a2, a3};
#pragma unroll
    for (int i = 0; i < 4; ++i) {
        int n = n0 + sg + 2 * i;
        h1b[(long)n * 128 + j] = __float2bfloat16(accs[i]);
        float ps = accs[i] * as, pd = accs[i] * ad;
#pragma unroll
        for (int off = 8; off; off >>= 1) {
            ps += __shfl_down(ps, off, 16);
            pd += __shfl_down(pd, off, 16);
        }
        if ((j & 15) == 0) {
            s1[n * 8 + (j >> 4)] = ps;
            d1[n * 8 + (j >> 4)] = pd;
        }
    }
}

// ---------------- layer 1 fused attention + aggregate -----------------------
// block 256 = 2 nodes x 2 waves. Phase B: 4 groups x 16 lanes per wave,
// each group owns an edge, each lane loads uint4 = 8 bf16 channels.
__global__ __launch_bounds__(256) void k_l1(
    const int* __restrict__ off, const int* __restrict__ csr,
    const float* __restrict__ s1, const float* __restrict__ d1,
    const uint4* __restrict__ h1q, const float* __restrict__ b1,
    float* __restrict__ emb) {
    __shared__ float st[2][2][8][2];    // [node][wave][head][{m,sum}]
    __shared__ float pacc[2][16][8];    // wave-1 partial accumulators
    int t = threadIdx.x;
    int nib = t >> 7;
    int w = (t >> 6) & 1;
    int l = t & 63;
    int node = blockIdx.x * 2 + nib;
    int lo = off[node], hi = off[node + 1];

    // phase A: online softmax stats; 16 slots (2 waves x 8), head h = l&7
    int h = l & 7, i = l >> 3;
    float dv = d1[node * 8 + h];
    float m = -1e30f, ss = 0.f;
    for (int idx = lo + (w * 8 + i); idx < hi; idx += 16) {
        int s = csr[idx];
        float e = lrelu(s1[s * 8 + h] + dv);
        float mn = fmaxf(m, e);
        ss = ss * __expf(m - mn) + __expf(e - mn);
        m = mn;
    }
#pragma unroll
    for (int ofs = 8; ofs < 64; ofs <<= 1) {
        float mo = __shfl_xor(m, ofs, 64);
        float so = __shfl_xor(ss, ofs, 64);
        float mn = fmaxf(m, mo);
        ss = ss * __expf(m - mn) + so * __expf(mo - mn);
        m = mn;
    }
    if (i == 0) { st[nib][w][h][0] = m; st[nib][w][h][1] = ss; }
    __syncthreads();

    // per-lane head for phase B: lane q = l&15 covers channels [8q, 8q+8)
    int g = l >> 4, q = l & 15;
    int hb = q >> 1;
    float m0 = st[nib][0][hb][0], q0 = st[nib][0][hb][1];
    float m1 = st[nib][1][hb][0], q1 = st[nib][1][hb][1];
    float mx = fmaxf(m0, m1);
    float den = q0 * __expf(m0 - mx) + q1 * __expf(m1 - mx);
    float rden = 1.f / (den + 1e-16f);
    float dvh = d1[node * 8 + hb];

    // phase B: 8 edge-slots (2 waves x 4 groups), 1-deep prefetch
    float acc[8];
#pragma unroll
    for (int c = 0; c < 8; ++c) acc[c] = 0.f;
    int idx = lo + w * 4 + g;
    int sc = 0; uint4 bv = make_uint4(0, 0, 0, 0); float sv = 0.f;
    if (idx < hi) {
        sc = csr[idx];
        bv = h1q[(size_t)sc * 16 + q];
        sv = s1[sc * 8 + hb];
    }
    while (idx < hi) {
        int nidx = idx + 8;
        int sn = 0; uint4 bn = make_uint4(0, 0, 0, 0); float svn = 0.f;
        if (nidx < hi) {
            sn = csr[nidx];
            bn = h1q[(size_t)sn * 16 + q];
            svn = s1[sn * 8 + hb];
        }
        float alpha = __expf(lrelu(sv + dvh) - mx) * rden;
        acc[0] = fmaf(alpha, bflo(bv.x), acc[0]);
        acc[1] = fmaf(alpha, bfhi(bv.x), acc[1]);
        acc[2] = fmaf(alpha, bflo(bv.y), acc[2]);
        acc[3] = fmaf(alpha, bfhi(bv.y), acc[3]);
        acc[4] = fmaf(alpha, bflo(bv.z), acc[4]);
        acc[5] = fmaf(alpha, bfhi(bv.z), acc[5]);
        acc[6] = fmaf(alpha, bflo(bv.w), acc[6]);
        acc[7] = fmaf(alpha, bfhi(bv.w), acc[7]);
        sc = sn; bv = bn; sv = svn; idx = nidx;
    }
    // reduce across the 4 groups (lanes q, q+16, q+32, q+48 share channels)
#pragma unroll
    for (int c = 0; c < 8; ++c) {
        acc[c] += __shfl_xor(acc[c], 16, 64);
        acc[c] += __shfl_xor(acc[c], 32, 64);
    }
    if (w == 1 && l < 16) {
#pragma unroll
        for (int c = 0; c < 8; ++c) pacc[nib][q][c] = acc[c];
    }
    __syncthreads();
    if (w == 0 && l < 16) {
        float4 o0, o1;
        float vv[8];
#pragma unroll
        for (int c = 0; c < 8; ++c) {
            float v = acc[c] + pacc[nib][q][c] + b1[8 * q + c];
            vv[c] = v > 0.f ? v : expm1f(v);
        }
        o0 = make_float4(vv[0], vv[1], vv[2], vv[3]);
        o1 = make_float4(vv[4], vv[5], vv[6], vv[7]);
        float4* ep = (float4*)(emb + (size_t)node * 128);
        ep[2 * q]     = o0;
        ep[2 * q + 1] = o1;
    }
}

// ---------------- layer 2 GEMM: h2(bf16) = emb @ W2 (128->16), s2/d2 --------
__global__ __launch_bounds__(256) void k_gemm2(
    const float* __restrict__ emb, const float* __restrict__ W,
    const float* __restrict__ asrc, const float* __restrict__ adst,
    __hip_bfloat16* __restrict__ h2b, float* __restrict__ s2,
    float* __restrict__ d2) {
    __shared__ float xs[16][129];
    int n0 = blockIdx.x * 16;
    int t = threadIdx.x;
#pragma unroll
    for (int i = 0; i < 8; ++i) {
        int idx = t + i * 256;
        xs[idx >> 7][idx & 127] = emb[(long)n0 * 128 + idx];
    }
    __syncthreads();
    int j = t & 15, sub = t >> 4;
    float acc = 0.f;
    for (int k = 0; k < 128; ++k) acc = fmaf(xs[sub][k], W[k * 16 + j], acc);
    int n = n0 + sub;
    h2b[(long)n * 16 + j] = __float2bfloat16(acc);
    float ps = acc * asrc[j], pd = acc * adst[j];
#pragma unroll
    for (int off = 8; off; off >>= 1) {
        ps += __shfl_down(ps, off, 16);
        pd += __shfl_down(pd, off, 16);
    }
    if (j == 0) { s2[n] = ps; d2[n] = pd; }
}

// ---------------- layer 2 fused attention + aggregate + log_softmax ---------
__global__ __launch_bounds__(256) void k_l2(
    const int* __restrict__ off, const int* __restrict__ csr,
    const float* __restrict__ s2, const float* __restrict__ d2,
    const unsigned int* __restrict__ h2w, const float* __restrict__ b2,
    float* __restrict__ logits) {
    int t = threadIdx.x;
    int node = blockIdx.x * 4 + (t >> 6);
    int l = t & 63;
    int lo = off[node], hi = off[node + 1];
    float dv = d2[node];

    float m = -1e30f, ss = 0.f;
    for (int idx = lo + l; idx < hi; idx += 64) {
        float e = lrelu(s2[csr[idx]] + dv);
        float mn = fmaxf(m, e);
        ss = ss * __expf(m - mn) + __expf(e - mn);
        m = mn;
    }
#pragma unroll
    for (int ofs = 1; ofs < 64; ofs <<= 1) {
        float mo = __shfl_xor(m, ofs, 64);
        float so = __shfl_xor(ss, ofs, 64);
        float mn = fmaxf(m, mo);
        ss = ss * __expf(m - mn) + so * __expf(mo - mn);
        m = mn;
    }
    float rden = 1.f / (ss + 1e-16f);

    int g = l >> 3, p = l & 7;
    float ax = 0.f, ay = 0.f;
    for (int idx = lo + g; idx < hi; idx += 8) {
        int s = csr[idx];
        float alpha = __expf(lrelu(s2[s] + dv) - m) * rden;
        unsigned int bv = h2w[(size_t)s * 8 + p];
        ax = fmaf(alpha, bflo(bv), ax);
        ay = fmaf(alpha, bfhi(bv), ay);
    }
#pragma unroll
    for (int ofs = 8; ofs < 64; ofs <<= 1) {
        ax += __shfl_xor(ax, ofs, 64);
        ay += __shfl_xor(ay, ofs, 64);
    }
    float v0 = ax + b2[2 * p], v1 = ay + b2[2 * p + 1];
    float mm = fmaxf(v0, v1);
#pragma unroll
    for (int ofs = 1; ofs < 8; ofs <<= 1) mm = fmaxf(mm, __shfl_xor(mm, ofs, 8));
    float sm = __expf(v0 - mm) + __expf(v1 - mm);
#pragma unroll
    for (int ofs = 1; ofs < 8; ofs <<= 1) sm += __shfl_xor(sm, ofs, 8);
    if (g == 0) {
        float ls = logf(sm);
        logits[node * 16 + 2 * p]     = v0 - mm - ls;
        logits[node * 16 + 2 * p + 1] = v1 - mm - ls;
    }
}

extern "C" void kernel_launch(void* const* d_in, const int* in_sizes, int n_in,
                              void* d_out, int out_size, void* d_ws, size_t ws_size,
                              hipStream_t stream) {
    const float* x   = (const float*)d_in[0];
    const int*   ei  = (const int*)d_in[1];
    const float* W1  = (const float*)d_in[2];
    const float* as1 = (const float*)d_in[3];
    const float* ad1 = (const float*)d_in[4];
    const float* b1  = (const float*)d_in[5];
    const float* W2  = (const float*)d_in[6];
    const float* as2 = (const float*)d_in[7];
    const float* ad2 = (const float*)d_in[8];
    const float* b2  = (const float*)d_in[9];

    float* out    = (float*)d_out;
    float* logits = out;                          // [N,16]
    float* emb    = out + (size_t)N_NODES * 16;   // [N,128]

    float* ws    = (float*)d_ws;
    unsigned int* h1w = (unsigned int*)ws;                    // N*64 words (bf16 x2)
    float* s1    = (float*)(h1w + (size_t)N_NODES * 64);      // N*8
    float* d1    = s1 + (size_t)N_NODES * 8;
    unsigned int* h2w = (unsigned int*)(d1 + (size_t)N_NODES * 8); // N*8 words
    float* s2    = (float*)(h2w + (size_t)N_NODES * 8);       // N
    float* d2v   = s2 + (size_t)N_NODES;
    int*   deg   = (int*)(d2v + (size_t)N_NODES);             // N
    int*   offs  = deg + N_NODES;                             // N+1
    int*   cur   = offs + N_NODES + 1;                        // N
    int*   csr   = cur + N_NODES;                             // ETOT
    int*   bsum  = csr + ETOT;                                // NBLK_SCAN
    int*   bpre  = bsum + NBLK_SCAN;                          // NBLK_SCAN

    const int* srcp = ei;
    const int* dstp = ei + E_EDGES;

    hipMemsetAsync(deg, 0, (size_t)N_NODES * sizeof(int), stream);

    int gE = (ETOT + 255) / 256;
    k_hist<<<gE, 256, 0, stream>>>(dstp, deg);
    k_scan_a<<<NBLK_SCAN, 256, 0, stream>>>(deg, bsum);
    k_scan_b<<<1, 64, 0, stream>>>(bsum, bpre);
    k_scan_c<<<NBLK_SCAN, 256, 0, stream>>>(deg, bpre, offs, cur);
    k_scatter<<<gE, 256, 0, stream>>>(srcp, dstp, cur, csr);

    k_gemm1<<<N_NODES / 8, 256, 0, stream>>>(x, W1, as1, ad1,
                                             (__hip_bfloat16*)h1w, s1, d1);
    k_l1<<<N_NODES / 2, 256, 0, stream>>>(offs, csr, s1, d1,
                                          (const uint4*)h1w, b1, emb);

    k_gemm2<<<N_NODES / 16, 256, 0, stream>>>(emb, W2, as2, ad2,
                                              (__hip_bfloat16*)h2w, s2, d2v);
    k_l2<<<N_NODES / 4, 256, 0, stream>>>(offs, csr, s2, d2v, h2w, b2, logits);
}

// Round 7
// 463.829 us; speedup vs baseline: 30.3897x; 1.1364x over previous
//
#include <hip/hip_runtime.h>
#include <hip/hip_bf16.h>
#include <math.h>

#define N_NODES 100000
#define E_EDGES 1600000
#define ETOT    (E_EDGES + N_NODES)
#define NEG     0.2f

#define SCAN_CHUNK 1024
#define NBLK_SCAN  ((N_NODES + SCAN_CHUNK - 1) / SCAN_CHUNK)   // 98

__device__ inline float lrelu(float x) { return x > 0.f ? x : NEG * x; }
__device__ inline float bflo(unsigned int b) { return __uint_as_float(b << 16); }
__device__ inline float bfhi(unsigned int b) { return __uint_as_float(b & 0xFFFF0000u); }

// ---------------- CSR build --------------------------------------------------
__global__ void k_hist(const int* __restrict__ dst, int* __restrict__ deg) {
    int e = blockIdx.x * blockDim.x + threadIdx.x;
    if (e >= ETOT) return;
    int d = (e < E_EDGES) ? dst[e] : e - E_EDGES;   // self-loops appended
    atomicAdd(&deg[d], 1);
}

__global__ __launch_bounds__(256) void k_scan_a(const int* __restrict__ deg,
                                                int* __restrict__ bsum) {
    __shared__ int red[256];
    int b = blockIdx.x, t = threadIdx.x;
    int base = b * SCAN_CHUNK + t * 4;
    int s = 0;
    if (base + 3 < N_NODES) {
        int4 v = *(const int4*)(deg + base);
        s = v.x + v.y + v.z + v.w;
    } else {
#pragma unroll
        for (int i = 0; i < 4; ++i) if (base + i < N_NODES) s += deg[base + i];
    }
    red[t] = s;
    __syncthreads();
    for (int ofs = 128; ofs; ofs >>= 1) {
        if (t < ofs) red[t] += red[t + ofs];
        __syncthreads();
    }
    if (t == 0) bsum[b] = red[0];
}

__global__ void k_scan_b(const int* __restrict__ bsum, int* __restrict__ bpre) {
    int t = threadIdx.x;   // 64
    int a = (2 * t     < NBLK_SCAN) ? bsum[2 * t]     : 0;
    int b = (2 * t + 1 < NBLK_SCAN) ? bsum[2 * t + 1] : 0;
    int local = a + b;
    int incl = local;
#pragma unroll
    for (int ofs = 1; ofs < 64; ofs <<= 1) {
        int u = __shfl_up(incl, ofs, 64);
        if (t >= ofs) incl += u;
    }
    int pre = incl - local;
    if (2 * t     < NBLK_SCAN) bpre[2 * t]     = pre;
    if (2 * t + 1 < NBLK_SCAN) bpre[2 * t + 1] = pre + a;
}

__global__ __launch_bounds__(256) void k_scan_c(const int* __restrict__ deg,
                                                const int* __restrict__ bpre,
                                                int* __restrict__ off,
                                                int* __restrict__ cur) {
    __shared__ int tsum[256];
    int b = blockIdx.x, t = threadIdx.x;
    int base = b * SCAN_CHUNK + t * 4;
    int d0 = 0, d1 = 0, d2 = 0, d3 = 0;
    if (base + 3 < N_NODES) {
        int4 v = *(const int4*)(deg + base);
        d0 = v.x; d1 = v.y; d2 = v.z; d3 = v.w;
    } else {
        if (base     < N_NODES) d0 = deg[base];
        if (base + 1 < N_NODES) d1 = deg[base + 1];
        if (base + 2 < N_NODES) d2 = deg[base + 2];
        if (base + 3 < N_NODES) d3 = deg[base + 3];
    }
    int s = d0 + d1 + d2 + d3;
    tsum[t] = s;
    __syncthreads();
    for (int ofs = 1; ofs < 256; ofs <<= 1) {
        int u = (t >= ofs) ? tsum[t - ofs] : 0;
        __syncthreads();
        tsum[t] += u;
        __syncthreads();
    }
    int run = bpre[b] + tsum[t] - s;
    if (base < N_NODES)     { off[base]     = run; cur[base]     = run; run += d0; }
    if (base + 1 < N_NODES) { off[base + 1] = run; cur[base + 1] = run; run += d1; }
    if (base + 2 < N_NODES) { off[base + 2] = run; cur[base + 2] = run; run += d2; }
    if (base + 3 < N_NODES) { off[base + 3] = run; cur[base + 3] = run; run += d3; }
    if (b == 0 && t == 0) off[N_NODES] = ETOT;
}

__global__ void k_scatter(const int* __restrict__ src, const int* __restrict__ dst,
                          int* __restrict__ cur, int* __restrict__ csr) {
    int e = blockIdx.x * blockDim.x + threadIdx.x;
    if (e >= ETOT) return;
    int s, d;
    if (e < E_EDGES) { s = src[e]; d = dst[e]; } else { s = d = e - E_EDGES; }
    int slot = atomicAdd(&cur[d], 1);
    csr[slot] = s;
}

// ---------------- layer 1 GEMM: h1(bf16) = x @ W1, plus s1/d1 ---------------
__global__ __launch_bounds__(256) void k_gemm1(
    const float* __restrict__ x, const float* __restrict__ W,
    const float* __restrict__ asrc, const float* __restrict__ adst,
    __hip_bfloat16* __restrict__ h1b, float* __restrict__ s1,
    float* __restrict__ d1) {
    __shared__ float xs[8][128];
    int n0 = blockIdx.x * 8;
    int t = threadIdx.x;
#pragma unroll
    for (int i = 0; i < 4; ++i) {
        int idx = t + i * 256;
        xs[idx >> 7][idx & 127] = x[(long)n0 * 128 + idx];
    }
    __syncthreads();
    int j = t & 127, sg = t >> 7;
    float a0 = 0.f, a1 = 0.f, a2 = 0.f, a3 = 0.f;
    for (int k = 0; k < 128; ++k) {
        float w = W[k * 128 + j];
        a0 = fmaf(xs[sg + 0][k], w, a0);
        a1 = fmaf(xs[sg + 2][k], w, a1);
        a2 = fmaf(xs[sg + 4][k], w, a2);
        a3 = fmaf(xs[sg + 6][k], w, a3);
    }
    float as = asrc[j], ad = adst[j];
    float accs[4] = {a0, a1, a2, a3};
#pragma unroll
    for (int i = 0; i < 4; ++i) {
        int n = n0 + sg + 2 * i;
        h1b[(long)n * 128 + j] = __float2bfloat16(accs[i]);
        float ps = accs[i] * as, pd = accs[i] * ad;
#pragma unroll
        for (int off = 8; off; off >>= 1) {
            ps += __shfl_down(ps, off, 16);
            pd += __shfl_down(pd, off, 16);
        }
        if ((j & 15) == 0) {
            s1[n * 8 + (j >> 4)] = ps;
            d1[n * 8 + (j >> 4)] = pd;
        }
    }
}

// ---------------- layer 1 single-pass softmax-aggregate ---------------------
// block 256 = 4 nodes x 1 wave. Wave: 4 groups x 16 lanes; group owns an edge;
// lane q handles channels [8q, 8q+8) (head hb=q>>1) and the denominator.
// exp without max-subtraction (logits bounded; self-loop keeps den > 0).
__global__ __launch_bounds__(256) void k_l1(
    const int* __restrict__ off, const int* __restrict__ csr,
    const float* __restrict__ s1, const float* __restrict__ d1,
    const uint4* __restrict__ h1q, const float* __restrict__ b1,
    float* __restrict__ emb) {
    int t = threadIdx.x;
    int node = blockIdx.x * 4 + (t >> 6);
    int l = t & 63;
    int g = l >> 4, q = l & 15;
    int hb = q >> 1;
    int lo = off[node], hi = off[node + 1];
    float dvh = d1[node * 8 + hb];

    float acc[8];
#pragma unroll
    for (int c = 0; c < 8; ++c) acc[c] = 0.f;
    float den = 0.f;

    int idx = lo + g;
    int sc = 0; uint4 bv = make_uint4(0, 0, 0, 0); float sv = 0.f;
    if (idx < hi) {
        sc = csr[idx];
        bv = h1q[(size_t)sc * 16 + q];
        sv = s1[sc * 8 + hb];
    }
    while (idx < hi) {
        int nidx = idx + 4;
        int sn = 0; uint4 bn = make_uint4(0, 0, 0, 0); float svn = 0.f;
        if (nidx < hi) {
            sn = csr[nidx];
            bn = h1q[(size_t)sn * 16 + q];
            svn = s1[sn * 8 + hb];
        }
        float w = __expf(lrelu(sv + dvh));
        den += w;
        acc[0] = fmaf(w, bflo(bv.x), acc[0]);
        acc[1] = fmaf(w, bfhi(bv.x), acc[1]);
        acc[2] = fmaf(w, bflo(bv.y), acc[2]);
        acc[3] = fmaf(w, bfhi(bv.y), acc[3]);
        acc[4] = fmaf(w, bflo(bv.z), acc[4]);
        acc[5] = fmaf(w, bfhi(bv.z), acc[5]);
        acc[6] = fmaf(w, bflo(bv.w), acc[6]);
        acc[7] = fmaf(w, bfhi(bv.w), acc[7]);
        sc = sn; bv = bn; sv = svn; idx = nidx;
    }
    // reduce across the 4 groups (lanes q, q+16, q+32, q+48 share channels)
#pragma unroll
    for (int c = 0; c < 8; ++c) {
        acc[c] += __shfl_xor(acc[c], 16, 64);
        acc[c] += __shfl_xor(acc[c], 32, 64);
    }
    den += __shfl_xor(den, 16, 64);
    den += __shfl_xor(den, 32, 64);

    if (l < 16) {
        float r = 1.f / den;
        float vv[8];
#pragma unroll
        for (int c = 0; c < 8; ++c) {
            float v = acc[c] * r + b1[8 * q + c];
            vv[c] = v > 0.f ? v : expm1f(v);
        }
        float4* ep = (float4*)(emb + (size_t)node * 128);
        ep[2 * q]     = make_float4(vv[0], vv[1], vv[2], vv[3]);
        ep[2 * q + 1] = make_float4(vv[4], vv[5], vv[6], vv[7]);
    }
}

// ---------------- layer 2 GEMM: h2(bf16) = emb @ W2 (128->16), s2/d2 --------
__global__ __launch_bounds__(256) void k_gemm2(
    const float* __restrict__ emb, const float* __restrict__ W,
    const float* __restrict__ asrc, const float* __restrict__ adst,
    __hip_bfloat16* __restrict__ h2b, float* __restrict__ s2,
    float* __restrict__ d2) {
    __shared__ float xs[16][129];
    int n0 = blockIdx.x * 16;
    int t = threadIdx.x;
#pragma unroll
    for (int i = 0; i < 8; ++i) {
        int idx = t + i * 256;
        xs[idx >> 7][idx & 127] = emb[(long)n0 * 128 + idx];
    }
    __syncthreads();
    int j = t & 15, sub = t >> 4;
    float acc = 0.f;
    for (int k = 0; k < 128; ++k) acc = fmaf(xs[sub][k], W[k * 16 + j], acc);
    int n = n0 + sub;
    h2b[(long)n * 16 + j] = __float2bfloat16(acc);
    float ps = acc * asrc[j], pd = acc * adst[j];
#pragma unroll
    for (int off = 8; off; off >>= 1) {
        ps += __shfl_down(ps, off, 16);
        pd += __shfl_down(pd, off, 16);
    }
    if (j == 0) { s2[n] = ps; d2[n] = pd; }
}

// ---------------- layer 2 single-pass aggregate + log_softmax ---------------
// block 256 = 4 nodes x 1 wave; 8 groups x 8 lanes (p = 2 channels each).
__global__ __launch_bounds__(256) void k_l2(
    const int* __restrict__ off, const int* __restrict__ csr,
    const float* __restrict__ s2, const float* __restrict__ d2,
    const unsigned int* __restrict__ h2w, const float* __restrict__ b2,
    float* __restrict__ logits) {
    int t = threadIdx.x;
    int node = blockIdx.x * 4 + (t >> 6);
    int l = t & 63;
    int g = l >> 3, p = l & 7;
    int lo = off[node], hi = off[node + 1];
    float dv = d2[node];

    float ax = 0.f, ay = 0.f, den = 0.f;
    for (int idx = lo + g; idx < hi; idx += 8) {
        int s = csr[idx];
        float w = __expf(lrelu(s2[s] + dv));
        den += w;
        unsigned int bv = h2w[(size_t)s * 8 + p];
        ax = fmaf(w, bflo(bv), ax);
        ay = fmaf(w, bfhi(bv), ay);
    }
#pragma unroll
    for (int ofs = 8; ofs < 64; ofs <<= 1) {
        ax += __shfl_xor(ax, ofs, 64);
        ay += __shfl_xor(ay, ofs, 64);
        den += __shfl_xor(den, ofs, 64);
    }
    float r = 1.f / den;
    float v0 = ax * r + b2[2 * p], v1 = ay * r + b2[2 * p + 1];
    float mm = fmaxf(v0, v1);
#pragma unroll
    for (int ofs = 1; ofs < 8; ofs <<= 1) mm = fmaxf(mm, __shfl_xor(mm, ofs, 8));
    float sm = __expf(v0 - mm) + __expf(v1 - mm);
#pragma unroll
    for (int ofs = 1; ofs < 8; ofs <<= 1) sm += __shfl_xor(sm, ofs, 8);
    if (g == 0) {
        float ls = logf(sm);
        logits[node * 16 + 2 * p]     = v0 - mm - ls;
        logits[node * 16 + 2 * p + 1] = v1 - mm - ls;
    }
}

extern "C" void kernel_launch(void* const* d_in, const int* in_sizes, int n_in,
                              void* d_out, int out_size, void* d_ws, size_t ws_size,
                              hipStream_t stream) {
    const float* x   = (const float*)d_in[0];
    const int*   ei  = (const int*)d_in[1];
    const float* W1  = (const float*)d_in[2];
    const float* as1 = (const float*)d_in[3];
    const float* ad1 = (const float*)d_in[4];
    const float* b1  = (const float*)d_in[5];
    const float* W2  = (const float*)d_in[6];
    const float* as2 = (const float*)d_in[7];
    const float* ad2 = (const float*)d_in[8];
    const float* b2  = (const float*)d_in[9];

    float* out    = (float*)d_out;
    float* logits = out;                          // [N,16]
    float* emb    = out + (size_t)N_NODES * 16;   // [N,128]

    float* ws    = (float*)d_ws;
    unsigned int* h1w = (unsigned int*)ws;                    // N*64 words (bf16 x2)
    float* s1    = (float*)(h1w + (size_t)N_NODES * 64);      // N*8
    float* d1    = s1 + (size_t)N_NODES * 8;
    unsigned int* h2w = (unsigned int*)(d1 + (size_t)N_NODES * 8); // N*8 words
    float* s2    = (float*)(h2w + (size_t)N_NODES * 8);       // N
    float* d2v   = s2 + (size_t)N_NODES;
    int*   deg   = (int*)(d2v + (size_t)N_NODES);             // N
    int*   offs  = deg + N_NODES;                             // N+1
    int*   cur   = offs + N_NODES + 1;                        // N
    int*   csr   = cur + N_NODES;                             // ETOT
    int*   bsum  = csr + ETOT;                                // NBLK_SCAN
    int*   bpre  = bsum + NBLK_SCAN;                          // NBLK_SCAN

    const int* srcp = ei;
    const int* dstp = ei + E_EDGES;

    hipMemsetAsync(deg, 0, (size_t)N_NODES * sizeof(int), stream);

    int gE = (ETOT + 255) / 256;
    k_hist<<<gE, 256, 0, stream>>>(dstp, deg);
    k_scan_a<<<NBLK_SCAN, 256, 0, stream>>>(deg, bsum);
    k_scan_b<<<1, 64, 0, stream>>>(bsum, bpre);
    k_scan_c<<<NBLK_SCAN, 256, 0, stream>>>(deg, bpre, offs, cur);
    k_scatter<<<gE, 256, 0, stream>>>(srcp, dstp, cur, csr);

    k_gemm1<<<N_NODES / 8, 256, 0, stream>>>(x, W1, as1, ad1,
                                             (__hip_bfloat16*)h1w, s1, d1);
    k_l1<<<N_NODES / 4, 256, 0, stream>>>(offs, csr, s1, d1,
                                          (const uint4*)h1w, b1, emb);

    k_gemm2<<<N_NODES / 16, 256, 0, stream>>>(emb, W2, as2, ad2,
                                              (__hip_bfloat16*)h2w, s2, d2v);
    k_l2<<<N_NODES / 4, 256, 0, stream>>>(offs, csr, s2, d2v, h2w, b2, logits);
}

// Round 8
// 462.414 us; speedup vs baseline: 30.4827x; 1.0031x over previous
//
#include <hip/hip_runtime.h>
#include <hip/hip_bf16.h>
#include <math.h>

#define N_NODES 100000
#define E_EDGES 1600000
#define ETOT    (E_EDGES + N_NODES)
#define NEG     0.2f

#define SCAN_CHUNK 1024
#define NBLK_SCAN  ((N_NODES + SCAN_CHUNK - 1) / SCAN_CHUNK)   // 98

#define HIST_BLOCKS  ((E_EDGES + 1023) / 1024)   // 1563 (4 edges/thread)
#define SCAT_BLOCKS  ((E_EDGES + 255) / 256)     // 6250
#define GEMM1_BLOCKS (N_NODES / 8)               // 12500
#define G1A          3125                        // gemm1 blocks fused with hist
#define G1B          (GEMM1_BLOCKS - G1A)        // 9375, fused with scatter

__device__ inline float lrelu(float x) { return x > 0.f ? x : NEG * x; }
__device__ inline float bflo(unsigned int b) { return __uint_as_float(b << 16); }
__device__ inline float bfhi(unsigned int b) { return __uint_as_float(b & 0xFFFF0000u); }

// ---------------- gemm1 role (device fn): 8 nodes per block -----------------
__device__ __forceinline__ void gemm1_role(
    int n0, int t, float (*xs)[128],
    const float* __restrict__ x, const float* __restrict__ W,
    const float* __restrict__ asrc, const float* __restrict__ adst,
    __hip_bfloat16* __restrict__ h1b, float* __restrict__ s1,
    float* __restrict__ d1) {
#pragma unroll
    for (int i = 0; i < 4; ++i) {
        int idx = t + i * 256;
        xs[idx >> 7][idx & 127] = x[(long)n0 * 128 + idx];
    }
    __syncthreads();
    int j = t & 127, sg = t >> 7;
    float a0 = 0.f, a1 = 0.f, a2 = 0.f, a3 = 0.f;
    for (int k = 0; k < 128; ++k) {
        float w = W[k * 128 + j];
        a0 = fmaf(xs[sg + 0][k], w, a0);
        a1 = fmaf(xs[sg + 2][k], w, a1);
        a2 = fmaf(xs[sg + 4][k], w, a2);
        a3 = fmaf(xs[sg + 6][k], w, a3);
    }
    float as = asrc[j], ad = adst[j];
    float accs[4] = {a0, a1, a2, a3};
#pragma unroll
    for (int i = 0; i < 4; ++i) {
        int n = n0 + sg + 2 * i;
        h1b[(long)n * 128 + j] = __float2bfloat16(accs[i]);
        float ps = accs[i] * as, pd = accs[i] * ad;
#pragma unroll
        for (int off = 8; off; off >>= 1) {
            ps += __shfl_down(ps, off, 16);
            pd += __shfl_down(pd, off, 16);
        }
        if ((j & 15) == 0) {
            s1[n * 8 + (j >> 4)] = ps;
            d1[n * 8 + (j >> 4)] = pd;
        }
    }
}

// ---------------- kernel A: hist (real edges, int4) || gemm1 quarter --------
__global__ __launch_bounds__(256) void k_parA(
    const int* __restrict__ dst, int* __restrict__ deg,
    const float* __restrict__ x, const float* __restrict__ W,
    const float* __restrict__ asrc, const float* __restrict__ adst,
    __hip_bfloat16* __restrict__ h1b, float* __restrict__ s1,
    float* __restrict__ d1) {
    __shared__ float xs[8][128];
    int bid = blockIdx.x, t = threadIdx.x;
    if (bid < HIST_BLOCKS) {
        int e0 = bid * 1024 + t * 4;
        if (e0 + 3 < E_EDGES) {
            int4 v = *(const int4*)(dst + e0);
            atomicAdd(&deg[v.x], 1);
            atomicAdd(&deg[v.y], 1);
            atomicAdd(&deg[v.z], 1);
            atomicAdd(&deg[v.w], 1);
        } else {
#pragma unroll
            for (int i = 0; i < 4; ++i)
                if (e0 + i < E_EDGES) atomicAdd(&deg[dst[e0 + i]], 1);
        }
    } else {
        gemm1_role((bid - HIST_BLOCKS) * 8, t, xs, x, W, asrc, adst, h1b, s1, d1);
    }
}

// ---------------- scan (degrees +1 for implicit self-loop) ------------------
__global__ __launch_bounds__(256) void k_scan_a(const int* __restrict__ deg,
                                                int* __restrict__ bsum) {
    __shared__ int red[256];
    int b = blockIdx.x, t = threadIdx.x;
    int base = b * SCAN_CHUNK + t * 4;
    int s = 0;
    if (base + 3 < N_NODES) {
        int4 v = *(const int4*)(deg + base);
        s = v.x + v.y + v.z + v.w + 4;
    } else {
#pragma unroll
        for (int i = 0; i < 4; ++i)
            if (base + i < N_NODES) s += deg[base + i] + 1;
    }
    red[t] = s;
    __syncthreads();
    for (int ofs = 128; ofs; ofs >>= 1) {
        if (t < ofs) red[t] += red[t + ofs];
        __syncthreads();
    }
    if (t == 0) bsum[b] = red[0];
}

__global__ void k_scan_b(const int* __restrict__ bsum, int* __restrict__ bpre) {
    int t = threadIdx.x;   // 64
    int a = (2 * t     < NBLK_SCAN) ? bsum[2 * t]     : 0;
    int b = (2 * t + 1 < NBLK_SCAN) ? bsum[2 * t + 1] : 0;
    int local = a + b;
    int incl = local;
#pragma unroll
    for (int ofs = 1; ofs < 64; ofs <<= 1) {
        int u = __shfl_up(incl, ofs, 64);
        if (t >= ofs) incl += u;
    }
    int pre = incl - local;
    if (2 * t     < NBLK_SCAN) bpre[2 * t]     = pre;
    if (2 * t + 1 < NBLK_SCAN) bpre[2 * t + 1] = pre + a;
}

// scan C: emits off/cur AND writes the self-loop into slot off[n]
__global__ __launch_bounds__(256) void k_scan_c(const int* __restrict__ deg,
                                                const int* __restrict__ bpre,
                                                int* __restrict__ off,
                                                int* __restrict__ cur,
                                                int* __restrict__ csr) {
    __shared__ int tsum[256];
    int b = blockIdx.x, t = threadIdx.x;
    int base = b * SCAN_CHUNK + t * 4;
    int d0 = 0, d1 = 0, d2 = 0, d3 = 0;
    if (base + 3 < N_NODES) {
        int4 v = *(const int4*)(deg + base);
        d0 = v.x + 1; d1 = v.y + 1; d2 = v.z + 1; d3 = v.w + 1;
    } else {
        if (base     < N_NODES) d0 = deg[base] + 1;
        if (base + 1 < N_NODES) d1 = deg[base + 1] + 1;
        if (base + 2 < N_NODES) d2 = deg[base + 2] + 1;
        if (base + 3 < N_NODES) d3 = deg[base + 3] + 1;
    }
    int s = d0 + d1 + d2 + d3;
    tsum[t] = s;
    __syncthreads();
    for (int ofs = 1; ofs < 256; ofs <<= 1) {
        int u = (t >= ofs) ? tsum[t - ofs] : 0;
        __syncthreads();
        tsum[t] += u;
        __syncthreads();
    }
    int run = bpre[b] + tsum[t] - s;
    if (base < N_NODES)     { off[base]     = run; csr[run] = base;
                              cur[base]     = run + 1; run += d0; }
    if (base + 1 < N_NODES) { off[base + 1] = run; csr[run] = base + 1;
                              cur[base + 1] = run + 1; run += d1; }
    if (base + 2 < N_NODES) { off[base + 2] = run; csr[run] = base + 2;
                              cur[base + 2] = run + 1; run += d2; }
    if (base + 3 < N_NODES) { off[base + 3] = run; csr[run] = base + 3;
                              cur[base + 3] = run + 1; run += d3; }
    if (b == 0 && t == 0) off[N_NODES] = ETOT;
}

// ---------------- kernel B: scatter (real edges) || gemm1 three-quarters ----
__global__ __launch_bounds__(256) void k_parB(
    const int* __restrict__ src, const int* __restrict__ dst,
    int* __restrict__ cur, int* __restrict__ csr,
    const float* __restrict__ x, const float* __restrict__ W,
    const float* __restrict__ asrc, const float* __restrict__ adst,
    __hip_bfloat16* __restrict__ h1b, float* __restrict__ s1,
    float* __restrict__ d1) {
    __shared__ float xs[8][128];
    int bid = blockIdx.x, t = threadIdx.x;
    if (bid < SCAT_BLOCKS) {
        int e = bid * 256 + t;
        if (e < E_EDGES) {
            int s = src[e], d = dst[e];
            int slot = atomicAdd(&cur[d], 1);
            csr[slot] = s;
        }
    } else {
        gemm1_role((G1A + bid - SCAT_BLOCKS) * 8, t, xs, x, W, asrc, adst,
                   h1b, s1, d1);
    }
}

// ---------------- layer 1 single-pass softmax-aggregate ---------------------
__global__ __launch_bounds__(256) void k_l1(
    const int* __restrict__ off, const int* __restrict__ csr,
    const float* __restrict__ s1, const float* __restrict__ d1,
    const uint4* __restrict__ h1q, const float* __restrict__ b1,
    float* __restrict__ emb) {
    int t = threadIdx.x;
    int node = blockIdx.x * 4 + (t >> 6);
    int l = t & 63;
    int g = l >> 4, q = l & 15;
    int hb = q >> 1;
    int lo = off[node], hi = off[node + 1];
    float dvh = d1[node * 8 + hb];

    float acc[8];
#pragma unroll
    for (int c = 0; c < 8; ++c) acc[c] = 0.f;
    float den = 0.f;

    int idx = lo + g;
    int sc = 0; uint4 bv = make_uint4(0, 0, 0, 0); float sv = 0.f;
    if (idx < hi) {
        sc = csr[idx];
        bv = h1q[(size_t)sc * 16 + q];
        sv = s1[sc * 8 + hb];
    }
    while (idx < hi) {
        int nidx = idx + 4;
        int sn = 0; uint4 bn = make_uint4(0, 0, 0, 0); float svn = 0.f;
        if (nidx < hi) {
            sn = csr[nidx];
            bn = h1q[(size_t)sn * 16 + q];
            svn = s1[sn * 8 + hb];
        }
        float w = __expf(lrelu(sv + dvh));
        den += w;
        acc[0] = fmaf(w, bflo(bv.x), acc[0]);
        acc[1] = fmaf(w, bfhi(bv.x), acc[1]);
        acc[2] = fmaf(w, bflo(bv.y), acc[2]);
        acc[3] = fmaf(w, bfhi(bv.y), acc[3]);
        acc[4] = fmaf(w, bflo(bv.z), acc[4]);
        acc[5] = fmaf(w, bfhi(bv.z), acc[5]);
        acc[6] = fmaf(w, bflo(bv.w), acc[6]);
        acc[7] = fmaf(w, bfhi(bv.w), acc[7]);
        sc = sn; bv = bn; sv = svn; idx = nidx;
    }
#pragma unroll
    for (int c = 0; c < 8; ++c) {
        acc[c] += __shfl_xor(acc[c], 16, 64);
        acc[c] += __shfl_xor(acc[c], 32, 64);
    }
    den += __shfl_xor(den, 16, 64);
    den += __shfl_xor(den, 32, 64);

    if (l < 16) {
        float r = 1.f / den;
        float vv[8];
#pragma unroll
        for (int c = 0; c < 8; ++c) {
            float v = acc[c] * r + b1[8 * q + c];
            vv[c] = v > 0.f ? v : expm1f(v);
        }
        float4* ep = (float4*)(emb + (size_t)node * 128);
        ep[2 * q]     = make_float4(vv[0], vv[1], vv[2], vv[3]);
        ep[2 * q + 1] = make_float4(vv[4], vv[5], vv[6], vv[7]);
    }
}

// ---------------- layer 2 GEMM: h2(bf16) = emb @ W2 (128->16), s2/d2 --------
__global__ __launch_bounds__(256) void k_gemm2(
    const float* __restrict__ emb, const float* __restrict__ W,
    const float* __restrict__ asrc, const float* __restrict__ adst,
    __hip_bfloat16* __restrict__ h2b, float* __restrict__ s2,
    float* __restrict__ d2) {
    __shared__ float xs[16][129];
    int n0 = blockIdx.x * 16;
    int t = threadIdx.x;
#pragma unroll
    for (int i = 0; i < 8; ++i) {
        int idx = t + i * 256;
        xs[idx >> 7][idx & 127] = emb[(long)n0 * 128 + idx];
    }
    __syncthreads();
    int j = t & 15, sub = t >> 4;
    float acc = 0.f;
    for (int k = 0; k < 128; ++k) acc = fmaf(xs[sub][k], W[k * 16 + j], acc);
    int n = n0 + sub;
    h2b[(long)n * 16 + j] = __float2bfloat16(acc);
    float ps = acc * asrc[j], pd = acc * adst[j];
#pragma unroll
    for (int off = 8; off; off >>= 1) {
        ps += __shfl_down(ps, off, 16);
        pd += __shfl_down(pd, off, 16);
    }
    if (j == 0) { s2[n] = ps; d2[n] = pd; }
}

// ---------------- layer 2 single-pass aggregate + log_softmax ---------------
__global__ __launch_bounds__(256) void k_l2(
    const int* __restrict__ off, const int* __restrict__ csr,
    const float* __restrict__ s2, const float* __restrict__ d2,
    const unsigned int* __restrict__ h2w, const float* __restrict__ b2,
    float* __restrict__ logits) {
    int t = threadIdx.x;
    int node = blockIdx.x * 4 + (t >> 6);
    int l = t & 63;
    int g = l >> 3, p = l & 7;
    int lo = off[node], hi = off[node + 1];
    float dv = d2[node];

    float ax = 0.f, ay = 0.f, den = 0.f;
    for (int idx = lo + g; idx < hi; idx += 8) {
        int s = csr[idx];
        float w = __expf(lrelu(s2[s] + dv));
        den += w;
        unsigned int bv = h2w[(size_t)s * 8 + p];
        ax = fmaf(w, bflo(bv), ax);
        ay = fmaf(w, bfhi(bv), ay);
    }
#pragma unroll
    for (int ofs = 8; ofs < 64; ofs <<= 1) {
        ax += __shfl_xor(ax, ofs, 64);
        ay += __shfl_xor(ay, ofs, 64);
        den += __shfl_xor(den, ofs, 64);
    }
    float r = 1.f / den;
    float v0 = ax * r + b2[2 * p], v1 = ay * r + b2[2 * p + 1];
    float mm = fmaxf(v0, v1);
#pragma unroll
    for (int ofs = 1; ofs < 8; ofs <<= 1) mm = fmaxf(mm, __shfl_xor(mm, ofs, 8));
    float sm = __expf(v0 - mm) + __expf(v1 - mm);
#pragma unroll
    for (int ofs = 1; ofs < 8; ofs <<= 1) sm += __shfl_xor(sm, ofs, 8);
    if (g == 0) {
        float ls = logf(sm);
        logits[node * 16 + 2 * p]     = v0 - mm - ls;
        logits[node * 16 + 2 * p + 1] = v1 - mm - ls;
    }
}

extern "C" void kernel_launch(void* const* d_in, const int* in_sizes, int n_in,
                              void* d_out, int out_size, void* d_ws, size_t ws_size,
                              hipStream_t stream) {
    const float* x   = (const float*)d_in[0];
    const int*   ei  = (const int*)d_in[1];
    const float* W1  = (const float*)d_in[2];
    const float* as1 = (const float*)d_in[3];
    const float* ad1 = (const float*)d_in[4];
    const float* b1  = (const float*)d_in[5];
    const float* W2  = (const float*)d_in[6];
    const float* as2 = (const float*)d_in[7];
    const float* ad2 = (const float*)d_in[8];
    const float* b2  = (const float*)d_in[9];

    float* out    = (float*)d_out;
    float* logits = out;                          // [N,16]
    float* emb    = out + (size_t)N_NODES * 16;   // [N,128]

    float* ws    = (float*)d_ws;
    unsigned int* h1w = (unsigned int*)ws;                    // N*64 words (bf16 x2)
    float* s1    = (float*)(h1w + (size_t)N_NODES * 64);      // N*8
    float* d1    = s1 + (size_t)N_NODES * 8;
    unsigned int* h2w = (unsigned int*)(d1 + (size_t)N_NODES * 8); // N*8 words
    float* s2    = (float*)(h2w + (size_t)N_NODES * 8);       // N
    float* d2v   = s2 + (size_t)N_NODES;
    int*   deg   = (int*)(d2v + (size_t)N_NODES);             // N
    int*   offs  = deg + N_NODES;                             // N+1
    int*   cur   = offs + N_NODES + 1;                        // N
    int*   csr   = cur + N_NODES;                             // ETOT
    int*   bsum  = csr + ETOT;                                // NBLK_SCAN
    int*   bpre  = bsum + NBLK_SCAN;                          // NBLK_SCAN

    const int* srcp = ei;
    const int* dstp = ei + E_EDGES;

    hipMemsetAsync(deg, 0, (size_t)N_NODES * sizeof(int), stream);

    k_parA<<<HIST_BLOCKS + G1A, 256, 0, stream>>>(dstp, deg, x, W1, as1, ad1,
                                                  (__hip_bfloat16*)h1w, s1, d1);
    k_scan_a<<<NBLK_SCAN, 256, 0, stream>>>(deg, bsum);
    k_scan_b<<<1, 64, 0, stream>>>(bsum, bpre);
    k_scan_c<<<NBLK_SCAN, 256, 0, stream>>>(deg, bpre, offs, cur, csr);
    k_parB<<<SCAT_BLOCKS + G1B, 256, 0, stream>>>(srcp, dstp, cur, csr,
                                                  x, W1, as1, ad1,
                                                  (__hip_bfloat16*)h1w, s1, d1);

    k_l1<<<N_NODES / 4, 256, 0, stream>>>(offs, csr, s1, d1,
                                          (const uint4*)h1w, b1, emb);

    k_gemm2<<<N_NODES / 16, 256, 0, stream>>>(emb, W2, as2, ad2,
                                              (__hip_bfloat16*)h2w, s2, d2v);
    k_l2<<<N_NODES / 4, 256, 0, stream>>>(offs, csr, s2, d2v, h2w, b2, logits);
}

// Round 9
// 440.351 us; speedup vs baseline: 32.0099x; 1.0501x over previous
//
#include <hip/hip_runtime.h>
#include <hip/hip_bf16.h>
#include <math.h>

#define N_NODES 100000
#define E_EDGES 1600000
#define ETOT    (E_EDGES + N_NODES)
#define NEG     0.2f

#define SCAN_CHUNK 1024
#define NBLK_SCAN  ((N_NODES + SCAN_CHUNK - 1) / SCAN_CHUNK)   // 98

// bucketed CSR build
#define SH        8
#define NBUCK     ((N_NODES + 255) >> 8)          // 391
#define BIN_TILE  4096
#define NBIN      ((E_EDGES + BIN_TILE - 1) / BIN_TILE)  // 391

#define HIST_BLOCKS ((E_EDGES + 1023) / 1024)     // 1563 (4 edges/thread)
#define G1A 5000
#define G1B 4500
#define G1C 3000    // G1A+G1B+G1C == N_NODES/8 == 12500

__device__ inline float lrelu(float x) { return x > 0.f ? x : NEG * x; }
__device__ inline float bflo(unsigned int b) { return __uint_as_float(b << 16); }
__device__ inline float bfhi(unsigned int b) { return __uint_as_float(b & 0xFFFF0000u); }

// ---------------- gemm1 role (device fn): 8 nodes per block -----------------
__device__ __forceinline__ void gemm1_role(
    int n0, int t, float (*xs)[128],
    const float* __restrict__ x, const float* __restrict__ W,
    const float* __restrict__ asrc, const float* __restrict__ adst,
    __hip_bfloat16* __restrict__ h1b, float* __restrict__ s1,
    float* __restrict__ d1) {
#pragma unroll
    for (int i = 0; i < 4; ++i) {
        int idx = t + i * 256;
        xs[idx >> 7][idx & 127] = x[(long)n0 * 128 + idx];
    }
    __syncthreads();
    int j = t & 127, sg = t >> 7;
    float a0 = 0.f, a1 = 0.f, a2 = 0.f, a3 = 0.f;
    for (int k = 0; k < 128; ++k) {
        float w = W[k * 128 + j];
        a0 = fmaf(xs[sg + 0][k], w, a0);
        a1 = fmaf(xs[sg + 2][k], w, a1);
        a2 = fmaf(xs[sg + 4][k], w, a2);
        a3 = fmaf(xs[sg + 6][k], w, a3);
    }
    float as = asrc[j], ad = adst[j];
    float accs[4] = {a0, a1, a2, a3};
#pragma unroll
    for (int i = 0; i < 4; ++i) {
        int n = n0 + sg + 2 * i;
        h1b[(long)n * 128 + j] = __float2bfloat16(accs[i]);
        float ps = accs[i] * as, pd = accs[i] * ad;
#pragma unroll
        for (int off = 8; off; off >>= 1) {
            ps += __shfl_down(ps, off, 16);
            pd += __shfl_down(pd, off, 16);
        }
        if ((j & 15) == 0) {
            s1[n * 8 + (j >> 4)] = ps;
            d1[n * 8 + (j >> 4)] = pd;
        }
    }
}

// ---------------- kernel A: hist (int4) || gemm1 part A (interleaved) -------
__global__ __launch_bounds__(256) void k_parA(
    const int* __restrict__ dst, int* __restrict__ deg,
    const float* __restrict__ x, const float* __restrict__ W,
    const float* __restrict__ asrc, const float* __restrict__ adst,
    __hip_bfloat16* __restrict__ h1b, float* __restrict__ s1,
    float* __restrict__ d1) {
    __shared__ float xs[8][128];
    int bid = blockIdx.x, t = threadIdx.x;
    // every 4th block (while hist ids remain) is a hist block
    bool isHist = (bid < 4 * HIST_BLOCKS) && ((bid & 3) == 0);
    if (isHist) {
        int hid = bid >> 2;
        int e0 = hid * 1024 + t * 4;
        if (e0 + 3 < E_EDGES) {
            int4 v = *(const int4*)(dst + e0);
            atomicAdd(&deg[v.x], 1);
            atomicAdd(&deg[v.y], 1);
            atomicAdd(&deg[v.z], 1);
            atomicAdd(&deg[v.w], 1);
        } else {
#pragma unroll
            for (int i = 0; i < 4; ++i)
                if (e0 + i < E_EDGES) atomicAdd(&deg[dst[e0 + i]], 1);
        }
    } else {
        int gid = (bid < 4 * HIST_BLOCKS) ? (bid - (bid >> 2) - 1)
                                          : (bid - HIST_BLOCKS);
        gemm1_role(gid * 8, t, xs, x, W, asrc, adst, h1b, s1, d1);
    }
}

// ---------------- scan (degrees +1 for implicit self-loop) ------------------
__global__ __launch_bounds__(256) void k_scan_a(const int* __restrict__ deg,
                                                int* __restrict__ bsum) {
    __shared__ int red[256];
    int b = blockIdx.x, t = threadIdx.x;
    int base = b * SCAN_CHUNK + t * 4;
    int s = 0;
    if (base + 3 < N_NODES) {
        int4 v = *(const int4*)(deg + base);
        s = v.x + v.y + v.z + v.w + 4;
    } else {
#pragma unroll
        for (int i = 0; i < 4; ++i)
            if (base + i < N_NODES) s += deg[base + i] + 1;
    }
    red[t] = s;
    __syncthreads();
    for (int ofs = 128; ofs; ofs >>= 1) {
        if (t < ofs) red[t] += red[t + ofs];
        __syncthreads();
    }
    if (t == 0) bsum[b] = red[0];
}

__global__ void k_scan_b(const int* __restrict__ bsum, int* __restrict__ bpre) {
    int t = threadIdx.x;   // 64
    int a = (2 * t     < NBLK_SCAN) ? bsum[2 * t]     : 0;
    int b = (2 * t + 1 < NBLK_SCAN) ? bsum[2 * t + 1] : 0;
    int local = a + b;
    int incl = local;
#pragma unroll
    for (int ofs = 1; ofs < 64; ofs <<= 1) {
        int u = __shfl_up(incl, ofs, 64);
        if (t >= ofs) incl += u;
    }
    int pre = incl - local;
    if (2 * t     < NBLK_SCAN) bpre[2 * t]     = pre;
    if (2 * t + 1 < NBLK_SCAN) bpre[2 * t + 1] = pre + a;
}

// scan C: off/cur, self-loop into csr[off[n]], and bucket COO bases (gcur)
__global__ __launch_bounds__(256) void k_scan_c(const int* __restrict__ deg,
                                                const int* __restrict__ bpre,
                                                int* __restrict__ off,
                                                int* __restrict__ cur,
                                                int* __restrict__ csr,
                                                int* __restrict__ gcur) {
    __shared__ int tsum[256];
    int b = blockIdx.x, t = threadIdx.x;
    int base = b * SCAN_CHUNK + t * 4;
    int d0 = 0, d1 = 0, d2 = 0, d3 = 0;
    if (base + 3 < N_NODES) {
        int4 v = *(const int4*)(deg + base);
        d0 = v.x + 1; d1 = v.y + 1; d2 = v.z + 1; d3 = v.w + 1;
    } else {
        if (base     < N_NODES) d0 = deg[base] + 1;
        if (base + 1 < N_NODES) d1 = deg[base + 1] + 1;
        if (base + 2 < N_NODES) d2 = deg[base + 2] + 1;
        if (base + 3 < N_NODES) d3 = deg[base + 3] + 1;
    }
    int s = d0 + d1 + d2 + d3;
    tsum[t] = s;
    __syncthreads();
    for (int ofs = 1; ofs < 256; ofs <<= 1) {
        int u = (t >= ofs) ? tsum[t - ofs] : 0;
        __syncthreads();
        tsum[t] += u;
        __syncthreads();
    }
    int run = bpre[b] + tsum[t] - s;
    if (base < N_NODES) {
        if ((base & 255) == 0) gcur[base >> SH] = run - base;  // COO bucket base
        off[base] = run; csr[run] = base; cur[base] = run + 1; run += d0;
    }
    if (base + 1 < N_NODES) { off[base + 1] = run; csr[run] = base + 1;
                              cur[base + 1] = run + 1; run += d1; }
    if (base + 2 < N_NODES) { off[base + 2] = run; csr[run] = base + 2;
                              cur[base + 2] = run + 1; run += d2; }
    if (base + 3 < N_NODES) { off[base + 3] = run; csr[run] = base + 3;
                              cur[base + 3] = run + 1; run += d3; }
    if (b == 0 && t == 0) off[N_NODES] = ETOT;
}

// ---------------- kernel B: bin (bucket-major COO) || gemm1 part B ----------
union SmemB {
    struct {
        int2 st[BIN_TILE];          // staged (src,dst), bucket-major
        int  hist[NBUCK + 1];       // counts -> exclusive starts -> cursors
        int  lstart[NBUCK];         // frozen exclusive starts
        int  gbase[NBUCK];          // reserved global bases
        int  tsum[256];
    } bin;
    float xs[8][128];
};

__global__ __launch_bounds__(256) void k_parB(
    const int* __restrict__ src, const int* __restrict__ dst,
    int* __restrict__ gcur, int2* __restrict__ coo,
    const float* __restrict__ x, const float* __restrict__ W,
    const float* __restrict__ asrc, const float* __restrict__ adst,
    __hip_bfloat16* __restrict__ h1b, float* __restrict__ s1,
    float* __restrict__ d1) {
    __shared__ SmemB sm;
    int bid = blockIdx.x, t = threadIdx.x;
    bool isBin = (bid < 12 * NBIN) && (bid % 12 == 0);
    if (isBin) {
        int wb = bid / 12;
        int e0 = wb * BIN_TILE;
        int nE = min(BIN_TILE, E_EDGES - e0);
        for (int i = t; i <= NBUCK; i += 256) sm.bin.hist[i] = 0;
        __syncthreads();
        for (int i = t; i < nE; i += 256)
            atomicAdd(&sm.bin.hist[dst[e0 + i] >> SH], 1);
        __syncthreads();
        // exclusive scan of hist[0..NBUCK-1]
        int i0 = 2 * t, i1 = 2 * t + 1;
        int h0 = (i0 < NBUCK) ? sm.bin.hist[i0] : 0;
        int h1v = (i1 < NBUCK) ? sm.bin.hist[i1] : 0;
        int s = h0 + h1v;
        sm.bin.tsum[t] = s;
        __syncthreads();
        for (int ofs = 1; ofs < 256; ofs <<= 1) {
            int u = (t >= ofs) ? sm.bin.tsum[t - ofs] : 0;
            __syncthreads();
            sm.bin.tsum[t] += u;
            __syncthreads();
        }
        int pre = sm.bin.tsum[t] - s;
        if (i0 < NBUCK) sm.bin.hist[i0] = pre;
        if (i1 < NBUCK) sm.bin.hist[i1] = pre + h0;
        if (t == 255) sm.bin.hist[NBUCK] = sm.bin.tsum[255];  // == nE
        __syncthreads();
        // freeze starts, reserve global space
        for (int i = t; i < NBUCK; i += 256) {
            int st_ = sm.bin.hist[i];
            int cnt = sm.bin.hist[i + 1] - st_;
            sm.bin.lstart[i] = st_;
            if (cnt > 0) sm.bin.gbase[i] = atomicAdd(&gcur[i], cnt);
        }
        __syncthreads();
        // pass 2: stage bucket-major
        for (int i = t; i < nE; i += 256) {
            int sv = src[e0 + i], dv = dst[e0 + i];
            int p = atomicAdd(&sm.bin.hist[dv >> SH], 1);
            sm.bin.st[p] = make_int2(sv, dv);
        }
        __syncthreads();
        // copy out coalesced per-bucket runs
        for (int i = t; i < nE; i += 256) {
            int2 e = sm.bin.st[i];
            int b2 = e.y >> SH;
            coo[sm.bin.gbase[b2] + (i - sm.bin.lstart[b2])] = e;
        }
    } else {
        int gid = (bid < 12 * NBIN) ? (bid - bid / 12 - 1) : (bid - NBIN);
        gemm1_role((G1A + gid) * 8, t, sm.xs, x, W, asrc, adst, h1b, s1, d1);
    }
}

// ---------------- kernel C: fine scatter (1 block/bucket) || gemm1 part C ---
__global__ __launch_bounds__(256) void k_parC(
    const int2* __restrict__ coo, const int* __restrict__ off,
    int* __restrict__ cur, int* __restrict__ csr,
    const float* __restrict__ x, const float* __restrict__ W,
    const float* __restrict__ asrc, const float* __restrict__ adst,
    __hip_bfloat16* __restrict__ h1b, float* __restrict__ s1,
    float* __restrict__ d1) {
    __shared__ float xs[8][128];
    int bid = blockIdx.x, t = threadIdx.x;
    bool isFine = (bid < 8 * NBUCK) && ((bid & 7) == 0);
    if (isFine) {
        int b = bid >> 3;
        int n0 = b << SH;
        int n1 = min(n0 + 256, N_NODES);
        int start = off[n0] - n0;
        int end = off[n1] - n1;
        for (int i = start + t; i < end; i += 256) {
            int2 e = coo[i];
            int slot = atomicAdd(&cur[e.y], 1);
            csr[slot] = e.x;
        }
    } else {
        int gid = (bid < 8 * NBUCK) ? (bid - (bid >> 3) - 1) : (bid - NBUCK);
        gemm1_role((G1A + G1B + gid) * 8, t, xs, x, W, asrc, adst, h1b, s1, d1);
    }
}

// ---------------- layer 1 single-pass softmax-aggregate ---------------------
__global__ __launch_bounds__(256) void k_l1(
    const int* __restrict__ off, const int* __restrict__ csr,
    const float* __restrict__ s1, const float* __restrict__ d1,
    const uint4* __restrict__ h1q, const float* __restrict__ b1,
    float* __restrict__ emb) {
    int t = threadIdx.x;
    int node = blockIdx.x * 4 + (t >> 6);
    int l = t & 63;
    int g = l >> 4, q = l & 15;
    int hb = q >> 1;
    int lo = off[node], hi = off[node + 1];
    float dvh = d1[node * 8 + hb];

    float acc[8];
#pragma unroll
    for (int c = 0; c < 8; ++c) acc[c] = 0.f;
    float den = 0.f;

    int idx = lo + g;
    int sc = 0; uint4 bv = make_uint4(0, 0, 0, 0); float sv = 0.f;
    if (idx < hi) {
        sc = csr[idx];
        bv = h1q[(size_t)sc * 16 + q];
        sv = s1[sc * 8 + hb];
    }
    while (idx < hi) {
        int nidx = idx + 4;
        int sn = 0; uint4 bn = make_uint4(0, 0, 0, 0); float svn = 0.f;
        if (nidx < hi) {
            sn = csr[nidx];
            bn = h1q[(size_t)sn * 16 + q];
            svn = s1[sn * 8 + hb];
        }
        float w = __expf(lrelu(sv + dvh));
        den += w;
        acc[0] = fmaf(w, bflo(bv.x), acc[0]);
        acc[1] = fmaf(w, bfhi(bv.x), acc[1]);
        acc[2] = fmaf(w, bflo(bv.y), acc[2]);
        acc[3] = fmaf(w, bfhi(bv.y), acc[3]);
        acc[4] = fmaf(w, bflo(bv.z), acc[4]);
        acc[5] = fmaf(w, bfhi(bv.z), acc[5]);
        acc[6] = fmaf(w, bflo(bv.w), acc[6]);
        acc[7] = fmaf(w, bfhi(bv.w), acc[7]);
        sc = sn; bv = bn; sv = svn; idx = nidx;
    }
#pragma unroll
    for (int c = 0; c < 8; ++c) {
        acc[c] += __shfl_xor(acc[c], 16, 64);
        acc[c] += __shfl_xor(acc[c], 32, 64);
    }
    den += __shfl_xor(den, 16, 64);
    den += __shfl_xor(den, 32, 64);

    if (l < 16) {
        float r = 1.f / den;
        float vv[8];
#pragma unroll
        for (int c = 0; c < 8; ++c) {
            float v = acc[c] * r + b1[8 * q + c];
            vv[c] = v > 0.f ? v : expm1f(v);
        }
        float4* ep = (float4*)(emb + (size_t)node * 128);
        ep[2 * q]     = make_float4(vv[0], vv[1], vv[2], vv[3]);
        ep[2 * q + 1] = make_float4(vv[4], vv[5], vv[6], vv[7]);
    }
}

// ---------------- layer 2 GEMM: h2(bf16) = emb @ W2 (128->16), s2/d2 --------
__global__ __launch_bounds__(256) void k_gemm2(
    const float* __restrict__ emb, const float* __restrict__ W,
    const float* __restrict__ asrc, const float* __restrict__ adst,
    __hip_bfloat16* __restrict__ h2b, float* __restrict__ s2,
    float* __restrict__ d2) {
    __shared__ float xs[16][129];
    int n0 = blockIdx.x * 16;
    int t = threadIdx.x;
#pragma unroll
    for (int i = 0; i < 8; ++i) {
        int idx = t + i * 256;
        xs[idx >> 7][idx & 127] = emb[(long)n0 * 128 + idx];
    }
    __syncthreads();
    int j = t & 15, sub = t >> 4;
    float acc = 0.f;
    for (int k = 0; k < 128; ++k) acc = fmaf(xs[sub][k], W[k * 16 + j], acc);
    int n = n0 + sub;
    h2b[(long)n * 16 + j] = __float2bfloat16(acc);
    float ps = acc * asrc[j], pd = acc * adst[j];
#pragma unroll
    for (int off = 8; off; off >>= 1) {
        ps += __shfl_down(ps, off, 16);
        pd += __shfl_down(pd, off, 16);
    }
    if (j == 0) { s2[n] = ps; d2[n] = pd; }
}

// ---------------- layer 2 single-pass aggregate + log_softmax ---------------
__global__ __launch_bounds__(256) void k_l2(
    const int* __restrict__ off, const int* __restrict__ csr,
    const float* __restrict__ s2, const float* __restrict__ d2,
    const unsigned int* __restrict__ h2w, const float* __restrict__ b2,
    float* __restrict__ logits) {
    int t = threadIdx.x;
    int node = blockIdx.x * 4 + (t >> 6);
    int l = t & 63;
    int g = l >> 3, p = l & 7;
    int lo = off[node], hi = off[node + 1];
    float dv = d2[node];

    float ax = 0.f, ay = 0.f, den = 0.f;
    for (int idx = lo + g; idx < hi; idx += 8) {
        int s = csr[idx];
        float w = __expf(lrelu(s2[s] + dv));
        den += w;
        unsigned int bv = h2w[(size_t)s * 8 + p];
        ax = fmaf(w, bflo(bv), ax);
        ay = fmaf(w, bfhi(bv), ay);
    }
#pragma unroll
    for (int ofs = 8; ofs < 64; ofs <<= 1) {
        ax += __shfl_xor(ax, ofs, 64);
        ay += __shfl_xor(ay, ofs, 64);
        den += __shfl_xor(den, ofs, 64);
    }
    float r = 1.f / den;
    float v0 = ax * r + b2[2 * p], v1 = ay * r + b2[2 * p + 1];
    float mm = fmaxf(v0, v1);
#pragma unroll
    for (int ofs = 1; ofs < 8; ofs <<= 1) mm = fmaxf(mm, __shfl_xor(mm, ofs, 8));
    float sm = __expf(v0 - mm) + __expf(v1 - mm);
#pragma unroll
    for (int ofs = 1; ofs < 8; ofs <<= 1) sm += __shfl_xor(sm, ofs, 8);
    if (g == 0) {
        float ls = logf(sm);
        logits[node * 16 + 2 * p]     = v0 - mm - ls;
        logits[node * 16 + 2 * p + 1] = v1 - mm - ls;
    }
}

extern "C" void kernel_launch(void* const* d_in, const int* in_sizes, int n_in,
                              void* d_out, int out_size, void* d_ws, size_t ws_size,
                              hipStream_t stream) {
    const float* x   = (const float*)d_in[0];
    const int*   ei  = (const int*)d_in[1];
    const float* W1  = (const float*)d_in[2];
    const float* as1 = (const float*)d_in[3];
    const float* ad1 = (const float*)d_in[4];
    const float* b1  = (const float*)d_in[5];
    const float* W2  = (const float*)d_in[6];
    const float* as2 = (const float*)d_in[7];
    const float* ad2 = (const float*)d_in[8];
    const float* b2  = (const float*)d_in[9];

    float* out    = (float*)d_out;
    float* logits = out;                          // [N,16]
    float* emb    = out + (size_t)N_NODES * 16;   // [N,128]

    float* ws    = (float*)d_ws;
    unsigned int* h1w = (unsigned int*)ws;                    // N*64 words (bf16 x2)
    float* s1    = (float*)(h1w + (size_t)N_NODES * 64);      // N*8
    float* d1    = s1 + (size_t)N_NODES * 8;
    unsigned int* h2w = (unsigned int*)(d1 + (size_t)N_NODES * 8); // N*8 words
    float* s2    = (float*)(h2w + (size_t)N_NODES * 8);       // N
    float* d2v   = s2 + (size_t)N_NODES;
    int*   deg   = (int*)(d2v + (size_t)N_NODES);             // N
    int*   offs  = deg + N_NODES;                             // N+1
    int*   cur   = offs + N_NODES + 1;                        // N
    int*   csr   = cur + N_NODES;                             // ETOT
    int*   bsum  = csr + ETOT;                                // NBLK_SCAN
    int*   bpre  = bsum + NBLK_SCAN;                          // NBLK_SCAN
    int*   gcur  = bpre + NBLK_SCAN;                          // NBUCK
    int2*  coo   = (int2*)(gcur + NBUCK + 1);                 // E_EDGES pairs

    const int* srcp = ei;
    const int* dstp = ei + E_EDGES;

    hipMemsetAsync(deg, 0, (size_t)N_NODES * sizeof(int), stream);

    k_parA<<<HIST_BLOCKS + G1A, 256, 0, stream>>>(dstp, deg, x, W1, as1, ad1,
                                                  (__hip_bfloat16*)h1w, s1, d1);
    k_scan_a<<<NBLK_SCAN, 256, 0, stream>>>(deg, bsum);
    k_scan_b<<<1, 64, 0, stream>>>(bsum, bpre);
    k_scan_c<<<NBLK_SCAN, 256, 0, stream>>>(deg, bpre, offs, cur, csr, gcur);
    k_parB<<<NBIN + G1B, 256, 0, stream>>>(srcp, dstp, gcur, coo,
                                           x, W1, as1, ad1,
                                           (__hip_bfloat16*)h1w, s1, d1);
    k_parC<<<NBUCK + G1C, 256, 0, stream>>>(coo, offs, cur, csr,
                                            x, W1, as1, ad1,
                                            (__hip_bfloat16*)h1w, s1, d1);

    k_l1<<<N_NODES / 4, 256, 0, stream>>>(offs, csr, s1, d1,
                                          (const uint4*)h1w, b1, emb);

    k_gemm2<<<N_NODES / 16, 256, 0, stream>>>(emb, W2, as2, ad2,
                                              (__hip_bfloat16*)h2w, s2, d2v);
    k_l2<<<N_NODES / 4, 256, 0, stream>>>(offs, csr, s2, d2v, h2w, b2, logits);
}

// Round 10
// 356.572 us; speedup vs baseline: 39.5309x; 1.2350x over previous
//
#include <hip/hip_runtime.h>
#include <hip/hip_bf16.h>
#include <math.h>

#define N_NODES 100000
#define E_EDGES 1600000
#define ETOT    (E_EDGES + N_NODES)
#define NEG     0.2f

#define SCAN_CHUNK 1024
#define NBLK_SCAN  ((N_NODES + SCAN_CHUNK - 1) / SCAN_CHUNK)   // 98

// bucketed CSR build
#define SH        8
#define NBUCK     ((N_NODES + 255) >> 8)          // 391
#define BIN_TILE  4096
#define NBIN      ((E_EDGES + BIN_TILE - 1) / BIN_TILE)  // 391
#define LDS_CAP   6016                            // per-bucket staging slots

#define HIST_BLOCKS ((E_EDGES + 1023) / 1024)     // 1563 (4 edges/thread)
#define G1A 5000
#define G1B 4500
#define G1C 3000    // G1A+G1B+G1C == N_NODES/8 == 12500

__device__ inline float lrelu(float x) { return x > 0.f ? x : NEG * x; }
__device__ inline float bflo(unsigned int b) { return __uint_as_float(b << 16); }
__device__ inline float bfhi(unsigned int b) { return __uint_as_float(b & 0xFFFF0000u); }

// ---------------- gemm1 role (device fn): 8 nodes per block -----------------
__device__ __forceinline__ void gemm1_role(
    int n0, int t, float (*xs)[128],
    const float* __restrict__ x, const float* __restrict__ W,
    const float* __restrict__ asrc, const float* __restrict__ adst,
    __hip_bfloat16* __restrict__ h1b, float* __restrict__ s1,
    float* __restrict__ d1) {
#pragma unroll
    for (int i = 0; i < 4; ++i) {
        int idx = t + i * 256;
        xs[idx >> 7][idx & 127] = x[(long)n0 * 128 + idx];
    }
    __syncthreads();
    int j = t & 127, sg = t >> 7;
    float a0 = 0.f, a1 = 0.f, a2 = 0.f, a3 = 0.f;
    for (int k = 0; k < 128; ++k) {
        float w = W[k * 128 + j];
        a0 = fmaf(xs[sg + 0][k], w, a0);
        a1 = fmaf(xs[sg + 2][k], w, a1);
        a2 = fmaf(xs[sg + 4][k], w, a2);
        a3 = fmaf(xs[sg + 6][k], w, a3);
    }
    float as = asrc[j], ad = adst[j];
    float accs[4] = {a0, a1, a2, a3};
#pragma unroll
    for (int i = 0; i < 4; ++i) {
        int n = n0 + sg + 2 * i;
        h1b[(long)n * 128 + j] = __float2bfloat16(accs[i]);
        float ps = accs[i] * as, pd = accs[i] * ad;
#pragma unroll
        for (int off = 8; off; off >>= 1) {
            ps += __shfl_down(ps, off, 16);
            pd += __shfl_down(pd, off, 16);
        }
        if ((j & 15) == 0) {
            s1[n * 8 + (j >> 4)] = ps;
            d1[n * 8 + (j >> 4)] = pd;
        }
    }
}

// ---------------- kernel A: hist (int4) || gemm1 part A (interleaved) -------
__global__ __launch_bounds__(256) void k_parA(
    const int* __restrict__ dst, int* __restrict__ deg,
    const float* __restrict__ x, const float* __restrict__ W,
    const float* __restrict__ asrc, const float* __restrict__ adst,
    __hip_bfloat16* __restrict__ h1b, float* __restrict__ s1,
    float* __restrict__ d1) {
    __shared__ float xs[8][128];
    int bid = blockIdx.x, t = threadIdx.x;
    bool isHist = (bid < 4 * HIST_BLOCKS) && ((bid & 3) == 0);
    if (isHist) {
        int hid = bid >> 2;
        int e0 = hid * 1024 + t * 4;
        if (e0 + 3 < E_EDGES) {
            int4 v = *(const int4*)(dst + e0);
            atomicAdd(&deg[v.x], 1);
            atomicAdd(&deg[v.y], 1);
            atomicAdd(&deg[v.z], 1);
            atomicAdd(&deg[v.w], 1);
        } else {
#pragma unroll
            for (int i = 0; i < 4; ++i)
                if (e0 + i < E_EDGES) atomicAdd(&deg[dst[e0 + i]], 1);
        }
    } else {
        int gid = (bid < 4 * HIST_BLOCKS) ? (bid - (bid >> 2) - 1)
                                          : (bid - HIST_BLOCKS);
        gemm1_role(gid * 8, t, xs, x, W, asrc, adst, h1b, s1, d1);
    }
}

// ---------------- scan (degrees +1 for implicit self-loop) ------------------
__global__ __launch_bounds__(256) void k_scan_a(const int* __restrict__ deg,
                                                int* __restrict__ bsum) {
    __shared__ int red[256];
    int b = blockIdx.x, t = threadIdx.x;
    int base = b * SCAN_CHUNK + t * 4;
    int s = 0;
    if (base + 3 < N_NODES) {
        int4 v = *(const int4*)(deg + base);
        s = v.x + v.y + v.z + v.w + 4;
    } else {
#pragma unroll
        for (int i = 0; i < 4; ++i)
            if (base + i < N_NODES) s += deg[base + i] + 1;
    }
    red[t] = s;
    __syncthreads();
    for (int ofs = 128; ofs; ofs >>= 1) {
        if (t < ofs) red[t] += red[t + ofs];
        __syncthreads();
    }
    if (t == 0) bsum[b] = red[0];
}

__global__ void k_scan_b(const int* __restrict__ bsum, int* __restrict__ bpre) {
    int t = threadIdx.x;   // 64
    int a = (2 * t     < NBLK_SCAN) ? bsum[2 * t]     : 0;
    int b = (2 * t + 1 < NBLK_SCAN) ? bsum[2 * t + 1] : 0;
    int local = a + b;
    int incl = local;
#pragma unroll
    for (int ofs = 1; ofs < 64; ofs <<= 1) {
        int u = __shfl_up(incl, ofs, 64);
        if (t >= ofs) incl += u;
    }
    int pre = incl - local;
    if (2 * t     < NBLK_SCAN) bpre[2 * t]     = pre;
    if (2 * t + 1 < NBLK_SCAN) bpre[2 * t + 1] = pre + a;
}

// scan C: off/cur, self-loop into csr[off[n]], and bucket COO bases (gcur)
__global__ __launch_bounds__(256) void k_scan_c(const int* __restrict__ deg,
                                                const int* __restrict__ bpre,
                                                int* __restrict__ off,
                                                int* __restrict__ cur,
                                                int* __restrict__ csr,
                                                int* __restrict__ gcur) {
    __shared__ int tsum[256];
    int b = blockIdx.x, t = threadIdx.x;
    int base = b * SCAN_CHUNK + t * 4;
    int d0 = 0, d1 = 0, d2 = 0, d3 = 0;
    if (base + 3 < N_NODES) {
        int4 v = *(const int4*)(deg + base);
        d0 = v.x + 1; d1 = v.y + 1; d2 = v.z + 1; d3 = v.w + 1;
    } else {
        if (base     < N_NODES) d0 = deg[base] + 1;
        if (base + 1 < N_NODES) d1 = deg[base + 1] + 1;
        if (base + 2 < N_NODES) d2 = deg[base + 2] + 1;
        if (base + 3 < N_NODES) d3 = deg[base + 3] + 1;
    }
    int s = d0 + d1 + d2 + d3;
    tsum[t] = s;
    __syncthreads();
    for (int ofs = 1; ofs < 256; ofs <<= 1) {
        int u = (t >= ofs) ? tsum[t - ofs] : 0;
        __syncthreads();
        tsum[t] += u;
        __syncthreads();
    }
    int run = bpre[b] + tsum[t] - s;
    if (base < N_NODES) {
        if ((base & 255) == 0) gcur[base >> SH] = run - base;  // COO bucket base
        off[base] = run; csr[run] = base; cur[base] = run + 1; run += d0;
    }
    if (base + 1 < N_NODES) { off[base + 1] = run; csr[run] = base + 1;
                              cur[base + 1] = run + 1; run += d1; }
    if (base + 2 < N_NODES) { off[base + 2] = run; csr[run] = base + 2;
                              cur[base + 2] = run + 1; run += d2; }
    if (base + 3 < N_NODES) { off[base + 3] = run; csr[run] = base + 3;
                              cur[base + 3] = run + 1; run += d3; }
    if (b == 0 && t == 0) off[N_NODES] = ETOT;
}

// ---------------- kernel B: bin (bucket-major COO) || gemm1 part B ----------
union SmemB {
    struct {
        int2 st[BIN_TILE];          // staged (src,dst), bucket-major
        int  hist[NBUCK + 1];       // counts -> exclusive starts -> cursors
        int  lstart[NBUCK];         // frozen exclusive starts
        int  gbase[NBUCK];          // reserved global bases
        int  tsum[256];
    } bin;
    float xs[8][128];
};

__global__ __launch_bounds__(256) void k_parB(
    const int* __restrict__ src, const int* __restrict__ dst,
    int* __restrict__ gcur, int2* __restrict__ coo,
    const float* __restrict__ x, const float* __restrict__ W,
    const float* __restrict__ asrc, const float* __restrict__ adst,
    __hip_bfloat16* __restrict__ h1b, float* __restrict__ s1,
    float* __restrict__ d1) {
    __shared__ SmemB sm;
    int bid = blockIdx.x, t = threadIdx.x;
    bool isBin = (bid < 12 * NBIN) && (bid % 12 == 0);
    if (isBin) {
        int wb = bid / 12;
        int e0 = wb * BIN_TILE;
        int nE = min(BIN_TILE, E_EDGES - e0);
        for (int i = t; i <= NBUCK; i += 256) sm.bin.hist[i] = 0;
        __syncthreads();
        for (int i = t; i < nE; i += 256)
            atomicAdd(&sm.bin.hist[dst[e0 + i] >> SH], 1);
        __syncthreads();
        int i0 = 2 * t, i1 = 2 * t + 1;
        int h0 = (i0 < NBUCK) ? sm.bin.hist[i0] : 0;
        int h1v = (i1 < NBUCK) ? sm.bin.hist[i1] : 0;
        int s = h0 + h1v;
        sm.bin.tsum[t] = s;
        __syncthreads();
        for (int ofs = 1; ofs < 256; ofs <<= 1) {
            int u = (t >= ofs) ? sm.bin.tsum[t - ofs] : 0;
            __syncthreads();
            sm.bin.tsum[t] += u;
            __syncthreads();
        }
        int pre = sm.bin.tsum[t] - s;
        if (i0 < NBUCK) sm.bin.hist[i0] = pre;
        if (i1 < NBUCK) sm.bin.hist[i1] = pre + h0;
        if (t == 255) sm.bin.hist[NBUCK] = sm.bin.tsum[255];
        __syncthreads();
        for (int i = t; i < NBUCK; i += 256) {
            int st_ = sm.bin.hist[i];
            int cnt = sm.bin.hist[i + 1] - st_;
            sm.bin.lstart[i] = st_;
            if (cnt > 0) sm.bin.gbase[i] = atomicAdd(&gcur[i], cnt);
        }
        __syncthreads();
        for (int i = t; i < nE; i += 256) {
            int sv = src[e0 + i], dv = dst[e0 + i];
            int p = atomicAdd(&sm.bin.hist[dv >> SH], 1);
            sm.bin.st[p] = make_int2(sv, dv);
        }
        __syncthreads();
        for (int i = t; i < nE; i += 256) {
            int2 e = sm.bin.st[i];
            int b2 = e.y >> SH;
            coo[sm.bin.gbase[b2] + (i - sm.bin.lstart[b2])] = e;
        }
    } else {
        int gid = (bid < 12 * NBIN) ? (bid - bid / 12 - 1) : (bid - NBIN);
        gemm1_role((G1A + gid) * 8, t, sm.xs, x, W, asrc, adst, h1b, s1, d1);
    }
}

// ---------------- kernel C: fine reorder in LDS (1 block/bucket) || gemm1 ---
union SmemC {
    struct {
        int lcur[256];
        int lsrc[LDS_CAP];
    } fine;
    float xs[8][128];
};

__global__ __launch_bounds__(256) void k_parC(
    const int2* __restrict__ coo, const int* __restrict__ off,
    int* __restrict__ cur, int* __restrict__ csr,
    const float* __restrict__ x, const float* __restrict__ W,
    const float* __restrict__ asrc, const float* __restrict__ adst,
    __hip_bfloat16* __restrict__ h1b, float* __restrict__ s1,
    float* __restrict__ d1) {
    __shared__ SmemC sm;
    int bid = blockIdx.x, t = threadIdx.x;
    bool isFine = (bid < 8 * NBUCK) && ((bid & 7) == 0);
    if (isFine) {
        int b = bid >> 3;
        int n0 = b << SH;
        int n1 = min(n0 + 256, N_NODES);
        int nn = n1 - n0;
        int base = off[n0], endv = off[n1];
        int ecnt = endv - base;
        int cooStart = base - n0;       // == off[n0] - n0
        int cooEnd = endv - n1;         // == off[n1] - n1
        if (ecnt <= LDS_CAP) {
            if (t < nn) {
                int o = off[n0 + t] - base;
                sm.fine.lcur[t] = o + 1;        // slot 0 = self-loop
                sm.fine.lsrc[o] = n0 + t;
            }
            __syncthreads();
            for (int i = cooStart + t; i < cooEnd; i += 256) {
                int2 e = coo[i];
                int p = atomicAdd(&sm.fine.lcur[e.y - n0], 1);
                sm.fine.lsrc[p] = e.x;
            }
            __syncthreads();
            for (int i = t; i < ecnt; i += 256)
                csr[base + i] = sm.fine.lsrc[i];
        } else {
            // fallback: global atomic scatter (self-loops already placed)
            for (int i = cooStart + t; i < cooEnd; i += 256) {
                int2 e = coo[i];
                int slot = atomicAdd(&cur[e.y], 1);
                csr[slot] = e.x;
            }
        }
    } else {
        int gid = (bid < 8 * NBUCK) ? (bid - (bid >> 3) - 1) : (bid - NBUCK);
        gemm1_role((G1A + G1B + gid) * 8, t, sm.xs, x, W, asrc, adst,
                   h1b, s1, d1);
    }
}

// ---------------- layer 1 single-pass softmax-aggregate ---------------------
__global__ __launch_bounds__(256) void k_l1(
    const int* __restrict__ off, const int* __restrict__ csr,
    const float* __restrict__ s1, const float* __restrict__ d1,
    const uint4* __restrict__ h1q, const float* __restrict__ b1,
    float* __restrict__ emb) {
    int t = threadIdx.x;
    int node = blockIdx.x * 4 + (t >> 6);
    int l = t & 63;
    int g = l >> 4, q = l & 15;
    int hb = q >> 1;
    int lo = off[node], hi = off[node + 1];
    float dvh = d1[node * 8 + hb];

    float acc[8];
#pragma unroll
    for (int c = 0; c < 8; ++c) acc[c] = 0.f;
    float den = 0.f;

    int idx = lo + g;
    int sc = 0; uint4 bv = make_uint4(0, 0, 0, 0); float sv = 0.f;
    if (idx < hi) {
        sc = csr[idx];
        bv = h1q[(size_t)sc * 16 + q];
        sv = s1[sc * 8 + hb];
    }
    while (idx < hi) {
        int nidx = idx + 4;
        int sn = 0; uint4 bn = make_uint4(0, 0, 0, 0); float svn = 0.f;
        if (nidx < hi) {
            sn = csr[nidx];
            bn = h1q[(size_t)sn * 16 + q];
            svn = s1[sn * 8 + hb];
        }
        float w = __expf(lrelu(sv + dvh));
        den += w;
        acc[0] = fmaf(w, bflo(bv.x), acc[0]);
        acc[1] = fmaf(w, bfhi(bv.x), acc[1]);
        acc[2] = fmaf(w, bflo(bv.y), acc[2]);
        acc[3] = fmaf(w, bfhi(bv.y), acc[3]);
        acc[4] = fmaf(w, bflo(bv.z), acc[4]);
        acc[5] = fmaf(w, bfhi(bv.z), acc[5]);
        acc[6] = fmaf(w, bflo(bv.w), acc[6]);
        acc[7] = fmaf(w, bfhi(bv.w), acc[7]);
        sc = sn; bv = bn; sv = svn; idx = nidx;
    }
#pragma unroll
    for (int c = 0; c < 8; ++c) {
        acc[c] += __shfl_xor(acc[c], 16, 64);
        acc[c] += __shfl_xor(acc[c], 32, 64);
    }
    den += __shfl_xor(den, 16, 64);
    den += __shfl_xor(den, 32, 64);

    if (l < 16) {
        float r = 1.f / den;
        float vv[8];
#pragma unroll
        for (int c = 0; c < 8; ++c) {
            float v = acc[c] * r + b1[8 * q + c];
            vv[c] = v > 0.f ? v : expm1f(v);
        }
        float4* ep = (float4*)(emb + (size_t)node * 128);
        ep[2 * q]     = make_float4(vv[0], vv[1], vv[2], vv[3]);
        ep[2 * q + 1] = make_float4(vv[4], vv[5], vv[6], vv[7]);
    }
}

// ---------------- layer 2 GEMM: h2(bf16) = emb @ W2 (128->16), s2/d2 --------
__global__ __launch_bounds__(256) void k_gemm2(
    const float* __restrict__ emb, const float* __restrict__ W,
    const float* __restrict__ asrc, const float* __restrict__ adst,
    __hip_bfloat16* __restrict__ h2b, float* __restrict__ s2,
    float* __restrict__ d2) {
    __shared__ float xs[16][129];
    int n0 = blockIdx.x * 16;
    int t = threadIdx.x;
#pragma unroll
    for (int i = 0; i < 8; ++i) {
        int idx = t + i * 256;
        xs[idx >> 7][idx & 127] = emb[(long)n0 * 128 + idx];
    }
    __syncthreads();
    int j = t & 15, sub = t >> 4;
    float acc = 0.f;
    for (int k = 0; k < 128; ++k) acc = fmaf(xs[sub][k], W[k * 16 + j], acc);
    int n = n0 + sub;
    h2b[(long)n * 16 + j] = __float2bfloat16(acc);
    float ps = acc * asrc[j], pd = acc * adst[j];
#pragma unroll
    for (int off = 8; off; off >>= 1) {
        ps += __shfl_down(ps, off, 16);
        pd += __shfl_down(pd, off, 16);
    }
    if (j == 0) { s2[n] = ps; d2[n] = pd; }
}

// ---------------- layer 2 single-pass aggregate + log_softmax ---------------
__global__ __launch_bounds__(256) void k_l2(
    const int* __restrict__ off, const int* __restrict__ csr,
    const float* __restrict__ s2, const float* __restrict__ d2,
    const unsigned int* __restrict__ h2w, const float* __restrict__ b2,
    float* __restrict__ logits) {
    int t = threadIdx.x;
    int node = blockIdx.x * 4 + (t >> 6);
    int l = t & 63;
    int g = l >> 3, p = l & 7;
    int lo = off[node], hi = off[node + 1];
    float dv = d2[node];

    float ax = 0.f, ay = 0.f, den = 0.f;
    for (int idx = lo + g; idx < hi; idx += 8) {
        int s = csr[idx];
        float w = __expf(lrelu(s2[s] + dv));
        den += w;
        unsigned int bv = h2w[(size_t)s * 8 + p];
        ax = fmaf(w, bflo(bv), ax);
        ay = fmaf(w, bfhi(bv), ay);
    }
#pragma unroll
    for (int ofs = 8; ofs < 64; ofs <<= 1) {
        ax += __shfl_xor(ax, ofs, 64);
        ay += __shfl_xor(ay, ofs, 64);
        den += __shfl_xor(den, ofs, 64);
    }
    float r = 1.f / den;
    float v0 = ax * r + b2[2 * p], v1 = ay * r + b2[2 * p + 1];
    float mm = fmaxf(v0, v1);
#pragma unroll
    for (int ofs = 1; ofs < 8; ofs <<= 1) mm = fmaxf(mm, __shfl_xor(mm, ofs, 8));
    float sm = __expf(v0 - mm) + __expf(v1 - mm);
#pragma unroll
    for (int ofs = 1; ofs < 8; ofs <<= 1) sm += __shfl_xor(sm, ofs, 8);
    if (g == 0) {
        float ls = logf(sm);
        logits[node * 16 + 2 * p]     = v0 - mm - ls;
        logits[node * 16 + 2 * p + 1] = v1 - mm - ls;
    }
}

extern "C" void kernel_launch(void* const* d_in, const int* in_sizes, int n_in,
                              void* d_out, int out_size, void* d_ws, size_t ws_size,
                              hipStream_t stream) {
    const float* x   = (const float*)d_in[0];
    const int*   ei  = (const int*)d_in[1];
    const float* W1  = (const float*)d_in[2];
    const float* as1 = (const float*)d_in[3];
    const float* ad1 = (const float*)d_in[4];
    const float* b1  = (const float*)d_in[5];
    const float* W2  = (const float*)d_in[6];
    const float* as2 = (const float*)d_in[7];
    const float* ad2 = (const float*)d_in[8];
    const float* b2  = (const float*)d_in[9];

    float* out    = (float*)d_out;
    float* logits = out;                          // [N,16]
    float* emb    = out + (size_t)N_NODES * 16;   // [N,128]

    float* ws    = (float*)d_ws;
    unsigned int* h1w = (unsigned int*)ws;                    // N*64 words (bf16 x2)
    float* s1    = (float*)(h1w + (size_t)N_NODES * 64);      // N*8
    float* d1    = s1 + (size_t)N_NODES * 8;
    unsigned int* h2w = (unsigned int*)(d1 + (size_t)N_NODES * 8); // N*8 words
    float* s2    = (float*)(h2w + (size_t)N_NODES * 8);       // N
    float* d2v   = s2 + (size_t)N_NODES;
    int*   deg   = (int*)(d2v + (size_t)N_NODES);             // N
    int*   offs  = deg + N_NODES;                             // N+1
    int*   cur   = offs + N_NODES + 1;                        // N
    int*   csr   = cur + N_NODES;                             // ETOT
    int*   bsum  = csr + ETOT;                                // NBLK_SCAN
    int*   bpre  = bsum + NBLK_SCAN;                          // NBLK_SCAN
    int*   gcur  = bpre + NBLK_SCAN;                          // NBUCK
    int2*  coo   = (int2*)(gcur + NBUCK + 1);                 // E_EDGES pairs

    const int* srcp = ei;
    const int* dstp = ei + E_EDGES;

    hipMemsetAsync(deg, 0, (size_t)N_NODES * sizeof(int), stream);

    k_parA<<<HIST_BLOCKS + G1A, 256, 0, stream>>>(dstp, deg, x, W1, as1, ad1,
                                                  (__hip_bfloat16*)h1w, s1, d1);
    k_scan_a<<<NBLK_SCAN, 256, 0, stream>>>(deg, bsum);
    k_scan_b<<<1, 64, 0, stream>>>(bsum, bpre);
    k_scan_c<<<NBLK_SCAN, 256, 0, stream>>>(deg, bpre, offs, cur, csr, gcur);
    k_parB<<<NBIN + G1B, 256, 0, stream>>>(srcp, dstp, gcur, coo,
                                           x, W1, as1, ad1,
                                           (__hip_bfloat16*)h1w, s1, d1);
    k_parC<<<NBUCK + G1C, 256, 0, stream>>>(coo, offs, cur, csr,
                                            x, W1, as1, ad1,
                                            (__hip_bfloat16*)h1w, s1, d1);

    k_l1<<<N_NODES / 4, 256, 0, stream>>>(offs, csr, s1, d1,
                                          (const uint4*)h1w, b1, emb);

    k_gemm2<<<N_NODES / 16, 256, 0, stream>>>(emb, W2, as2, ad2,
                                              (__hip_bfloat16*)h2w, s2, d2v);
    k_l2<<<N_NODES / 4, 256, 0, stream>>>(offs, csr, s2, d2v, h2w, b2, logits);
}

// Round 11
// 356.544 us; speedup vs baseline: 39.5340x; 1.0001x over previous
//
#include <hip/hip_runtime.h>
#include <hip/hip_bf16.h>
#include <math.h>

#define N_NODES 100000
#define E_EDGES 1600000
#define ETOT    (E_EDGES + N_NODES)
#define NEG     0.2f

#define SCAN_CHUNK 1024
#define NBLK_SCAN  ((N_NODES + SCAN_CHUNK - 1) / SCAN_CHUNK)   // 98

// bucketed CSR build
#define SH        8
#define NBUCK     ((N_NODES + 255) >> 8)          // 391
#define BIN_TILE  4096
#define NBIN      ((E_EDGES + BIN_TILE - 1) / BIN_TILE)  // 391
#define LDS_CAP   6016                            // per-bucket staging slots

#define HIST_BLOCKS ((E_EDGES + 1023) / 1024)     // 1563 (4 edges/thread)
#define G1A 5000
#define G1B 4500
#define G1C 3000    // G1A+G1B+G1C == N_NODES/8 == 12500

__device__ inline float lrelu(float x) { return x > 0.f ? x : NEG * x; }
__device__ inline float bflo(unsigned int b) { return __uint_as_float(b << 16); }
__device__ inline float bfhi(unsigned int b) { return __uint_as_float(b & 0xFFFF0000u); }

// ---------------- gemm1 role (device fn): 8 nodes per block -----------------
__device__ __forceinline__ void gemm1_role(
    int n0, int t, float (*xs)[128],
    const float* __restrict__ x, const float* __restrict__ W,
    const float* __restrict__ asrc, const float* __restrict__ adst,
    __hip_bfloat16* __restrict__ h1b, float* __restrict__ s1,
    float* __restrict__ d1) {
#pragma unroll
    for (int i = 0; i < 4; ++i) {
        int idx = t + i * 256;
        xs[idx >> 7][idx & 127] = x[(long)n0 * 128 + idx];
    }
    __syncthreads();
    int j = t & 127, sg = t >> 7;
    float a0 = 0.f, a1 = 0.f, a2 = 0.f, a3 = 0.f;
    for (int k = 0; k < 128; ++k) {
        float w = W[k * 128 + j];
        a0 = fmaf(xs[sg + 0][k], w, a0);
        a1 = fmaf(xs[sg + 2][k], w, a1);
        a2 = fmaf(xs[sg + 4][k], w, a2);
        a3 = fmaf(xs[sg + 6][k], w, a3);
    }
    float as = asrc[j], ad = adst[j];
    float accs[4] = {a0, a1, a2, a3};
#pragma unroll
    for (int i = 0; i < 4; ++i) {
        int n = n0 + sg + 2 * i;
        h1b[(long)n * 128 + j] = __float2bfloat16(accs[i]);
        float ps = accs[i] * as, pd = accs[i] * ad;
#pragma unroll
        for (int off = 8; off; off >>= 1) {
            ps += __shfl_down(ps, off, 16);
            pd += __shfl_down(pd, off, 16);
        }
        if ((j & 15) == 0) {
            s1[n * 8 + (j >> 4)] = ps;
            d1[n * 8 + (j >> 4)] = pd;
        }
    }
}

// ---------------- kernel A: hist (int4) || gemm1 part A (interleaved) -------
__global__ __launch_bounds__(256) void k_parA(
    const int* __restrict__ dst, int* __restrict__ deg,
    const float* __restrict__ x, const float* __restrict__ W,
    const float* __restrict__ asrc, const float* __restrict__ adst,
    __hip_bfloat16* __restrict__ h1b, float* __restrict__ s1,
    float* __restrict__ d1) {
    __shared__ float xs[8][128];
    int bid = blockIdx.x, t = threadIdx.x;
    bool isHist = (bid < 4 * HIST_BLOCKS) && ((bid & 3) == 0);
    if (isHist) {
        int hid = bid >> 2;
        int e0 = hid * 1024 + t * 4;
        if (e0 + 3 < E_EDGES) {
            int4 v = *(const int4*)(dst + e0);
            atomicAdd(&deg[v.x], 1);
            atomicAdd(&deg[v.y], 1);
            atomicAdd(&deg[v.z], 1);
            atomicAdd(&deg[v.w], 1);
        } else {
#pragma unroll
            for (int i = 0; i < 4; ++i)
                if (e0 + i < E_EDGES) atomicAdd(&deg[dst[e0 + i]], 1);
        }
    } else {
        int gid = (bid < 4 * HIST_BLOCKS) ? (bid - (bid >> 2) - 1)
                                          : (bid - HIST_BLOCKS);
        gemm1_role(gid * 8, t, xs, x, W, asrc, adst, h1b, s1, d1);
    }
}

// ---------------- scan (degrees +1 for implicit self-loop) ------------------
__global__ __launch_bounds__(256) void k_scan_a(const int* __restrict__ deg,
                                                int* __restrict__ bsum) {
    __shared__ int red[256];
    int b = blockIdx.x, t = threadIdx.x;
    int base = b * SCAN_CHUNK + t * 4;
    int s = 0;
    if (base + 3 < N_NODES) {
        int4 v = *(const int4*)(deg + base);
        s = v.x + v.y + v.z + v.w + 4;
    } else {
#pragma unroll
        for (int i = 0; i < 4; ++i)
            if (base + i < N_NODES) s += deg[base + i] + 1;
    }
    red[t] = s;
    __syncthreads();
    for (int ofs = 128; ofs; ofs >>= 1) {
        if (t < ofs) red[t] += red[t + ofs];
        __syncthreads();
    }
    if (t == 0) bsum[b] = red[0];
}

__global__ void k_scan_b(const int* __restrict__ bsum, int* __restrict__ bpre) {
    int t = threadIdx.x;   // 64
    int a = (2 * t     < NBLK_SCAN) ? bsum[2 * t]     : 0;
    int b = (2 * t + 1 < NBLK_SCAN) ? bsum[2 * t + 1] : 0;
    int local = a + b;
    int incl = local;
#pragma unroll
    for (int ofs = 1; ofs < 64; ofs <<= 1) {
        int u = __shfl_up(incl, ofs, 64);
        if (t >= ofs) incl += u;
    }
    int pre = incl - local;
    if (2 * t     < NBLK_SCAN) bpre[2 * t]     = pre;
    if (2 * t + 1 < NBLK_SCAN) bpre[2 * t + 1] = pre + a;
}

// scan C: off/cur, self-loop into csr[off[n]], and bucket COO bases (gcur)
__global__ __launch_bounds__(256) void k_scan_c(const int* __restrict__ deg,
                                                const int* __restrict__ bpre,
                                                int* __restrict__ off,
                                                int* __restrict__ cur,
                                                int* __restrict__ csr,
                                                int* __restrict__ gcur) {
    __shared__ int tsum[256];
    int b = blockIdx.x, t = threadIdx.x;
    int base = b * SCAN_CHUNK + t * 4;
    int d0 = 0, d1 = 0, d2 = 0, d3 = 0;
    if (base + 3 < N_NODES) {
        int4 v = *(const int4*)(deg + base);
        d0 = v.x + 1; d1 = v.y + 1; d2 = v.z + 1; d3 = v.w + 1;
    } else {
        if (base     < N_NODES) d0 = deg[base] + 1;
        if (base + 1 < N_NODES) d1 = deg[base + 1] + 1;
        if (base + 2 < N_NODES) d2 = deg[base + 2] + 1;
        if (base + 3 < N_NODES) d3 = deg[base + 3] + 1;
    }
    int s = d0 + d1 + d2 + d3;
    tsum[t] = s;
    __syncthreads();
    for (int ofs = 1; ofs < 256; ofs <<= 1) {
        int u = (t >= ofs) ? tsum[t - ofs] : 0;
        __syncthreads();
        tsum[t] += u;
        __syncthreads();
    }
    int run = bpre[b] + tsum[t] - s;
    if (base < N_NODES) {
        if ((base & 255) == 0) gcur[base >> SH] = run - base;  // COO bucket base
        off[base] = run; csr[run] = base; cur[base] = run + 1; run += d0;
    }
    if (base + 1 < N_NODES) { off[base + 1] = run; csr[run] = base + 1;
                              cur[base + 1] = run + 1; run += d1; }
    if (base + 2 < N_NODES) { off[base + 2] = run; csr[run] = base + 2;
                              cur[base + 2] = run + 1; run += d2; }
    if (base + 3 < N_NODES) { off[base + 3] = run; csr[run] = base + 3;
                              cur[base + 3] = run + 1; run += d3; }
    if (b == 0 && t == 0) off[N_NODES] = ETOT;
}

// ---------------- kernel B: bin (bucket-major COO) || gemm1 part B ----------
union SmemB {
    struct {
        int2 st[BIN_TILE];          // staged (src,dst), bucket-major
        int  hist[NBUCK + 1];       // counts -> exclusive starts -> cursors
        int  lstart[NBUCK];         // frozen exclusive starts
        int  gbase[NBUCK];          // reserved global bases
        int  tsum[256];
    } bin;
    float xs[8][128];
};

__global__ __launch_bounds__(256) void k_parB(
    const int* __restrict__ src, const int* __restrict__ dst,
    int* __restrict__ gcur, int2* __restrict__ coo,
    const float* __restrict__ x, const float* __restrict__ W,
    const float* __restrict__ asrc, const float* __restrict__ adst,
    __hip_bfloat16* __restrict__ h1b, float* __restrict__ s1,
    float* __restrict__ d1) {
    __shared__ SmemB sm;
    int bid = blockIdx.x, t = threadIdx.x;
    bool isBin = (bid < 12 * NBIN) && (bid % 12 == 0);
    if (isBin) {
        int wb = bid / 12;
        int e0 = wb * BIN_TILE;
        int nE = min(BIN_TILE, E_EDGES - e0);
        for (int i = t; i <= NBUCK; i += 256) sm.bin.hist[i] = 0;
        __syncthreads();
        for (int i = t; i < nE; i += 256)
            atomicAdd(&sm.bin.hist[dst[e0 + i] >> SH], 1);
        __syncthreads();
        int i0 = 2 * t, i1 = 2 * t + 1;
        int h0 = (i0 < NBUCK) ? sm.bin.hist[i0] : 0;
        int h1v = (i1 < NBUCK) ? sm.bin.hist[i1] : 0;
        int s = h0 + h1v;
        sm.bin.tsum[t] = s;
        __syncthreads();
        for (int ofs = 1; ofs < 256; ofs <<= 1) {
            int u = (t >= ofs) ? sm.bin.tsum[t - ofs] : 0;
            __syncthreads();
            sm.bin.tsum[t] += u;
            __syncthreads();
        }
        int pre = sm.bin.tsum[t] - s;
        if (i0 < NBUCK) sm.bin.hist[i0] = pre;
        if (i1 < NBUCK) sm.bin.hist[i1] = pre + h0;
        if (t == 255) sm.bin.hist[NBUCK] = sm.bin.tsum[255];
        __syncthreads();
        for (int i = t; i < NBUCK; i += 256) {
            int st_ = sm.bin.hist[i];
            int cnt = sm.bin.hist[i + 1] - st_;
            sm.bin.lstart[i] = st_;
            if (cnt > 0) sm.bin.gbase[i] = atomicAdd(&gcur[i], cnt);
        }
        __syncthreads();
        for (int i = t; i < nE; i += 256) {
            int sv = src[e0 + i], dv = dst[e0 + i];
            int p = atomicAdd(&sm.bin.hist[dv >> SH], 1);
            sm.bin.st[p] = make_int2(sv, dv);
        }
        __syncthreads();
        for (int i = t; i < nE; i += 256) {
            int2 e = sm.bin.st[i];
            int b2 = e.y >> SH;
            coo[sm.bin.gbase[b2] + (i - sm.bin.lstart[b2])] = e;
        }
    } else {
        int gid = (bid < 12 * NBIN) ? (bid - bid / 12 - 1) : (bid - NBIN);
        gemm1_role((G1A + gid) * 8, t, sm.xs, x, W, asrc, adst, h1b, s1, d1);
    }
}

// ---------------- kernel C: fine reorder in LDS (1 block/bucket) || gemm1 ---
union SmemC {
    struct {
        int lcur[256];
        int lsrc[LDS_CAP];
    } fine;
    float xs[8][128];
};

__global__ __launch_bounds__(256) void k_parC(
    const int2* __restrict__ coo, const int* __restrict__ off,
    int* __restrict__ cur, int* __restrict__ csr,
    const float* __restrict__ x, const float* __restrict__ W,
    const float* __restrict__ asrc, const float* __restrict__ adst,
    __hip_bfloat16* __restrict__ h1b, float* __restrict__ s1,
    float* __restrict__ d1) {
    __shared__ SmemC sm;
    int bid = blockIdx.x, t = threadIdx.x;
    bool isFine = (bid < 8 * NBUCK) && ((bid & 7) == 0);
    if (isFine) {
        int b = bid >> 3;
        int n0 = b << SH;
        int n1 = min(n0 + 256, N_NODES);
        int nn = n1 - n0;
        int base = off[n0], endv = off[n1];
        int ecnt = endv - base;
        int cooStart = base - n0;       // == off[n0] - n0
        int cooEnd = endv - n1;         // == off[n1] - n1
        if (ecnt <= LDS_CAP) {
            if (t < nn) {
                int o = off[n0 + t] - base;
                sm.fine.lcur[t] = o + 1;        // slot 0 = self-loop
                sm.fine.lsrc[o] = n0 + t;
            }
            __syncthreads();
            for (int i = cooStart + t; i < cooEnd; i += 256) {
                int2 e = coo[i];
                int p = atomicAdd(&sm.fine.lcur[e.y - n0], 1);
                sm.fine.lsrc[p] = e.x;
            }
            __syncthreads();
            for (int i = t; i < ecnt; i += 256)
                csr[base + i] = sm.fine.lsrc[i];
        } else {
            // fallback: global atomic scatter (self-loops already placed)
            for (int i = cooStart + t; i < cooEnd; i += 256) {
                int2 e = coo[i];
                int slot = atomicAdd(&cur[e.y], 1);
                csr[slot] = e.x;
            }
        }
    } else {
        int gid = (bid < 8 * NBUCK) ? (bid - (bid >> 3) - 1) : (bid - NBUCK);
        gemm1_role((G1A + G1B + gid) * 8, t, sm.xs, x, W, asrc, adst,
                   h1b, s1, d1);
    }
}

// ---------------- layer 1 single-pass softmax-aggregate ---------------------
__global__ __launch_bounds__(256) void k_l1(
    const int* __restrict__ off, const int* __restrict__ csr,
    const float* __restrict__ s1, const float* __restrict__ d1,
    const uint4* __restrict__ h1q, const float* __restrict__ b1,
    float* __restrict__ emb) {
    int t = threadIdx.x;
    int node = blockIdx.x * 4 + (t >> 6);
    int l = t & 63;
    int g = l >> 4, q = l & 15;
    int hb = q >> 1;
    int lo = off[node], hi = off[node + 1];
    float dvh = d1[node * 8 + hb];

    float acc[8];
#pragma unroll
    for (int c = 0; c < 8; ++c) acc[c] = 0.f;
    float den = 0.f;

    int idx = lo + g;
    int sc = 0; uint4 bv = make_uint4(0, 0, 0, 0); float sv = 0.f;
    if (idx < hi) {
        sc = csr[idx];
        bv = h1q[(size_t)sc * 16 + q];
        sv = s1[sc * 8 + hb];
    }
    while (idx < hi) {
        int nidx = idx + 4;
        int sn = 0; uint4 bn = make_uint4(0, 0, 0, 0); float svn = 0.f;
        if (nidx < hi) {
            sn = csr[nidx];
            bn = h1q[(size_t)sn * 16 + q];
            svn = s1[sn * 8 + hb];
        }
        float w = __expf(lrelu(sv + dvh));
        den += w;
        acc[0] = fmaf(w, bflo(bv.x), acc[0]);
        acc[1] = fmaf(w, bfhi(bv.x), acc[1]);
        acc[2] = fmaf(w, bflo(bv.y), acc[2]);
        acc[3] = fmaf(w, bfhi(bv.y), acc[3]);
        acc[4] = fmaf(w, bflo(bv.z), acc[4]);
        acc[5] = fmaf(w, bfhi(bv.z), acc[5]);
        acc[6] = fmaf(w, bflo(bv.w), acc[6]);
        acc[7] = fmaf(w, bfhi(bv.w), acc[7]);
        sc = sn; bv = bn; sv = svn; idx = nidx;
    }
#pragma unroll
    for (int c = 0; c < 8; ++c) {
        acc[c] += __shfl_xor(acc[c], 16, 64);
        acc[c] += __shfl_xor(acc[c], 32, 64);
    }
    den += __shfl_xor(den, 16, 64);
    den += __shfl_xor(den, 32, 64);

    if (l < 16) {
        float r = 1.f / den;
        float vv[8];
#pragma unroll
        for (int c = 0; c < 8; ++c) {
            float v = acc[c] * r + b1[8 * q + c];
            vv[c] = v > 0.f ? v : expm1f(v);
        }
        float4* ep = (float4*)(emb + (size_t)node * 128);
        ep[2 * q]     = make_float4(vv[0], vv[1], vv[2], vv[3]);
        ep[2 * q + 1] = make_float4(vv[4], vv[5], vv[6], vv[7]);
    }
}

// ---------------- layer 2 GEMM: h2(bf16) = emb @ W2 (128->16), s2/d2 --------
__global__ __launch_bounds__(256) void k_gemm2(
    const float* __restrict__ emb, const float* __restrict__ W,
    const float* __restrict__ asrc, const float* __restrict__ adst,
    __hip_bfloat16* __restrict__ h2b, float* __restrict__ s2,
    float* __restrict__ d2) {
    __shared__ float xs[16][129];
    int n0 = blockIdx.x * 16;
    int t = threadIdx.x;
#pragma unroll
    for (int i = 0; i < 8; ++i) {
        int idx = t + i * 256;
        xs[idx >> 7][idx & 127] = emb[(long)n0 * 128 + idx];
    }
    __syncthreads();
    int j = t & 15, sub = t >> 4;
    float acc = 0.f;
    for (int k = 0; k < 128; ++k) acc = fmaf(xs[sub][k], W[k * 16 + j], acc);
    int n = n0 + sub;
    h2b[(long)n * 16 + j] = __float2bfloat16(acc);
    float ps = acc * asrc[j], pd = acc * adst[j];
#pragma unroll
    for (int off = 8; off; off >>= 1) {
        ps += __shfl_down(ps, off, 16);
        pd += __shfl_down(pd, off, 16);
    }
    if (j == 0) { s2[n] = ps; d2[n] = pd; }
}

// ---------------- layer 2 single-pass aggregate + log_softmax ---------------
__global__ __launch_bounds__(256) void k_l2(
    const int* __restrict__ off, const int* __restrict__ csr,
    const float* __restrict__ s2, const float* __restrict__ d2,
    const unsigned int* __restrict__ h2w, const float* __restrict__ b2,
    float* __restrict__ logits) {
    int t = threadIdx.x;
    int node = blockIdx.x * 4 + (t >> 6);
    int l = t & 63;
    int g = l >> 3, p = l & 7;
    int lo = off[node], hi = off[node + 1];
    float dv = d2[node];

    float ax = 0.f, ay = 0.f, den = 0.f;
    for (int idx = lo + g; idx < hi; idx += 8) {
        int s = csr[idx];
        float w = __expf(lrelu(s2[s] + dv));
        den += w;
        unsigned int bv = h2w[(size_t)s * 8 + p];
        ax = fmaf(w, bflo(bv), ax);
        ay = fmaf(w, bfhi(bv), ay);
    }
#pragma unroll
    for (int ofs = 8; ofs < 64; ofs <<= 1) {
        ax += __shfl_xor(ax, ofs, 64);
        ay += __shfl_xor(ay, ofs, 64);
        den += __shfl_xor(den, ofs, 64);
    }
    float r = 1.f / den;
    float v0 = ax * r + b2[2 * p], v1 = ay * r + b2[2 * p + 1];
    float mm = fmaxf(v0, v1);
#pragma unroll
    for (int ofs = 1; ofs < 8; ofs <<= 1) mm = fmaxf(mm, __shfl_xor(mm, ofs, 8));
    float sm = __expf(v0 - mm) + __expf(v1 - mm);
#pragma unroll
    for (int ofs = 1; ofs < 8; ofs <<= 1) sm += __shfl_xor(sm, ofs, 8);
    if (g == 0) {
        float ls = logf(sm);
        logits[node * 16 + 2 * p]     = v0 - mm - ls;
        logits[node * 16 + 2 * p + 1] = v1 - mm - ls;
    }
}

extern "C" void kernel_launch(void* const* d_in, const int* in_sizes, int n_in,
                              void* d_out, int out_size, void* d_ws, size_t ws_size,
                              hipStream_t stream) {
    const float* x   = (const float*)d_in[0];
    const int*   ei  = (const int*)d_in[1];
    const float* W1  = (const float*)d_in[2];
    const float* as1 = (const float*)d_in[3];
    const float* ad1 = (const float*)d_in[4];
    const float* b1  = (const float*)d_in[5];
    const float* W2  = (const float*)d_in[6];
    const float* as2 = (const float*)d_in[7];
    const float* ad2 = (const float*)d_in[8];
    const float* b2  = (const float*)d_in[9];

    float* out    = (float*)d_out;
    float* logits = out;                          // [N,16]
    float* emb    = out + (size_t)N_NODES * 16;   // [N,128]

    float* ws    = (float*)d_ws;
    unsigned int* h1w = (unsigned int*)ws;                    // N*64 words (bf16 x2)
    float* s1    = (float*)(h1w + (size_t)N_NODES * 64);      // N*8
    float* d1    = s1 + (size_t)N_NODES * 8;
    unsigned int* h2w = (unsigned int*)(d1 + (size_t)N_NODES * 8); // N*8 words
    float* s2    = (float*)(h2w + (size_t)N_NODES * 8);       // N
    float* d2v   = s2 + (size_t)N_NODES;
    int*   deg   = (int*)(d2v + (size_t)N_NODES);             // N
    int*   offs  = deg + N_NODES;                             // N+1
    int*   cur   = offs + N_NODES + 1;                        // N
    int*   csr   = cur + N_NODES;                             // ETOT
    int*   bsum  = csr + ETOT;                                // NBLK_SCAN
    int*   bpre  = bsum + NBLK_SCAN;                          // NBLK_SCAN
    int*   gcur  = bpre + NBLK_SCAN;                          // NBUCK
    int2*  coo   = (int2*)(gcur + NBUCK + 1);                 // E_EDGES pairs

    const int* srcp = ei;
    const int* dstp = ei + E_EDGES;

    hipMemsetAsync(deg, 0, (size_t)N_NODES * sizeof(int), stream);

    k_parA<<<HIST_BLOCKS + G1A, 256, 0, stream>>>(dstp, deg, x, W1, as1, ad1,
                                                  (__hip_bfloat16*)h1w, s1, d1);
    k_scan_a<<<NBLK_SCAN, 256, 0, stream>>>(deg, bsum);
    k_scan_b<<<1, 64, 0, stream>>>(bsum, bpre);
    k_scan_c<<<NBLK_SCAN, 256, 0, stream>>>(deg, bpre, offs, cur, csr, gcur);
    k_parB<<<NBIN + G1B, 256, 0, stream>>>(srcp, dstp, gcur, coo,
                                           x, W1, as1, ad1,
                                           (__hip_bfloat16*)h1w, s1, d1);
    k_parC<<<NBUCK + G1C, 256, 0, stream>>>(coo, offs, cur, csr,
                                            x, W1, as1, ad1,
                                            (__hip_bfloat16*)h1w, s1, d1);

    k_l1<<<N_NODES / 4, 256, 0, stream>>>(offs, csr, s1, d1,
                                          (const uint4*)h1w, b1, emb);

    k_gemm2<<<N_NODES / 16, 256, 0, stream>>>(emb, W2, as2, ad2,
                                              (__hip_bfloat16*)h2w, s2, d2v);
    k_l2<<<N_NODES / 4, 256, 0, stream>>>(offs, csr, s2, d2v, h2w, b2, logits);
}

// Round 12
// 319.049 us; speedup vs baseline: 44.1800x; 1.1175x over previous
//
#include <hip/hip_runtime.h>
#include <hip/hip_bf16.h>
#include <math.h>

#define N_NODES 100000
#define E_EDGES 1600000
#define ETOT    (E_EDGES + N_NODES)
#define NEG     0.2f

#define SCAN_CHUNK 1024
#define NBLK_SCAN  ((N_NODES + SCAN_CHUNK - 1) / SCAN_CHUNK)   // 98

// bucketed CSR build
#define SH        8
#define NBUCK     ((N_NODES + 255) >> 8)          // 391
#define BIN_TILE  4096
#define NBIN      ((E_EDGES + BIN_TILE - 1) / BIN_TILE)  // 391
#define LDS_CAP   6016

// hist: 8 edges/thread -> 782 blocks; mfma gemm1: 64 nodes/block -> 1563
#define NHIST     ((E_EDGES + 2047) / 2048)       // 782
#define NMFMA     ((N_NODES + 63) / 64)           // 1563

typedef __attribute__((ext_vector_type(8))) short bf16x8;
typedef __attribute__((ext_vector_type(4))) float f32x4;

__device__ inline float lrelu(float x) { return x > 0.f ? x : NEG * x; }
__device__ inline float bflo(unsigned int b) { return __uint_as_float(b << 16); }
__device__ inline float bfhi(unsigned int b) { return __uint_as_float(b & 0xFFFF0000u); }
__device__ inline unsigned short f2bf(float f) {   // RNE bf16 bits
    unsigned int u = __float_as_uint(f);
    return (unsigned short)((u + 0x7FFFu + ((u >> 16) & 1u)) >> 16);
}

// ---------------- kernel A: hist || MFMA gemm1 (bf16) -----------------------
// mfma block: 64 nodes x 128 out, K=128. LDS: x-tile bf16 [64][136],
// W^T bf16 [128][136] (pad 8 keeps 16B alignment, spreads banks).
union SmemA {
    struct { unsigned short xb[64][136]; unsigned short wt[128][136]; } m;
};

__global__ __launch_bounds__(256) void k_parA(
    const int* __restrict__ dst, int* __restrict__ deg,
    const float* __restrict__ x, const float* __restrict__ W,
    const float* __restrict__ asrc, const float* __restrict__ adst,
    __hip_bfloat16* __restrict__ h1b, float* __restrict__ s1,
    float* __restrict__ d1) {
    __shared__ SmemA sm;
    int bid = blockIdx.x, t = threadIdx.x;
    bool isHist = (bid % 3 == 0) && (bid / 3 < NHIST);
    if (isHist) {
        int hid = bid / 3;
        int e0 = hid * 2048 + t * 8;
#pragma unroll
        for (int half = 0; half < 2; ++half) {
            int e = e0 + half * 4;
            if (e + 3 < E_EDGES) {
                int4 v = *(const int4*)(dst + e);
                atomicAdd(&deg[v.x], 1);
                atomicAdd(&deg[v.y], 1);
                atomicAdd(&deg[v.z], 1);
                atomicAdd(&deg[v.w], 1);
            } else {
                for (int i = 0; i < 4; ++i)
                    if (e + i < E_EDGES) atomicAdd(&deg[dst[e + i]], 1);
            }
        }
        return;
    }
    int gid = bid - bid / 3 - 1;          // 0..NMFMA-1
    int n0 = gid * 64;

    // stage x tile (64x128 fp32 -> bf16), float4 coalesced
#pragma unroll
    for (int i = 0; i < 8; ++i) {
        int i4 = t + i * 256;             // 0..2047 float4s
        int r = i4 >> 5;                  // node row 0..63
        int c = (i4 & 31) * 4;            // col 0..124
        float4 v = make_float4(0.f, 0.f, 0.f, 0.f);
        if (n0 + r < N_NODES) v = *(const float4*)(x + (size_t)(n0 + r) * 128 + c);
        sm.m.xb[r][c + 0] = f2bf(v.x);
        sm.m.xb[r][c + 1] = f2bf(v.y);
        sm.m.xb[r][c + 2] = f2bf(v.z);
        sm.m.xb[r][c + 3] = f2bf(v.w);
    }
    // stage W transposed (W[k][n] -> wt[n][k]), float4 coalesced reads
#pragma unroll
    for (int i = 0; i < 16; ++i) {
        int i4 = t + i * 256;             // 0..4095 float4s
        int k = i4 >> 5;                  // 0..127
        int n = (i4 & 31) * 4;
        float4 v = *(const float4*)(W + (size_t)k * 128 + n);
        sm.m.wt[n + 0][k] = f2bf(v.x);
        sm.m.wt[n + 1][k] = f2bf(v.y);
        sm.m.wt[n + 2][k] = f2bf(v.z);
        sm.m.wt[n + 3][k] = f2bf(v.w);
    }
    __syncthreads();

    int l = t & 63, wv = t >> 6;
    int col = l & 15, q4 = l >> 4;
    int rbase = wv * 16;
    int koff = q4 * 8;

    bf16x8 a[4];
#pragma unroll
    for (int st = 0; st < 4; ++st)
        a[st] = *(const bf16x8*)&sm.m.xb[rbase + col][st * 32 + koff];

    int nodeb = n0 + rbase + q4 * 4;
#pragma unroll
    for (int nt = 0; nt < 8; ++nt) {
        f32x4 acc = {0.f, 0.f, 0.f, 0.f};
#pragma unroll
        for (int st = 0; st < 4; ++st) {
            bf16x8 b = *(const bf16x8*)&sm.m.wt[nt * 16 + col][st * 32 + koff];
            acc = __builtin_amdgcn_mfma_f32_16x16x32_bf16(a[st], b, acc, 0, 0, 0);
        }
        float as_v = asrc[nt * 16 + col];
        float ad_v = adst[nt * 16 + col];
#pragma unroll
        for (int r = 0; r < 4; ++r) {
            int node = nodeb + r;
            if (node < N_NODES)
                h1b[(size_t)node * 128 + nt * 16 + col] = __float2bfloat16(acc[r]);
            float ps = acc[r] * as_v, pd = acc[r] * ad_v;
#pragma unroll
            for (int ofs = 1; ofs < 16; ofs <<= 1) {
                ps += __shfl_xor(ps, ofs, 64);
                pd += __shfl_xor(pd, ofs, 64);
            }
            if (col == 0 && node < N_NODES) {
                s1[node * 8 + nt] = ps;
                d1[node * 8 + nt] = pd;
            }
        }
    }
}

// ---------------- scan (degrees +1 for implicit self-loop) ------------------
__global__ __launch_bounds__(256) void k_scan_a(const int* __restrict__ deg,
                                                int* __restrict__ bsum) {
    __shared__ int red[256];
    int b = blockIdx.x, t = threadIdx.x;
    int base = b * SCAN_CHUNK + t * 4;
    int s = 0;
    if (base + 3 < N_NODES) {
        int4 v = *(const int4*)(deg + base);
        s = v.x + v.y + v.z + v.w + 4;
    } else {
#pragma unroll
        for (int i = 0; i < 4; ++i)
            if (base + i < N_NODES) s += deg[base + i] + 1;
    }
    red[t] = s;
    __syncthreads();
    for (int ofs = 128; ofs; ofs >>= 1) {
        if (t < ofs) red[t] += red[t + ofs];
        __syncthreads();
    }
    if (t == 0) bsum[b] = red[0];
}

__global__ void k_scan_b(const int* __restrict__ bsum, int* __restrict__ bpre) {
    int t = threadIdx.x;   // 64
    int a = (2 * t     < NBLK_SCAN) ? bsum[2 * t]     : 0;
    int b = (2 * t + 1 < NBLK_SCAN) ? bsum[2 * t + 1] : 0;
    int local = a + b;
    int incl = local;
#pragma unroll
    for (int ofs = 1; ofs < 64; ofs <<= 1) {
        int u = __shfl_up(incl, ofs, 64);
        if (t >= ofs) incl += u;
    }
    int pre = incl - local;
    if (2 * t     < NBLK_SCAN) bpre[2 * t]     = pre;
    if (2 * t + 1 < NBLK_SCAN) bpre[2 * t + 1] = pre + a;
}

// scan C: off/cur, self-loop into csr[off[n]], and bucket COO bases (gcur)
__global__ __launch_bounds__(256) void k_scan_c(const int* __restrict__ deg,
                                                const int* __restrict__ bpre,
                                                int* __restrict__ off,
                                                int* __restrict__ cur,
                                                int* __restrict__ csr,
                                                int* __restrict__ gcur) {
    __shared__ int tsum[256];
    int b = blockIdx.x, t = threadIdx.x;
    int base = b * SCAN_CHUNK + t * 4;
    int d0 = 0, d1 = 0, d2 = 0, d3 = 0;
    if (base + 3 < N_NODES) {
        int4 v = *(const int4*)(deg + base);
        d0 = v.x + 1; d1 = v.y + 1; d2 = v.z + 1; d3 = v.w + 1;
    } else {
        if (base     < N_NODES) d0 = deg[base] + 1;
        if (base + 1 < N_NODES) d1 = deg[base + 1] + 1;
        if (base + 2 < N_NODES) d2 = deg[base + 2] + 1;
        if (base + 3 < N_NODES) d3 = deg[base + 3] + 1;
    }
    int s = d0 + d1 + d2 + d3;
    tsum[t] = s;
    __syncthreads();
    for (int ofs = 1; ofs < 256; ofs <<= 1) {
        int u = (t >= ofs) ? tsum[t - ofs] : 0;
        __syncthreads();
        tsum[t] += u;
        __syncthreads();
    }
    int run = bpre[b] + tsum[t] - s;
    if (base < N_NODES) {
        if ((base & 255) == 0) gcur[base >> SH] = run - base;  // COO bucket base
        off[base] = run; csr[run] = base; cur[base] = run + 1; run += d0;
    }
    if (base + 1 < N_NODES) { off[base + 1] = run; csr[run] = base + 1;
                              cur[base + 1] = run + 1; run += d1; }
    if (base + 2 < N_NODES) { off[base + 2] = run; csr[run] = base + 2;
                              cur[base + 2] = run + 1; run += d2; }
    if (base + 3 < N_NODES) { off[base + 3] = run; csr[run] = base + 3;
                              cur[base + 3] = run + 1; run += d3; }
    if (b == 0 && t == 0) off[N_NODES] = ETOT;
}

// ---------------- bin: bucket-major COO (standalone) ------------------------
__global__ __launch_bounds__(256) void k_bin(
    const int* __restrict__ src, const int* __restrict__ dst,
    int* __restrict__ gcur, int2* __restrict__ coo) {
    __shared__ int2 st[BIN_TILE];
    __shared__ int  hist[NBUCK + 1];
    __shared__ int  lstart[NBUCK];
    __shared__ int  gbase[NBUCK];
    __shared__ int  tsum[256];
    int wb = blockIdx.x, t = threadIdx.x;
    int e0 = wb * BIN_TILE;
    int nE = min(BIN_TILE, E_EDGES - e0);
    for (int i = t; i <= NBUCK; i += 256) hist[i] = 0;
    __syncthreads();
    for (int i = t; i < nE; i += 256)
        atomicAdd(&hist[dst[e0 + i] >> SH], 1);
    __syncthreads();
    int i0 = 2 * t, i1 = 2 * t + 1;
    int h0 = (i0 < NBUCK) ? hist[i0] : 0;
    int h1v = (i1 < NBUCK) ? hist[i1] : 0;
    int s = h0 + h1v;
    tsum[t] = s;
    __syncthreads();
    for (int ofs = 1; ofs < 256; ofs <<= 1) {
        int u = (t >= ofs) ? tsum[t - ofs] : 0;
        __syncthreads();
        tsum[t] += u;
        __syncthreads();
    }
    int pre = tsum[t] - s;
    if (i0 < NBUCK) hist[i0] = pre;
    if (i1 < NBUCK) hist[i1] = pre + h0;
    if (t == 255) hist[NBUCK] = tsum[255];
    __syncthreads();
    for (int i = t; i < NBUCK; i += 256) {
        int st_ = hist[i];
        int cnt = hist[i + 1] - st_;
        lstart[i] = st_;
        if (cnt > 0) gbase[i] = atomicAdd(&gcur[i], cnt);
    }
    __syncthreads();
    for (int i = t; i < nE; i += 256) {
        int sv = src[e0 + i], dv = dst[e0 + i];
        int p = atomicAdd(&hist[dv >> SH], 1);
        st[p] = make_int2(sv, dv);
    }
    __syncthreads();
    for (int i = t; i < nE; i += 256) {
        int2 e = st[i];
        int b2 = e.y >> SH;
        coo[gbase[b2] + (i - lstart[b2])] = e;
    }
}

// ---------------- fine: per-bucket LDS reorder (standalone) -----------------
__global__ __launch_bounds__(256) void k_fine(
    const int2* __restrict__ coo, const int* __restrict__ off,
    int* __restrict__ cur, int* __restrict__ csr) {
    __shared__ int lcur[256];
    __shared__ int lsrc[LDS_CAP];
    int b = blockIdx.x, t = threadIdx.x;
    int n0 = b << SH;
    int n1 = min(n0 + 256, N_NODES);
    int nn = n1 - n0;
    int base = off[n0], endv = off[n1];
    int ecnt = endv - base;
    int cooStart = base - n0;
    int cooEnd = endv - n1;
    if (ecnt <= LDS_CAP) {
        if (t < nn) {
            int o = off[n0 + t] - base;
            lcur[t] = o + 1;            // slot 0 = self-loop
            lsrc[o] = n0 + t;
        }
        __syncthreads();
        for (int i = cooStart + t; i < cooEnd; i += 256) {
            int2 e = coo[i];
            int p = atomicAdd(&lcur[e.y - n0], 1);
            lsrc[p] = e.x;
        }
        __syncthreads();
        for (int i = t; i < ecnt; i += 256)
            csr[base + i] = lsrc[i];
    } else {
        for (int i = cooStart + t; i < cooEnd; i += 256) {
            int2 e = coo[i];
            int slot = atomicAdd(&cur[e.y], 1);
            csr[slot] = e.x;
        }
    }
}

// ---------------- layer 1 single-pass softmax-aggregate ---------------------
__global__ __launch_bounds__(256) void k_l1(
    const int* __restrict__ off, const int* __restrict__ csr,
    const float* __restrict__ s1, const float* __restrict__ d1,
    const uint4* __restrict__ h1q, const float* __restrict__ b1,
    float* __restrict__ emb) {
    int t = threadIdx.x;
    int node = blockIdx.x * 4 + (t >> 6);
    int l = t & 63;
    int g = l >> 4, q = l & 15;
    int hb = q >> 1;
    int lo = off[node], hi = off[node + 1];
    float dvh = d1[node * 8 + hb];

    float acc[8];
#pragma unroll
    for (int c = 0; c < 8; ++c) acc[c] = 0.f;
    float den = 0.f;

    int idx = lo + g;
    int sc = 0; uint4 bv = make_uint4(0, 0, 0, 0); float sv = 0.f;
    if (idx < hi) {
        sc = csr[idx];
        bv = h1q[(size_t)sc * 16 + q];
        sv = s1[sc * 8 + hb];
    }
    while (idx < hi) {
        int nidx = idx + 4;
        int sn = 0; uint4 bn = make_uint4(0, 0, 0, 0); float svn = 0.f;
        if (nidx < hi) {
            sn = csr[nidx];
            bn = h1q[(size_t)sn * 16 + q];
            svn = s1[sn * 8 + hb];
        }
        float w = __expf(lrelu(sv + dvh));
        den += w;
        acc[0] = fmaf(w, bflo(bv.x), acc[0]);
        acc[1] = fmaf(w, bfhi(bv.x), acc[1]);
        acc[2] = fmaf(w, bflo(bv.y), acc[2]);
        acc[3] = fmaf(w, bfhi(bv.y), acc[3]);
        acc[4] = fmaf(w, bflo(bv.z), acc[4]);
        acc[5] = fmaf(w, bfhi(bv.z), acc[5]);
        acc[6] = fmaf(w, bflo(bv.w), acc[6]);
        acc[7] = fmaf(w, bfhi(bv.w), acc[7]);
        sc = sn; bv = bn; sv = svn; idx = nidx;
    }
#pragma unroll
    for (int c = 0; c < 8; ++c) {
        acc[c] += __shfl_xor(acc[c], 16, 64);
        acc[c] += __shfl_xor(acc[c], 32, 64);
    }
    den += __shfl_xor(den, 16, 64);
    den += __shfl_xor(den, 32, 64);

    if (l < 16) {
        float r = 1.f / den;
        float vv[8];
#pragma unroll
        for (int c = 0; c < 8; ++c) {
            float v = acc[c] * r + b1[8 * q + c];
            vv[c] = v > 0.f ? v : expm1f(v);
        }
        float4* ep = (float4*)(emb + (size_t)node * 128);
        ep[2 * q]     = make_float4(vv[0], vv[1], vv[2], vv[3]);
        ep[2 * q + 1] = make_float4(vv[4], vv[5], vv[6], vv[7]);
    }
}

// ---------------- layer 2 GEMM: h2(bf16) = emb @ W2 (128->16), s2/d2 --------
__global__ __launch_bounds__(256) void k_gemm2(
    const float* __restrict__ emb, const float* __restrict__ W,
    const float* __restrict__ asrc, const float* __restrict__ adst,
    __hip_bfloat16* __restrict__ h2b, float* __restrict__ s2,
    float* __restrict__ d2) {
    __shared__ float xs[16][129];
    int n0 = blockIdx.x * 16;
    int t = threadIdx.x;
#pragma unroll
    for (int i = 0; i < 8; ++i) {
        int idx = t + i * 256;
        xs[idx >> 7][idx & 127] = emb[(long)n0 * 128 + idx];
    }
    __syncthreads();
    int j = t & 15, sub = t >> 4;
    float acc = 0.f;
    for (int k = 0; k < 128; ++k) acc = fmaf(xs[sub][k], W[k * 16 + j], acc);
    int n = n0 + sub;
    h2b[(long)n * 16 + j] = __float2bfloat16(acc);
    float ps = acc * asrc[j], pd = acc * adst[j];
#pragma unroll
    for (int off = 8; off; off >>= 1) {
        ps += __shfl_down(ps, off, 16);
        pd += __shfl_down(pd, off, 16);
    }
    if (j == 0) { s2[n] = ps; d2[n] = pd; }
}

// ---------------- layer 2 single-pass aggregate + log_softmax ---------------
__global__ __launch_bounds__(256) void k_l2(
    const int* __restrict__ off, const int* __restrict__ csr,
    const float* __restrict__ s2, const float* __restrict__ d2,
    const unsigned int* __restrict__ h2w, const float* __restrict__ b2,
    float* __restrict__ logits) {
    int t = threadIdx.x;
    int node = blockIdx.x * 4 + (t >> 6);
    int l = t & 63;
    int g = l >> 3, p = l & 7;
    int lo = off[node], hi = off[node + 1];
    float dv = d2[node];

    float ax = 0.f, ay = 0.f, den = 0.f;
    for (int idx = lo + g; idx < hi; idx += 8) {
        int s = csr[idx];
        float w = __expf(lrelu(s2[s] + dv));
        den += w;
        unsigned int bv = h2w[(size_t)s * 8 + p];
        ax = fmaf(w, bflo(bv), ax);
        ay = fmaf(w, bfhi(bv), ay);
    }
#pragma unroll
    for (int ofs = 8; ofs < 64; ofs <<= 1) {
        ax += __shfl_xor(ax, ofs, 64);
        ay += __shfl_xor(ay, ofs, 64);
        den += __shfl_xor(den, ofs, 64);
    }
    float r = 1.f / den;
    float v0 = ax * r + b2[2 * p], v1 = ay * r + b2[2 * p + 1];
    float mm = fmaxf(v0, v1);
#pragma unroll
    for (int ofs = 1; ofs < 8; ofs <<= 1) mm = fmaxf(mm, __shfl_xor(mm, ofs, 8));
    float sm = __expf(v0 - mm) + __expf(v1 - mm);
#pragma unroll
    for (int ofs = 1; ofs < 8; ofs <<= 1) sm += __shfl_xor(sm, ofs, 8);
    if (g == 0) {
        float ls = logf(sm);
        logits[node * 16 + 2 * p]     = v0 - mm - ls;
        logits[node * 16 + 2 * p + 1] = v1 - mm - ls;
    }
}

extern "C" void kernel_launch(void* const* d_in, const int* in_sizes, int n_in,
                              void* d_out, int out_size, void* d_ws, size_t ws_size,
                              hipStream_t stream) {
    const float* x   = (const float*)d_in[0];
    const int*   ei  = (const int*)d_in[1];
    const float* W1  = (const float*)d_in[2];
    const float* as1 = (const float*)d_in[3];
    const float* ad1 = (const float*)d_in[4];
    const float* b1  = (const float*)d_in[5];
    const float* W2  = (const float*)d_in[6];
    const float* as2 = (const float*)d_in[7];
    const float* ad2 = (const float*)d_in[8];
    const float* b2  = (const float*)d_in[9];

    float* out    = (float*)d_out;
    float* logits = out;                          // [N,16]
    float* emb    = out + (size_t)N_NODES * 16;   // [N,128]

    float* ws    = (float*)d_ws;
    unsigned int* h1w = (unsigned int*)ws;                    // N*64 words (bf16 x2)
    float* s1    = (float*)(h1w + (size_t)N_NODES * 64);      // N*8
    float* d1    = s1 + (size_t)N_NODES * 8;
    unsigned int* h2w = (unsigned int*)(d1 + (size_t)N_NODES * 8); // N*8 words
    float* s2    = (float*)(h2w + (size_t)N_NODES * 8);       // N
    float* d2v   = s2 + (size_t)N_NODES;
    int*   deg   = (int*)(d2v + (size_t)N_NODES);             // N
    int*   offs  = deg + N_NODES;                             // N+1
    int*   cur   = offs + N_NODES + 1;                        // N
    int*   csr   = cur + N_NODES;                             // ETOT
    int*   bsum  = csr + ETOT;                                // NBLK_SCAN
    int*   bpre  = bsum + NBLK_SCAN;                          // NBLK_SCAN
    int*   gcur  = bpre + NBLK_SCAN;                          // NBUCK
    int2*  coo   = (int2*)(gcur + NBUCK + 1);                 // E_EDGES pairs

    const int* srcp = ei;
    const int* dstp = ei + E_EDGES;

    hipMemsetAsync(deg, 0, (size_t)N_NODES * sizeof(int), stream);

    k_parA<<<NHIST + NMFMA, 256, 0, stream>>>(dstp, deg, x, W1, as1, ad1,
                                              (__hip_bfloat16*)h1w, s1, d1);
    k_scan_a<<<NBLK_SCAN, 256, 0, stream>>>(deg, bsum);
    k_scan_b<<<1, 64, 0, stream>>>(bsum, bpre);
    k_scan_c<<<NBLK_SCAN, 256, 0, stream>>>(deg, bpre, offs, cur, csr, gcur);
    k_bin<<<NBIN, 256, 0, stream>>>(srcp, dstp, gcur, coo);
    k_fine<<<NBUCK, 256, 0, stream>>>(coo, offs, cur, csr);

    k_l1<<<N_NODES / 4, 256, 0, stream>>>(offs, csr, s1, d1,
                                          (const uint4*)h1w, b1, emb);

    k_gemm2<<<N_NODES / 16, 256, 0, stream>>>(emb, W2, as2, ad2,
                                              (__hip_bfloat16*)h2w, s2, d2v);
    k_l2<<<N_NODES / 4, 256, 0, stream>>>(offs, csr, s2, d2v, h2w, b2, logits);
}